// Round 1
// baseline (958.561 us; speedup 1.0000x reference)
//
#include <hip/hip_runtime.h>
#include <math.h>

#define B_ 2
#define N_ 8192          // points per batch
#define G_ 64
#define NG 4096          // G*G latent grid points
#define WID_ 64
#define K_ 16
#define CIN_ 6
#define COUT_ 3
#define PI_ 3.14159265358979323846

// ---------------------------------------------------------------- helpers
__device__ __forceinline__ float gelu_f(float x) {
    // exact-erf GELU, matches jax.nn.gelu(approximate=False)
    return 0.5f * x * (1.0f + erff(x * 0.70710678118654752440f));
}
__device__ __forceinline__ int cellof(float v) {
    int c = (int)floorf((v + 1.0f) * 32.0f);   // 64 cells over [-1,1], h = 0.03125
    return min(63, max(0, c));
}

// ---------------------------------------------------------------- grid gen
// numpy linspace semantics: computed in double, endpoint forced, cast to f32.
__global__ void k_gridgen(float4* gp) {
    int p = blockIdx.x * blockDim.x + threadIdx.x;
    if (p >= NG) return;
    int i = p >> 6, j = p & 63;
    double st = 2.0 / 63.0;
    float gx = (i == 63) ? 1.0f : (float)(-1.0 + st * (double)i);
    float gy = (j == 63) ? 1.0f : (float)(-1.0 + st * (double)j);
    float s2 = __fadd_rn(__fmul_rn(gx, gx), __fmul_rn(gy, gy));
    gp[p] = make_float4(gx, gy, s2, 0.f);
}

// ---------------------------------------------------------------- lift MLP
__global__ void __launch_bounds__(256) k_lift(
    const float* __restrict__ fin, const float* __restrict__ W1,
    const float* __restrict__ b1, const float* __restrict__ W2,
    const float* __restrict__ b2, float* __restrict__ fout) {
    __shared__ float xr[4][8];
    __shared__ __align__(16) float h[4][64];
    int ql = threadIdx.x >> 6, j = threadIdx.x & 63;
    int node = blockIdx.x * 4 + ql;      // < B_*N_
    if (j < CIN_) xr[ql][j] = fin[node * CIN_ + j];
    __syncthreads();
    float a = b1[j];
#pragma unroll
    for (int i = 0; i < CIN_; i++) a = fmaf(xr[ql][i], W1[i * 64 + j], a);
    h[ql][j] = gelu_f(a);
    __syncthreads();
    float a2 = b2[j];
    for (int k = 0; k < 64; k += 4) {
        float w0 = W2[(k + 0) * 64 + j], w1 = W2[(k + 1) * 64 + j];
        float w2 = W2[(k + 2) * 64 + j], w3 = W2[(k + 3) * 64 + j];
        const float4 hv = *(const float4*)&h[ql][k];
        a2 = fmaf(hv.x, w0, fmaf(hv.y, w1, fmaf(hv.z, w2, fmaf(hv.w, w3, a2))));
    }
    fout[node * 64 + j] = a2;
}

// ---------------------------------------------------------------- binning
__global__ void k_bincount(const float2* __restrict__ coords, int* __restrict__ cnt) {
    int t = blockIdx.x * blockDim.x + threadIdx.x;
    if (t >= B_ * N_) return;
    float2 c = coords[t];
    int b = t >> 13;
    int cell = cellof(c.x) * 64 + cellof(c.y);
    atomicAdd(&cnt[b * 4096 + cell], 1);
}
__global__ void k_binscan(const int* __restrict__ cnt, int* __restrict__ offs) {
    int b = blockIdx.x, t = threadIdx.x;    // 1024 threads
    __shared__ int s[1024];
    int4 v = ((const int4*)(cnt + b * 4096))[t];
    int sum = v.x + v.y + v.z + v.w;
    s[t] = sum;
    __syncthreads();
    for (int d = 1; d < 1024; d <<= 1) {
        int x = (t >= d) ? s[t - d] : 0;
        __syncthreads();
        s[t] += x;
        __syncthreads();
    }
    int incl = s[t], excl = incl - sum;
    int* ob = offs + b * 4097;
    ob[4 * t] = excl; ob[4 * t + 1] = excl + v.x;
    ob[4 * t + 2] = excl + v.x + v.y; ob[4 * t + 3] = excl + v.x + v.y + v.z;
    if (t == 1023) ob[4096] = incl;
}
__global__ void k_binscatter(const float2* __restrict__ coords, const int* __restrict__ offs,
                             int* __restrict__ fill, float4* __restrict__ srt) {
    int t = blockIdx.x * blockDim.x + threadIdx.x;
    if (t >= B_ * N_) return;
    float2 c = coords[t];
    int b = t >> 13, n = t & 8191;
    int cell = cellof(c.x) * 64 + cellof(c.y);
    int pos = offs[b * 4097 + cell] + atomicAdd(&fill[b * 4096 + cell], 1);
    float s2 = __fadd_rn(__fmul_rn(c.x, c.x), __fmul_rn(c.y, c.y));
    srt[b * N_ + pos] = make_float4(c.x, c.y, s2, __int_as_float(n));
}

// ---------------------------------------------------------------- kNN grid->points (queries = lattice nodes)
__global__ void k_knn_in(const float4* __restrict__ gp, const float4* __restrict__ srt,
                         const int* __restrict__ offs, int* __restrict__ oidx,
                         float* __restrict__ odist, float* __restrict__ lastd) {
    int t = blockIdx.x * blockDim.x + threadIdx.x;
    if (t >= B_ * NG) return;
    int b = t >> 12, p = t & 4095;
    float4 q = gp[p];
    float qx = q.x, qy = q.y, q2 = q.z;
    int cqx = cellof(qx), cqy = cellof(qy);
    float bd[16]; int bi[16];
#pragma unroll
    for (int r = 0; r < 16; r++) { bd[r] = 3.4e38f; bi[r] = 0x7fffffff; }
    const float4* S = srt + b * N_;
    const int* OF = offs + b * 4097;

    auto scan_cell = [&](int cx, int cy) {
        int cell = cx * 64 + cy;
        int s0 = OF[cell], s1 = OF[cell + 1];
        for (int s = s0; s < s1; s++) {
            float4 sp = S[s];
            float dot = __fadd_rn(__fmul_rn(qx, sp.x), __fmul_rn(qy, sp.y));
            float d2 = __fsub_rn(__fadd_rn(q2, sp.z), 2.0f * dot);  // numpy order
            int si = __float_as_int(sp.w);
            if (d2 <= bd[15]) {
#pragma unroll
                for (int u = 0; u < 16; u++) {
                    bool bet = (d2 < bd[u]) || (d2 == bd[u] && si < bi[u]);
                    float td = bd[u]; int ti = bi[u];
                    if (bet) { bd[u] = d2; bi[u] = si; d2 = td; si = ti; }
                }
            }
        }
    };

    for (int r = 0; r < 64; r++) {
        if (r >= 2) {
            float bm = (float)(r - 1) * 0.03125f;   // min dist of any unseen ring-r point
            if (bd[15] < bm * bm - 1e-5f) break;
        }
        int x0 = cqx - r, x1 = cqx + r, y0 = cqy - r, y1 = cqy + r;
        int cxa = max(x0, 0), cxb = min(x1, 63);
        for (int cx = cxa; cx <= cxb; cx++) {
            if (cx == x0 || cx == x1) {
                int ya = max(y0, 0), yb = min(y1, 63);
                for (int cy = ya; cy <= yb; cy++) scan_cell(cx, cy);
            } else {
                if (y0 >= 0) scan_cell(cx, y0);
                if (y1 <= 63) scan_cell(cx, y1);
            }
        }
    }
    int base = t * 16;
    float dl = 0.f;
#pragma unroll
    for (int e = 0; e < 16; e++) {
        oidx[base + e] = bi[e];
        float d = sqrtf(fmaxf(bd[e], 0.f));
        odist[base + e] = d;
        dl = d;
    }
    lastd[t] = dl;
}

// ---------------------------------------------------------------- kNN points->grid (sources = regular lattice: 8x8 box)
__global__ void k_knn_out(const float2* __restrict__ coords, const float4* __restrict__ gp,
                          int* __restrict__ oidx, float* __restrict__ odist,
                          float* __restrict__ lastd) {
    int t = blockIdx.x * blockDim.x + threadIdx.x;
    if (t >= B_ * N_) return;
    float2 c = coords[t];
    float qx = c.x, qy = c.y;
    float q2 = __fadd_rn(__fmul_rn(qx, qx), __fmul_rn(qy, qy));
    int i0 = (int)floorf((qx + 1.0f) * 31.5f);
    int j0 = (int)floorf((qy + 1.0f) * 31.5f);
    int li = min(max(i0 - 3, 0), 56);
    int lj = min(max(j0 - 3, 0), 56);
    float bd[16]; int bi[16];
#pragma unroll
    for (int r = 0; r < 16; r++) { bd[r] = 3.4e38f; bi[r] = 0x7fffffff; }
    for (int ii = 0; ii < 8; ii++) {
        int gi = li + ii;
        for (int jj = 0; jj < 8; jj++) {
            int p = gi * 64 + (lj + jj);
            float4 sp = gp[p];
            float dot = __fadd_rn(__fmul_rn(qx, sp.x), __fmul_rn(qy, sp.y));
            float d2 = __fsub_rn(__fadd_rn(q2, sp.z), 2.0f * dot);
            int si = p;
            if (d2 <= bd[15]) {
#pragma unroll
                for (int u = 0; u < 16; u++) {
                    bool bet = (d2 < bd[u]) || (d2 == bd[u] && si < bi[u]);
                    float td = bd[u]; int ti = bi[u];
                    if (bet) { bd[u] = d2; bi[u] = si; d2 = td; si = ti; }
                }
            }
        }
    }
    int base = t * 16;
    float dl = 0.f;
#pragma unroll
    for (int e = 0; e < 16; e++) {
        oidx[base + e] = bi[e];
        float d = sqrtf(fmaxf(bd[e], 0.f));
        odist[base + e] = d;
        dl = d;
    }
    lastd[t] = dl;
}

// ---------------------------------------------------------------- exact lower-median via radix select on float bits (all vals >= 0)
__global__ void k_median(const float* __restrict__ vals, int n, int rank, float* __restrict__ sig) {
    __shared__ unsigned hist[256];
    __shared__ unsigned selp;
    __shared__ int selr;
    unsigned prefix = 0; int r = rank;
    for (int lvl = 3; lvl >= 0; --lvl) {
        for (int i = threadIdx.x; i < 256; i += blockDim.x) hist[i] = 0;
        __syncthreads();
        unsigned mhi = (lvl == 3) ? 0u : (0xFFFFFFFFu << ((lvl + 1) * 8));
        for (int i = threadIdx.x; i < n; i += blockDim.x) {
            unsigned u = __float_as_uint(vals[i]);
            if ((u & mhi) == prefix) atomicAdd(&hist[(u >> (lvl * 8)) & 255], 1u);
        }
        __syncthreads();
        if (threadIdx.x == 0) {
            int rr = r; unsigned bsel = 255;
            for (unsigned bb = 0; bb < 256; bb++) {
                unsigned cc = hist[bb];
                if (rr < (int)cc) { bsel = bb; break; }
                rr -= cc;
            }
            selp = prefix | (bsel << (lvl * 8));
            selr = rr;
        }
        __syncthreads();
        prefix = selp; r = selr;
        __syncthreads();
    }
    if (threadIdx.x == 0) *sig = fmaxf(__uint_as_float(prefix), 1e-6f);
}

// ---------------------------------------------------------------- edge MLP + weighted aggregation (one wave per query)
// MODE 0: queries = grid, sources = coords, feats rows = N_ per batch
// MODE 1: queries = coords, sources = grid,  feats rows = NG per batch
template <int MODE>
__global__ void __launch_bounds__(256) k_edge(
    const int* __restrict__ idxb, const float* __restrict__ distb, const float* __restrict__ sigp,
    const float2* __restrict__ coords, const float4* __restrict__ gp,
    const float* __restrict__ feats,
    const float* __restrict__ W1, const float* __restrict__ b1,
    const float* __restrict__ W2, const float* __restrict__ b2,
    const float* __restrict__ W3, const float* __restrict__ b3,
    float* __restrict__ outb, int Nq, int srcRows) {
    __shared__ __align__(16) float eA[4][16][72];  // edge feats / layer-2 hidden
    __shared__ __align__(16) float hB[4][16][64];  // layer-1 hidden
    __shared__ float wts[4][16];
    __shared__ int nidx[4][16];
    __shared__ float dls[4][16];
    __shared__ float qxy[4][2];
    int ql = threadIdx.x >> 6, j = threadIdx.x & 63;
    int gq = blockIdx.x * 4 + ql;
    int b = gq / Nq, p = gq - b * Nq;

    if (j < 16) {
        int base = gq * 16 + j;
        int si = idxb[base];
        float d = distb[base];
        nidx[ql][j] = si;
        dls[ql][j] = d;
        wts[ql][j] = expf(-d / (*sigp));
    }
    if (j == 0) {
        float qx, qy;
        if (MODE == 0) { float4 g = gp[p]; qx = g.x; qy = g.y; }
        else           { float2 cc = coords[(long)b * Nq + p]; qx = cc.x; qy = cc.y; }
        qxy[ql][0] = qx; qxy[ql][1] = qy;
    }
    __syncthreads();
    float qx = qxy[ql][0], qy = qxy[ql][1];
    if (j < 16) {
        int si = nidx[ql][j];
        float sx, sy;
        if (MODE == 0) { float2 cc = coords[(long)b * srcRows + si]; sx = cc.x; sy = cc.y; }
        else           { float4 g = gp[si]; sx = g.x; sy = g.y; }
        eA[ql][j][0] = qx; eA[ql][j][1] = qy;
        eA[ql][j][2] = sx; eA[ql][j][3] = sy;
        eA[ql][j][4] = qx - sx; eA[ql][j][5] = qy - sy;
        eA[ql][j][6] = dls[ql][j];
        eA[ql][j][71] = 0.f;
    }
#pragma unroll
    for (int e = 0; e < 16; e++) {
        int si = nidx[ql][e];
        eA[ql][e][7 + j] = feats[((long)b * srcRows + si) * 64 + j];
    }
    __syncthreads();

    float acc[16];
    // ---- layer 1 (71 -> 64)
    {
        float bj = b1[j];
#pragma unroll
        for (int e = 0; e < 16; e++) acc[e] = bj;
        for (int i = 0; i < 68; i += 4) {
            float w0 = W1[(i + 0) * 64 + j], w1 = W1[(i + 1) * 64 + j];
            float w2 = W1[(i + 2) * 64 + j], w3 = W1[(i + 3) * 64 + j];
#pragma unroll
            for (int e = 0; e < 16; e++) {
                const float4 ev = *(const float4*)&eA[ql][e][i];
                acc[e] = fmaf(ev.x, w0, fmaf(ev.y, w1, fmaf(ev.z, w2, fmaf(ev.w, w3, acc[e]))));
            }
        }
        float w0 = W1[68 * 64 + j], w1 = W1[69 * 64 + j], w2 = W1[70 * 64 + j];
#pragma unroll
        for (int e = 0; e < 16; e++) {
            const float4 ev = *(const float4*)&eA[ql][e][68];
            acc[e] = fmaf(ev.x, w0, fmaf(ev.y, w1, fmaf(ev.z, w2, acc[e])));
        }
    }
#pragma unroll
    for (int e = 0; e < 16; e++) hB[ql][e][j] = gelu_f(acc[e]);
    __syncthreads();
    // ---- layer 2 (64 -> 64)
    {
        float bj = b2[j];
#pragma unroll
        for (int e = 0; e < 16; e++) acc[e] = bj;
        for (int k = 0; k < 64; k += 4) {
            float w0 = W2[(k + 0) * 64 + j], w1 = W2[(k + 1) * 64 + j];
            float w2 = W2[(k + 2) * 64 + j], w3 = W2[(k + 3) * 64 + j];
#pragma unroll
            for (int e = 0; e < 16; e++) {
                const float4 hv = *(const float4*)&hB[ql][e][k];
                acc[e] = fmaf(hv.x, w0, fmaf(hv.y, w1, fmaf(hv.z, w2, fmaf(hv.w, w3, acc[e]))));
            }
        }
    }
#pragma unroll
    for (int e = 0; e < 16; e++) eA[ql][e][j] = gelu_f(acc[e]);  // h2 into eA (reads done)
    __syncthreads();
    // ---- layer 3 (64 -> 64), no activation
    {
        float bj = b3[j];
#pragma unroll
        for (int e = 0; e < 16; e++) acc[e] = bj;
        for (int k = 0; k < 64; k += 4) {
            float w0 = W3[(k + 0) * 64 + j], w1 = W3[(k + 1) * 64 + j];
            float w2 = W3[(k + 2) * 64 + j], w3 = W3[(k + 3) * 64 + j];
#pragma unroll
            for (int e = 0; e < 16; e++) {
                const float4 hv = *(const float4*)&eA[ql][e][k];
                acc[e] = fmaf(hv.x, w0, fmaf(hv.y, w1, fmaf(hv.z, w2, fmaf(hv.w, w3, acc[e]))));
            }
        }
    }
    float sw = 0.f, so = 0.f;
#pragma unroll
    for (int e = 0; e < 16; e++) {
        float w = wts[ql][e];
        sw += w;
        so = fmaf(w, acc[e], so);
    }
    outb[(long)gq * 64 + j] = so / fmaxf(sw, 1e-6f);
}

// ---------------------------------------------------------------- transpose (B,R,C) -> (B,C,R)
__global__ void k_transp(const float* __restrict__ src, float* __restrict__ dst, int R, int C) {
    __shared__ float t[32][33];
    int b = blockIdx.z;
    int c0 = blockIdx.x * 32, r0 = blockIdx.y * 32;
    int tx = threadIdx.x, ty0 = threadIdx.y;    // (32,8)
    for (int yy = ty0; yy < 32; yy += 8) {
        int r = r0 + yy, c = c0 + tx;
        if (r < R && c < C) t[yy][tx] = src[((long)b * R + r) * C + c];
    }
    __syncthreads();
    for (int yy = ty0; yy < 32; yy += 8) {
        int c = c0 + yy, r = r0 + tx;
        if (r < R && c < C) dst[((long)b * C + c) * R + r] = t[tx][yy];
    }
}

// ---------------------------------------------------------------- FNO: truncated forward DFT (rows 0..11 & 52..63, cols 0..11)
__global__ void __launch_bounds__(256) k_f1(const float* __restrict__ x, float* __restrict__ Xh) {
    int blk = blockIdx.x;    // b*64 + ch
    int tid = threadIdx.x;   // 256
    __shared__ float img[4096];
    __shared__ float Tre[64][12], Tim[64][12];
    __shared__ float cs[64], sn[64];
    if (tid < 64) {
        double a = (2.0 * PI_ / 64.0) * (double)tid;
        cs[tid] = (float)cos(a);
        sn[tid] = (float)sin(a);
    }
    for (int p = tid; p < 4096; p += 256) img[p] = x[(long)blk * 4096 + p];
    __syncthreads();
    for (int o = tid; o < 768; o += 256) {       // (h, c)
        int h = o / 12, c = o - 12 * h;
        float re = 0.f, im = 0.f;
        for (int w = 0; w < 64; w++) {
            float v = img[h * 64 + w];
            int k = (c * w) & 63;
            re = fmaf(v, cs[k], re);
            im = fmaf(-v, sn[k], im);
        }
        Tre[h][c] = re; Tim[h][c] = im;
    }
    __syncthreads();
    for (int o = tid; o < 288; o += 256) {       // (x24, c12)
        int xx = o / 12, c = o - 12 * xx;
        int r = (xx < 12) ? xx : (xx + 40);
        float re = 0.f, im = 0.f;
        for (int h = 0; h < 64; h++) {
            int k = (r * h) & 63;
            float cr = cs[k], si = sn[k];
            float a = Tre[h][c], bb = Tim[h][c];
            re += a * cr + bb * si;              // (a+ib)*e^{-i phi}
            im += bb * cr - a * si;
        }
        Xh[((long)blk * 288 + o) * 2] = re;
        Xh[((long)blk * 288 + o) * 2 + 1] = im;
    }
}

// mode-mix: Yhat[b,o,m] = sum_i Wc[i,o,m] * Xhat[b,i,m]
__global__ void k_f2(const float* __restrict__ Xh, const float* __restrict__ s1,
                     const float* __restrict__ s2, float* __restrict__ Yh) {
    int m = blockIdx.x;                  // 0..287
    int xx = m / 12, y = m - 12 * xx;
    const float* W; int xw;
    if (xx < 12) { W = s1; xw = xx; } else { W = s2; xw = xx - 12; }
    __shared__ float xr[128], xi[128];
    int tid = threadIdx.x;               // 128
    {
        int bb = tid >> 6, i = tid & 63;
        xr[tid] = Xh[(((long)bb * 64 + i) * 288 + m) * 2];
        xi[tid] = Xh[(((long)bb * 64 + i) * 288 + m) * 2 + 1];
    }
    __syncthreads();
    int bb = tid >> 6, o = tid & 63;
    float re = 0.f, im = 0.f;
    for (int i = 0; i < 64; i++) {
        long wb = (long)i * 18432 + (long)o * 288 + xw * 24 + y * 2;
        float wr = W[wb], wi = W[wb + 1];
        float a = xr[bb * 64 + i], cc = xi[bb * 64 + i];
        re += a * wr - cc * wi;
        im += a * wi + cc * wr;
    }
    Yh[(((long)bb * 64 + o) * 288 + m) * 2] = re;
    Yh[(((long)bb * 64 + o) * 288 + m) * 2 + 1] = im;
}

// inverse DFT + pointwise conv + bias + InstanceNorm + GELU, fused per (b, out-channel)
__global__ void __launch_bounds__(256) k_f3(const float* __restrict__ Yh, const float* __restrict__ x,
                                            const float* __restrict__ pwW, const float* __restrict__ pwb,
                                            float* __restrict__ xo) {
    int blk = blockIdx.x;
    int b = blk >> 6, o = blk & 63;
    int tid = threadIdx.x;   // 256
    __shared__ float yre[288], yim[288];
    __shared__ float Qre[64][12], Qim[64][12];
    __shared__ float yimg[4096];
    __shared__ float cs[64], sn[64];
    __shared__ float red[256];
    if (tid < 64) {
        double a = (2.0 * PI_ / 64.0) * (double)tid;
        cs[tid] = (float)cos(a);
        sn[tid] = (float)sin(a);
    }
    for (int t = tid; t < 288; t += 256) {
        yre[t] = Yh[((long)blk * 288 + t) * 2];
        yim[t] = Yh[((long)blk * 288 + t) * 2 + 1];
    }
    __syncthreads();
    for (int q = tid; q < 768; q += 256) {    // (h, c): complex ifft along rows (1/64 scale)
        int h = q / 12, c = q - 12 * h;
        float re = 0.f, im = 0.f;
#pragma unroll
        for (int xx = 0; xx < 24; xx++) {
            int r = (xx < 12) ? xx : (xx + 40);
            int k = (r * h) & 63;
            float wr = cs[k], wi = sn[k];
            float a = yre[xx * 12 + c], bb = yim[xx * 12 + c];
            re += a * wr - bb * wi;           // (a+ib)*e^{+i phi}
            im += a * wi + bb * wr;
        }
        Qre[h][c] = re * (1.0f / 64.0f);
        Qim[h][c] = im * (1.0f / 64.0f);
    }
    __syncthreads();
    float bias = pwb[o];
    for (int p = tid; p < 4096; p += 256) {
        int h = p >> 6, w = p & 63;
        float sp = Qre[h][0];                 // irfft along cols: DC imag dropped
#pragma unroll
        for (int c = 1; c < 12; c++) {
            int k = (c * w) & 63;
            sp += 2.0f * (Qre[h][c] * cs[k] - Qim[h][c] * sn[k]);
        }
        sp *= (1.0f / 64.0f);
        float acc = sp + bias;
        for (int i = 0; i < 64; i++)
            acc = fmaf(x[(((long)b * 64 + i) * 4096) + p], pwW[o * 64 + i], acc);
        yimg[p] = acc;
    }
    __syncthreads();
    float part = 0.f;
    for (int p = tid; p < 4096; p += 256) part += yimg[p];
    red[tid] = part;
    __syncthreads();
    for (int d = 128; d > 0; d >>= 1) { if (tid < d) red[tid] += red[tid + d]; __syncthreads(); }
    float mu = red[0] * (1.0f / 4096.0f);
    __syncthreads();
    float vp = 0.f;
    for (int p = tid; p < 4096; p += 256) { float dd = yimg[p] - mu; vp = fmaf(dd, dd, vp); }
    red[tid] = vp;
    __syncthreads();
    for (int d = 128; d > 0; d >>= 1) { if (tid < d) red[tid] += red[tid + d]; __syncthreads(); }
    float var = red[0] * (1.0f / 4096.0f);
    float inv = 1.0f / sqrtf(var + 1e-5f);
    for (int p = tid; p < 4096; p += 256) {
        float v = (yimg[p] - mu) * inv;
        xo[(long)blk * 4096 + p] = gelu_f(v);
    }
}

// ---------------------------------------------------------------- projection MLP (64 -> 64 -> 3)
__global__ void __launch_bounds__(256) k_proj(
    const float* __restrict__ y, const float* __restrict__ W1, const float* __restrict__ b1,
    const float* __restrict__ W2, const float* __restrict__ b2, float* __restrict__ out) {
    __shared__ __align__(16) float yr[4][64];
    __shared__ float h[4][64];
    int ql = threadIdx.x >> 6, j = threadIdx.x & 63;
    long node = (long)blockIdx.x * 4 + ql;
    yr[ql][j] = y[node * 64 + j];
    __syncthreads();
    float a = b1[j];
    for (int k = 0; k < 64; k += 4) {
        float w0 = W1[(k + 0) * 64 + j], w1 = W1[(k + 1) * 64 + j];
        float w2 = W1[(k + 2) * 64 + j], w3 = W1[(k + 3) * 64 + j];
        const float4 hv = *(const float4*)&yr[ql][k];
        a = fmaf(hv.x, w0, fmaf(hv.y, w1, fmaf(hv.z, w2, fmaf(hv.w, w3, a))));
    }
    h[ql][j] = gelu_f(a);
    __syncthreads();
    if (j < 3) {
        float a2 = b2[j];
        for (int k = 0; k < 64; k++) a2 = fmaf(h[ql][k], W2[k * 3 + j], a2);
        out[node * 3 + j] = a2;
    }
}

// ---------------------------------------------------------------- launch
extern "C" void kernel_launch(void* const* d_in, const int* in_sizes, int n_in,
                              void* d_out, int out_size, void* d_ws, size_t ws_size,
                              hipStream_t stream) {
    (void)in_sizes; (void)n_in; (void)out_size; (void)ws_size;
    const float* coords   = (const float*)d_in[0];
    const float* features = (const float*)d_in[1];
    const float* lift_W1 = (const float*)d_in[2];
    const float* lift_b1 = (const float*)d_in[3];
    const float* lift_W2 = (const float*)d_in[4];
    const float* lift_b2 = (const float*)d_in[5];
    const float* gin_W1 = (const float*)d_in[6];
    const float* gin_b1 = (const float*)d_in[7];
    const float* gin_W2 = (const float*)d_in[8];
    const float* gin_b2 = (const float*)d_in[9];
    const float* gin_W3 = (const float*)d_in[10];
    const float* gin_b3 = (const float*)d_in[11];
    const float* spec1 = (const float*)d_in[12];
    const float* spec2 = (const float*)d_in[13];
    const float* pw_W  = (const float*)d_in[14];
    const float* pw_b  = (const float*)d_in[15];
    const float* gout_W1 = (const float*)d_in[16];
    const float* gout_b1 = (const float*)d_in[17];
    const float* gout_W2 = (const float*)d_in[18];
    const float* gout_b2 = (const float*)d_in[19];
    const float* gout_W3 = (const float*)d_in[20];
    const float* gout_b3 = (const float*)d_in[21];
    const float* proj_W1 = (const float*)d_in[22];
    const float* proj_b1 = (const float*)d_in[23];
    const float* proj_W2 = (const float*)d_in[24];
    const float* proj_b2 = (const float*)d_in[25];

    char* ws = (char*)d_ws;
    size_t off = 0;
    auto alloc = [&](size_t bytes) -> char* {
        char* p = ws + off;
        off = (off + bytes + 255) & ~(size_t)255;
        return p;
    };
    float4* grid_pack = (float4*)alloc((size_t)NG * 16);
    float*  feat      = (float*)alloc((size_t)B_ * N_ * 64 * 4);
    int*    bin_cnt   = (int*)alloc((size_t)B_ * 4096 * 4);
    int*    bin_fill  = (int*)alloc((size_t)B_ * 4096 * 4);
    int*    bin_off   = (int*)alloc((size_t)B_ * 4097 * 4);
    float4* srt       = (float4*)alloc((size_t)B_ * N_ * 16);
    int*    idx_in    = (int*)alloc((size_t)B_ * NG * 16 * 4);
    float*  dist_in   = (float*)alloc((size_t)B_ * NG * 16 * 4);
    float*  lastd_in  = (float*)alloc((size_t)B_ * NG * 4);
    float*  sig_in    = (float*)alloc(256);
    float*  gout_buf  = (float*)alloc((size_t)B_ * NG * 64 * 4);
    float*  xb0       = (float*)alloc((size_t)B_ * 64 * NG * 4);
    float*  xb1       = (float*)alloc((size_t)B_ * 64 * NG * 4);
    float*  Xh        = (float*)alloc((size_t)B_ * 64 * 288 * 2 * 4);
    float*  Yh        = (float*)alloc((size_t)B_ * 64 * 288 * 2 * 4);
    float*  g2        = (float*)alloc((size_t)B_ * NG * 64 * 4);
    int*    idx_out   = (int*)alloc((size_t)B_ * N_ * 16 * 4);
    float*  dist_out  = (float*)alloc((size_t)B_ * N_ * 16 * 4);
    float*  lastd_out = (float*)alloc((size_t)B_ * N_ * 4);
    float*  sig_out   = (float*)alloc(256);
    float*  ybuf      = (float*)alloc((size_t)B_ * N_ * 64 * 4);

    hipMemsetAsync(bin_cnt, 0, (size_t)B_ * 4096 * 4, stream);
    hipMemsetAsync(bin_fill, 0, (size_t)B_ * 4096 * 4, stream);

    k_gridgen<<<NG / 256, 256, 0, stream>>>(grid_pack);
    k_lift<<<(B_ * N_) / 4, 256, 0, stream>>>(features, lift_W1, lift_b1, lift_W2, lift_b2, feat);
    k_bincount<<<(B_ * N_) / 256, 256, 0, stream>>>((const float2*)coords, bin_cnt);
    k_binscan<<<B_, 1024, 0, stream>>>(bin_cnt, bin_off);
    k_binscatter<<<(B_ * N_) / 256, 256, 0, stream>>>((const float2*)coords, bin_off, bin_fill, srt);
    k_knn_in<<<(B_ * NG) / 256, 256, 0, stream>>>(grid_pack, srt, bin_off, idx_in, dist_in, lastd_in);
    k_median<<<1, 1024, 0, stream>>>(lastd_in, B_ * NG, (B_ * NG - 1) / 2, sig_in);
    k_edge<0><<<(B_ * NG) / 4, 256, 0, stream>>>(idx_in, dist_in, sig_in, (const float2*)coords,
        grid_pack, feat, gin_W1, gin_b1, gin_W2, gin_b2, gin_W3, gin_b3, gout_buf, NG, N_);
    {
        dim3 g(64 / 32, NG / 32, B_); dim3 t(32, 8);
        k_transp<<<g, t, 0, stream>>>(gout_buf, xb0, NG, 64);
    }
    float* xc = xb0; float* xn = xb1;
    for (int d = 0; d < 3; d++) {
        k_f1<<<B_ * 64, 256, 0, stream>>>(xc, Xh);
        k_f2<<<288, 128, 0, stream>>>(Xh, spec1 + (size_t)d * 1179648, spec2 + (size_t)d * 1179648, Yh);
        k_f3<<<B_ * 64, 256, 0, stream>>>(Yh, xc, pw_W + (size_t)d * 4096, pw_b + (size_t)d * 64, xn);
        float* tmp = xc; xc = xn; xn = tmp;
    }
    {
        dim3 g(NG / 32, 64 / 32, B_); dim3 t(32, 8);
        k_transp<<<g, t, 0, stream>>>(xc, g2, 64, NG);
    }
    k_knn_out<<<(B_ * N_) / 256, 256, 0, stream>>>((const float2*)coords, grid_pack, idx_out, dist_out, lastd_out);
    k_median<<<1, 1024, 0, stream>>>(lastd_out, B_ * N_, (B_ * N_ - 1) / 2, sig_out);
    k_edge<1><<<(B_ * N_) / 4, 256, 0, stream>>>(idx_out, dist_out, sig_out, (const float2*)coords,
        grid_pack, g2, gout_W1, gout_b1, gout_W2, gout_b2, gout_W3, gout_b3, ybuf, N_, NG);
    k_proj<<<(B_ * N_) / 4, 256, 0, stream>>>(ybuf, proj_W1, proj_b1, proj_W2, proj_b2, (float*)d_out);
}

// Round 2
// 747.677 us; speedup vs baseline: 1.2821x; 1.2821x over previous
//
#include <hip/hip_runtime.h>
#include <math.h>

#define B_ 2
#define N_ 8192          // points per batch
#define G_ 64
#define NG 4096          // G*G latent grid points
#define WID_ 64
#define K_ 16
#define CIN_ 6
#define COUT_ 3
#define PI_ 3.14159265358979323846

typedef unsigned long long u64k;

// ---------------------------------------------------------------- helpers
__device__ __forceinline__ float gelu_f(float x) {
    // exact-erf GELU, matches jax.nn.gelu(approximate=False)
    return 0.5f * x * (1.0f + erff(x * 0.70710678118654752440f));
}
__device__ __forceinline__ int cellof(float v) {
    int c = (int)floorf((v + 1.0f) * 32.0f);   // 64 cells over [-1,1], h = 0.03125
    return min(63, max(0, c));
}
__device__ __forceinline__ u64k umin64(u64k a, u64k b) { return a < b ? a : b; }
__device__ __forceinline__ u64k umax64(u64k a, u64k b) { return a < b ? b : a; }
__device__ __forceinline__ u64k shflxor64(u64k v, int m) {
    return (u64k)__shfl_xor((long long)v, m, 64);
}
// full 64-lane bitonic sort, ascending (PAD = ~0ull sorts to top)
__device__ __forceinline__ void bsort64(u64k& key, int lane) {
#pragma unroll
    for (int sz = 2; sz <= 64; sz <<= 1) {
#pragma unroll
        for (int j = sz >> 1; j >= 1; j >>= 1) {
            u64k o = shflxor64(key, j);
            bool keep_min = ((lane & j) == 0) == ((lane & sz) == 0);
            key = keep_min ? umin64(key, o) : umax64(key, o);
        }
    }
}
// merge sorted batch `key` into running sorted `R` (both ascending, 64 lanes);
// result: R = smallest 64 of the union, sorted ascending
__device__ __forceinline__ void bmerge_into(u64k& R, u64k key, int lane) {
    u64k o = shflxor64(key, 63);          // reversed batch
    u64k L = umin64(R, o);                // bitonic sequence of lower half
#pragma unroll
    for (int j = 32; j >= 1; j >>= 1) {
        u64k t = shflxor64(L, j);
        L = ((lane & j) == 0) ? umin64(L, t) : umax64(L, t);
    }
    R = L;
}

// ---------------------------------------------------------------- grid gen
// numpy linspace semantics: computed in double, endpoint forced, cast to f32.
__global__ void k_gridgen(float4* gp) {
    int p = blockIdx.x * blockDim.x + threadIdx.x;
    if (p >= NG) return;
    int i = p >> 6, j = p & 63;
    double st = 2.0 / 63.0;
    float gx = (i == 63) ? 1.0f : (float)(-1.0 + st * (double)i);
    float gy = (j == 63) ? 1.0f : (float)(-1.0 + st * (double)j);
    float s2 = __fadd_rn(__fmul_rn(gx, gx), __fmul_rn(gy, gy));
    gp[p] = make_float4(gx, gy, s2, 0.f);
}

// ---------------------------------------------------------------- lift MLP
__global__ void __launch_bounds__(256) k_lift(
    const float* __restrict__ fin, const float* __restrict__ W1,
    const float* __restrict__ b1, const float* __restrict__ W2,
    const float* __restrict__ b2, float* __restrict__ fout) {
    __shared__ float xr[4][8];
    __shared__ __align__(16) float h[4][64];
    int ql = threadIdx.x >> 6, j = threadIdx.x & 63;
    int node = blockIdx.x * 4 + ql;      // < B_*N_
    if (j < CIN_) xr[ql][j] = fin[node * CIN_ + j];
    __syncthreads();
    float a = b1[j];
#pragma unroll
    for (int i = 0; i < CIN_; i++) a = fmaf(xr[ql][i], W1[i * 64 + j], a);
    h[ql][j] = gelu_f(a);
    __syncthreads();
    float a2 = b2[j];
    for (int k = 0; k < 64; k += 4) {
        float w0 = W2[(k + 0) * 64 + j], w1 = W2[(k + 1) * 64 + j];
        float w2 = W2[(k + 2) * 64 + j], w3 = W2[(k + 3) * 64 + j];
        const float4 hv = *(const float4*)&h[ql][k];
        a2 = fmaf(hv.x, w0, fmaf(hv.y, w1, fmaf(hv.z, w2, fmaf(hv.w, w3, a2))));
    }
    fout[node * 64 + j] = a2;
}

// ---------------------------------------------------------------- binning
__global__ void k_bincount(const float2* __restrict__ coords, int* __restrict__ cnt) {
    int t = blockIdx.x * blockDim.x + threadIdx.x;
    if (t >= B_ * N_) return;
    float2 c = coords[t];
    int b = t >> 13;
    int cell = cellof(c.x) * 64 + cellof(c.y);
    atomicAdd(&cnt[b * 4096 + cell], 1);
}
__global__ void k_binscan(const int* __restrict__ cnt, int* __restrict__ offs) {
    int b = blockIdx.x, t = threadIdx.x;    // 1024 threads
    __shared__ int s[1024];
    int4 v = ((const int4*)(cnt + b * 4096))[t];
    int sum = v.x + v.y + v.z + v.w;
    s[t] = sum;
    __syncthreads();
    for (int d = 1; d < 1024; d <<= 1) {
        int x = (t >= d) ? s[t - d] : 0;
        __syncthreads();
        s[t] += x;
        __syncthreads();
    }
    int incl = s[t], excl = incl - sum;
    int* ob = offs + b * 4097;
    ob[4 * t] = excl; ob[4 * t + 1] = excl + v.x;
    ob[4 * t + 2] = excl + v.x + v.y; ob[4 * t + 3] = excl + v.x + v.y + v.z;
    if (t == 1023) ob[4096] = incl;
}
__global__ void k_binscatter(const float2* __restrict__ coords, const int* __restrict__ offs,
                             int* __restrict__ fill, float4* __restrict__ srt) {
    int t = blockIdx.x * blockDim.x + threadIdx.x;
    if (t >= B_ * N_) return;
    float2 c = coords[t];
    int b = t >> 13, n = t & 8191;
    int cell = cellof(c.x) * 64 + cellof(c.y);
    int pos = offs[b * 4097 + cell] + atomicAdd(&fill[b * 4096 + cell], 1);
    float s2 = __fadd_rn(__fmul_rn(c.x, c.x), __fmul_rn(c.y, c.y));
    srt[b * N_ + pos] = make_float4(c.x, c.y, s2, __int_as_float(n));
}

// ---------------------------------------------------------------- kNN grid->points: one wave per query
__global__ void __launch_bounds__(256) k_knn_in(
    const float4* __restrict__ gp, const float4* __restrict__ srt,
    const int* __restrict__ offs, int* __restrict__ oidx,
    float* __restrict__ odist, float* __restrict__ lastd) {
    int lane = threadIdx.x & 63;
    int w = (blockIdx.x * blockDim.x + threadIdx.x) >> 6;   // wave-uniform query id
    int b = w >> 12, p = w & 4095;
    float4 q = gp[p];
    float qx = q.x, qy = q.y, q2 = q.z;
    int cqx = cellof(qx), cqy = cellof(qy);
    const float4* S = srt + b * N_;
    const int* OF = offs + b * 4097;

    u64k R = ~0ull;          // running sorted top-64 (ascending)
    u64k pend = ~0ull;       // pending batch
    int fill = 0;

    auto flush = [&]() {
        bsort64(pend, lane);
        bmerge_into(R, pend, lane);
        pend = ~0ull;
        fill = 0;
    };
    auto feed = [&](int s0, int s1) {
        int cnt = s1 - s0;
        while (cnt > 0) {
            int take = min(cnt, 64 - fill);
            int t = lane - fill;
            if (t >= 0 && t < take) {
                float4 sp = S[s0 + t];
                float dot = __fadd_rn(__fmul_rn(qx, sp.x), __fmul_rn(qy, sp.y));
                float d2 = __fsub_rn(__fadd_rn(q2, sp.z), 2.0f * dot);
                d2 = fmaxf(d2, 0.0f);
                pend = ((u64k)__float_as_uint(d2) << 32) | (unsigned)__float_as_int(sp.w);
            }
            fill += take; s0 += take; cnt -= take;
            if (fill == 64) flush();
        }
    };

    {   // initial 5x5 square (radius 2)
        int xa = max(cqx - 2, 0), xb = min(cqx + 2, 63);
        int ya = max(cqy - 2, 0), yb = min(cqy + 2, 63);
        for (int cx = xa; cx <= xb; cx++) feed(OF[cx * 64 + ya], OF[cx * 64 + yb + 1]);
    }
    int r = 2;
    while (true) {
        if (fill) flush();
        u64k T = (u64k)__shfl((long long)R, 15, 64);
        float d16 = __uint_as_float((unsigned)(T >> 32));    // NaN if <16 found -> continue
        float bm = (float)r * 0.03125f;                      // min dist of any unseen point
        if (d16 < bm * bm - 1e-5f) break;
        if (cqx - r <= 0 && cqx + r >= 63 && cqy - r <= 0 && cqy + r >= 63) break;
        r++;
        int ya = max(cqy - r, 0), yb = min(cqy + r, 63);
        if (cqx - r >= 0)  { int c0 = (cqx - r) * 64; feed(OF[c0 + ya], OF[c0 + yb + 1]); }
        if (cqx + r <= 63) { int c0 = (cqx + r) * 64; feed(OF[c0 + ya], OF[c0 + yb + 1]); }
        int xa2 = max(cqx - r + 1, 0), xb2 = min(cqx + r - 1, 63);
        for (int cx = xa2; cx <= xb2; cx++) {
            if (cqy - r >= 0)  { int cc = cx * 64 + cqy - r; feed(OF[cc], OF[cc + 1]); }
            if (cqy + r <= 63) { int cc = cx * 64 + cqy + r; feed(OF[cc], OF[cc + 1]); }
        }
    }
    if (lane < 16) {
        float d2 = __uint_as_float((unsigned)(R >> 32));
        float d = sqrtf(d2);
        oidx[w * 16 + lane] = (int)(unsigned)(R & 0xffffffffu);
        odist[w * 16 + lane] = d;
        if (lane == 15) lastd[w] = d;
    }
}

// ---------------------------------------------------------------- kNN points->grid: one wave per query, fixed 8x8 lattice box
__global__ void __launch_bounds__(256) k_knn_out(
    const float2* __restrict__ coords, const float4* __restrict__ gp,
    int* __restrict__ oidx, float* __restrict__ odist, float* __restrict__ lastd) {
    int lane = threadIdx.x & 63;
    int w = (blockIdx.x * blockDim.x + threadIdx.x) >> 6;   // 0..B_*N_-1
    float2 c = coords[w];
    float qx = c.x, qy = c.y;
    float q2 = __fadd_rn(__fmul_rn(qx, qx), __fmul_rn(qy, qy));
    int i0 = (int)floorf((qx + 1.0f) * 31.5f);
    int j0 = (int)floorf((qy + 1.0f) * 31.5f);
    int li = min(max(i0 - 3, 0), 56);
    int lj = min(max(j0 - 3, 0), 56);
    int p = (li + (lane >> 3)) * 64 + (lj + (lane & 7));
    float4 sp = gp[p];
    float dot = __fadd_rn(__fmul_rn(qx, sp.x), __fmul_rn(qy, sp.y));
    float d2 = fmaxf(__fsub_rn(__fadd_rn(q2, sp.z), 2.0f * dot), 0.0f);
    u64k key = ((u64k)__float_as_uint(d2) << 32) | (unsigned)p;
    bsort64(key, lane);
    if (lane < 16) {
        float dd = sqrtf(__uint_as_float((unsigned)(key >> 32)));
        oidx[w * 16 + lane] = (int)(unsigned)(key & 0xffffffffu);
        odist[w * 16 + lane] = dd;
        if (lane == 15) lastd[w] = dd;
    }
}

// ---------------------------------------------------------------- exact lower-median via radix select on float bits (all vals >= 0)
__global__ void k_median(const float* __restrict__ vals, int n, int rank, float* __restrict__ sig) {
    __shared__ unsigned hist[256];
    __shared__ unsigned selp;
    __shared__ int selr;
    unsigned prefix = 0; int r = rank;
    for (int lvl = 3; lvl >= 0; --lvl) {
        for (int i = threadIdx.x; i < 256; i += blockDim.x) hist[i] = 0;
        __syncthreads();
        unsigned mhi = (lvl == 3) ? 0u : (0xFFFFFFFFu << ((lvl + 1) * 8));
        for (int i = threadIdx.x; i < n; i += blockDim.x) {
            unsigned u = __float_as_uint(vals[i]);
            if ((u & mhi) == prefix) atomicAdd(&hist[(u >> (lvl * 8)) & 255], 1u);
        }
        __syncthreads();
        if (threadIdx.x == 0) {
            int rr = r; unsigned bsel = 255;
            for (unsigned bb = 0; bb < 256; bb++) {
                unsigned cc = hist[bb];
                if (rr < (int)cc) { bsel = bb; break; }
                rr -= cc;
            }
            selp = prefix | (bsel << (lvl * 8));
            selr = rr;
        }
        __syncthreads();
        prefix = selp; r = selr;
        __syncthreads();
    }
    if (threadIdx.x == 0) *sig = fmaxf(__uint_as_float(prefix), 1e-6f);
}

// ---------------------------------------------------------------- edge MLP + weighted aggregation
// One wave (64 lanes) per 8 queries: lane = (q_local<<3) | jg, each lane owns
// 8 output features (j = jg*8..jg*8+7) and accumulates 8 edges at a time.
// LDS row stride per query padded (+4 floats) so the 8 queries' ds_read_b128
// addresses land on distinct 4-bank groups -> conflict-free full-BW reads.
// MODE 0: queries = grid, sources = coords, feats rows = N_ per batch
// MODE 1: queries = coords, sources = grid,  feats rows = NG per batch
template <int MODE>
__global__ void __launch_bounds__(64, 1) k_edge(
    const int* __restrict__ idxb, const float* __restrict__ distb, const float* __restrict__ sigp,
    const float2* __restrict__ coords, const float4* __restrict__ gp,
    const float* __restrict__ feats,
    const float* __restrict__ W1, const float* __restrict__ b1,
    const float* __restrict__ W2, const float* __restrict__ b2,
    const float* __restrict__ W3, const float* __restrict__ b3,
    float* __restrict__ outb, int Nq, int srcRows) {
    __shared__ __align__(16) float eA[8][16 * 72 + 4];   // 8 q x 16 edge-rows x 72
    __shared__ float wts[8][16];
    __shared__ int   nidx[8][16];
    const int lane = threadIdx.x;          // 0..63
    const int qw = blockIdx.x * 8;         // first query handled by this wave
    const float sig = *sigp;

    // ---- metadata + geometry (128 (q,e) pairs)
    for (int it = 0; it < 2; it++) {
        int ent = it * 64 + lane;
        int q = ent >> 4, e = ent & 15;
        int gq = qw + q;
        int b = gq / Nq, p = gq - b * Nq;
        int si = idxb[gq * 16 + e];
        float d = distb[gq * 16 + e];
        nidx[q][e] = si;
        wts[q][e] = expf(-d / sig);
        float qx, qy, sx, sy;
        if (MODE == 0) {
            float4 g = gp[p]; qx = g.x; qy = g.y;
            float2 cc = coords[(long)b * srcRows + si]; sx = cc.x; sy = cc.y;
        } else {
            float2 cc = coords[(long)b * Nq + p]; qx = cc.x; qy = cc.y;
            float4 g = gp[si]; sx = g.x; sy = g.y;
        }
        float* row = &eA[q][e * 72];
        row[0] = qx; row[1] = qy; row[2] = sx; row[3] = sy;
        row[4] = qx - sx; row[5] = qy - sy; row[6] = d; row[7] = 0.f;
    }
    __syncthreads();
    // ---- feats gather: 128 rows x 16 float4
    for (int it = 0; it < 32; it++) {
        int slot = it * 64 + lane;
        int rowi = slot >> 4, f4 = slot & 15;
        int q = rowi >> 4, e = rowi & 15;
        int gq = qw + q;
        int b = gq / Nq;
        int si = nidx[q][e];
        const float4 v = *(const float4*)&feats[((long)b * srcRows + si) * 64 + f4 * 4];
        *(float4*)&eA[q][e * 72 + 8 + f4 * 4] = v;
    }
    __syncthreads();

    const int ql = lane >> 3, jg = lane & 7, j0 = jg * 8;
    float sumw = 0.f;
    for (int e = 0; e < 16; e++) sumw += wts[ql][e];
    float so[8];
#pragma unroll
    for (int jj = 0; jj < 8; jj++) so[jj] = 0.f;

    for (int eh = 0; eh < 2; eh++) {
        const int e0 = eh * 8;
        float acc[8][8];
        // ---------- layer 1: x[0..71] (x[7]==0, W1 rows skip slot 7)
        {
            float4 bv0 = *(const float4*)&b1[j0], bv1 = *(const float4*)&b1[j0 + 4];
            float bj[8] = {bv0.x, bv0.y, bv0.z, bv0.w, bv1.x, bv1.y, bv1.z, bv1.w};
#pragma unroll
            for (int e = 0; e < 8; e++)
#pragma unroll
                for (int jj = 0; jj < 8; jj++) acc[e][jj] = bj[jj];
            for (int c = 0; c < 18; c++) {
                float w[4][8];
#pragma unroll
                for (int rr = 0; rr < 4; rr++) {
                    int t = c * 4 + rr;
                    int wrow = t - (t > 6);
                    float4 a = *(const float4*)&W1[wrow * 64 + j0];
                    float4 bq = *(const float4*)&W1[wrow * 64 + j0 + 4];
                    if (t == 7) { a = make_float4(0.f, 0.f, 0.f, 0.f); bq = a; }
                    w[rr][0] = a.x; w[rr][1] = a.y; w[rr][2] = a.z; w[rr][3] = a.w;
                    w[rr][4] = bq.x; w[rr][5] = bq.y; w[rr][6] = bq.z; w[rr][7] = bq.w;
                }
#pragma unroll
                for (int e = 0; e < 8; e++) {
                    const float4 xv = *(const float4*)&eA[ql][(e0 + e) * 72 + c * 4];
                    const float xs[4] = {xv.x, xv.y, xv.z, xv.w};
#pragma unroll
                    for (int rr = 0; rr < 4; rr++)
#pragma unroll
                        for (int jj = 0; jj < 8; jj++)
                            acc[e][jj] = fmaf(xs[rr], w[rr][jj], acc[e][jj]);
                }
            }
        }
        __syncthreads();
#pragma unroll
        for (int e = 0; e < 8; e++) {
            float4 h0 = make_float4(gelu_f(acc[e][0]), gelu_f(acc[e][1]),
                                    gelu_f(acc[e][2]), gelu_f(acc[e][3]));
            float4 h1 = make_float4(gelu_f(acc[e][4]), gelu_f(acc[e][5]),
                                    gelu_f(acc[e][6]), gelu_f(acc[e][7]));
            *(float4*)&eA[ql][(e0 + e) * 72 + j0] = h0;
            *(float4*)&eA[ql][(e0 + e) * 72 + j0 + 4] = h1;
        }
        __syncthreads();
        // ---------- layer 2: x[0..63]
        {
            float4 bv0 = *(const float4*)&b2[j0], bv1 = *(const float4*)&b2[j0 + 4];
            float bj[8] = {bv0.x, bv0.y, bv0.z, bv0.w, bv1.x, bv1.y, bv1.z, bv1.w};
#pragma unroll
            for (int e = 0; e < 8; e++)
#pragma unroll
                for (int jj = 0; jj < 8; jj++) acc[e][jj] = bj[jj];
            for (int c = 0; c < 16; c++) {
                float w[4][8];
#pragma unroll
                for (int rr = 0; rr < 4; rr++) {
                    float4 a = *(const float4*)&W2[(c * 4 + rr) * 64 + j0];
                    float4 bq = *(const float4*)&W2[(c * 4 + rr) * 64 + j0 + 4];
                    w[rr][0] = a.x; w[rr][1] = a.y; w[rr][2] = a.z; w[rr][3] = a.w;
                    w[rr][4] = bq.x; w[rr][5] = bq.y; w[rr][6] = bq.z; w[rr][7] = bq.w;
                }
#pragma unroll
                for (int e = 0; e < 8; e++) {
                    const float4 xv = *(const float4*)&eA[ql][(e0 + e) * 72 + c * 4];
                    const float xs[4] = {xv.x, xv.y, xv.z, xv.w};
#pragma unroll
                    for (int rr = 0; rr < 4; rr++)
#pragma unroll
                        for (int jj = 0; jj < 8; jj++)
                            acc[e][jj] = fmaf(xs[rr], w[rr][jj], acc[e][jj]);
                }
            }
        }
        __syncthreads();
#pragma unroll
        for (int e = 0; e < 8; e++) {
            float4 h0 = make_float4(gelu_f(acc[e][0]), gelu_f(acc[e][1]),
                                    gelu_f(acc[e][2]), gelu_f(acc[e][3]));
            float4 h1 = make_float4(gelu_f(acc[e][4]), gelu_f(acc[e][5]),
                                    gelu_f(acc[e][6]), gelu_f(acc[e][7]));
            *(float4*)&eA[ql][(e0 + e) * 72 + j0] = h0;
            *(float4*)&eA[ql][(e0 + e) * 72 + j0 + 4] = h1;
        }
        __syncthreads();
        // ---------- layer 3: x[0..63], no activation; accumulate weighted sum
        {
            float4 bv0 = *(const float4*)&b3[j0], bv1 = *(const float4*)&b3[j0 + 4];
            float bj[8] = {bv0.x, bv0.y, bv0.z, bv0.w, bv1.x, bv1.y, bv1.z, bv1.w};
#pragma unroll
            for (int e = 0; e < 8; e++)
#pragma unroll
                for (int jj = 0; jj < 8; jj++) acc[e][jj] = bj[jj];
            for (int c = 0; c < 16; c++) {
                float w[4][8];
#pragma unroll
                for (int rr = 0; rr < 4; rr++) {
                    float4 a = *(const float4*)&W3[(c * 4 + rr) * 64 + j0];
                    float4 bq = *(const float4*)&W3[(c * 4 + rr) * 64 + j0 + 4];
                    w[rr][0] = a.x; w[rr][1] = a.y; w[rr][2] = a.z; w[rr][3] = a.w;
                    w[rr][4] = bq.x; w[rr][5] = bq.y; w[rr][6] = bq.z; w[rr][7] = bq.w;
                }
#pragma unroll
                for (int e = 0; e < 8; e++) {
                    const float4 xv = *(const float4*)&eA[ql][(e0 + e) * 72 + c * 4];
                    const float xs[4] = {xv.x, xv.y, xv.z, xv.w};
#pragma unroll
                    for (int rr = 0; rr < 4; rr++)
#pragma unroll
                        for (int jj = 0; jj < 8; jj++)
                            acc[e][jj] = fmaf(xs[rr], w[rr][jj], acc[e][jj]);
                }
            }
#pragma unroll
            for (int e = 0; e < 8; e++) {
                float wv = wts[ql][e0 + e];
#pragma unroll
                for (int jj = 0; jj < 8; jj++) so[jj] = fmaf(wv, acc[e][jj], so[jj]);
            }
        }
        __syncthreads();
    }
    float den = fmaxf(sumw, 1e-6f);
    int gq = qw + ql;
    float4 o0 = make_float4(so[0] / den, so[1] / den, so[2] / den, so[3] / den);
    float4 o1 = make_float4(so[4] / den, so[5] / den, so[6] / den, so[7] / den);
    *(float4*)&outb[(long)gq * 64 + j0] = o0;
    *(float4*)&outb[(long)gq * 64 + j0 + 4] = o1;
}

// ---------------------------------------------------------------- transpose (B,R,C) -> (B,C,R)
__global__ void k_transp(const float* __restrict__ src, float* __restrict__ dst, int R, int C) {
    __shared__ float t[32][33];
    int b = blockIdx.z;
    int c0 = blockIdx.x * 32, r0 = blockIdx.y * 32;
    int tx = threadIdx.x, ty0 = threadIdx.y;    // (32,8)
    for (int yy = ty0; yy < 32; yy += 8) {
        int r = r0 + yy, c = c0 + tx;
        if (r < R && c < C) t[yy][tx] = src[((long)b * R + r) * C + c];
    }
    __syncthreads();
    for (int yy = ty0; yy < 32; yy += 8) {
        int c = c0 + yy, r = r0 + tx;
        if (r < R && c < C) dst[((long)b * C + c) * R + r] = t[tx][yy];
    }
}

// ---------------------------------------------------------------- FNO: truncated forward DFT (rows 0..11 & 52..63, cols 0..11)
__global__ void __launch_bounds__(256) k_f1(const float* __restrict__ x, float* __restrict__ Xh) {
    int blk = blockIdx.x;    // b*64 + ch
    int tid = threadIdx.x;   // 256
    __shared__ float img[4096];
    __shared__ float Tre[64][12], Tim[64][12];
    __shared__ float cs[64], sn[64];
    if (tid < 64) {
        double a = (2.0 * PI_ / 64.0) * (double)tid;
        cs[tid] = (float)cos(a);
        sn[tid] = (float)sin(a);
    }
    for (int p = tid; p < 4096; p += 256) img[p] = x[(long)blk * 4096 + p];
    __syncthreads();
    for (int o = tid; o < 768; o += 256) {       // (h, c)
        int h = o / 12, c = o - 12 * h;
        float re = 0.f, im = 0.f;
        for (int w = 0; w < 64; w++) {
            float v = img[h * 64 + w];
            int k = (c * w) & 63;
            re = fmaf(v, cs[k], re);
            im = fmaf(-v, sn[k], im);
        }
        Tre[h][c] = re; Tim[h][c] = im;
    }
    __syncthreads();
    for (int o = tid; o < 288; o += 256) {       // (x24, c12)
        int xx = o / 12, c = o - 12 * xx;
        int r = (xx < 12) ? xx : (xx + 40);
        float re = 0.f, im = 0.f;
        for (int h = 0; h < 64; h++) {
            int k = (r * h) & 63;
            float cr = cs[k], si = sn[k];
            float a = Tre[h][c], bb = Tim[h][c];
            re += a * cr + bb * si;              // (a+ib)*e^{-i phi}
            im += bb * cr - a * si;
        }
        Xh[((long)blk * 288 + o) * 2] = re;
        Xh[((long)blk * 288 + o) * 2 + 1] = im;
    }
}

// mode-mix: Yhat[b,o,m] = sum_i Wc[i,o,m] * Xhat[b,i,m]
__global__ void k_f2(const float* __restrict__ Xh, const float* __restrict__ s1,
                     const float* __restrict__ s2, float* __restrict__ Yh) {
    int m = blockIdx.x;                  // 0..287
    int xx = m / 12, y = m - 12 * xx;
    const float* W; int xw;
    if (xx < 12) { W = s1; xw = xx; } else { W = s2; xw = xx - 12; }
    __shared__ float xr[128], xi[128];
    int tid = threadIdx.x;               // 128
    {
        int bb = tid >> 6, i = tid & 63;
        xr[tid] = Xh[(((long)bb * 64 + i) * 288 + m) * 2];
        xi[tid] = Xh[(((long)bb * 64 + i) * 288 + m) * 2 + 1];
    }
    __syncthreads();
    int bb = tid >> 6, o = tid & 63;
    float re = 0.f, im = 0.f;
    for (int i = 0; i < 64; i++) {
        long wb = (long)i * 18432 + (long)o * 288 + xw * 24 + y * 2;
        float wr = W[wb], wi = W[wb + 1];
        float a = xr[bb * 64 + i], cc = xi[bb * 64 + i];
        re += a * wr - cc * wi;
        im += a * wi + cc * wr;
    }
    Yh[(((long)bb * 64 + o) * 288 + m) * 2] = re;
    Yh[(((long)bb * 64 + o) * 288 + m) * 2 + 1] = im;
}

// inverse DFT + pointwise conv + bias + InstanceNorm + GELU, fused per (b, out-channel)
__global__ void __launch_bounds__(256) k_f3(const float* __restrict__ Yh, const float* __restrict__ x,
                                            const float* __restrict__ pwW, const float* __restrict__ pwb,
                                            float* __restrict__ xo) {
    int blk = blockIdx.x;
    int b = blk >> 6, o = blk & 63;
    int tid = threadIdx.x;   // 256
    __shared__ float yre[288], yim[288];
    __shared__ float Qre[64][12], Qim[64][12];
    __shared__ float yimg[4096];
    __shared__ float cs[64], sn[64];
    __shared__ float red[256];
    if (tid < 64) {
        double a = (2.0 * PI_ / 64.0) * (double)tid;
        cs[tid] = (float)cos(a);
        sn[tid] = (float)sin(a);
    }
    for (int t = tid; t < 288; t += 256) {
        yre[t] = Yh[((long)blk * 288 + t) * 2];
        yim[t] = Yh[((long)blk * 288 + t) * 2 + 1];
    }
    __syncthreads();
    for (int q = tid; q < 768; q += 256) {    // (h, c): complex ifft along rows (1/64 scale)
        int h = q / 12, c = q - 12 * h;
        float re = 0.f, im = 0.f;
#pragma unroll
        for (int xx = 0; xx < 24; xx++) {
            int r = (xx < 12) ? xx : (xx + 40);
            int k = (r * h) & 63;
            float wr = cs[k], wi = sn[k];
            float a = yre[xx * 12 + c], bb = yim[xx * 12 + c];
            re += a * wr - bb * wi;           // (a+ib)*e^{+i phi}
            im += a * wi + bb * wr;
        }
        Qre[h][c] = re * (1.0f / 64.0f);
        Qim[h][c] = im * (1.0f / 64.0f);
    }
    __syncthreads();
    float bias = pwb[o];
    for (int p = tid; p < 4096; p += 256) {
        int h = p >> 6, w = p & 63;
        float sp = Qre[h][0];                 // irfft along cols: DC imag dropped
#pragma unroll
        for (int c = 1; c < 12; c++) {
            int k = (c * w) & 63;
            sp += 2.0f * (Qre[h][c] * cs[k] - Qim[h][c] * sn[k]);
        }
        sp *= (1.0f / 64.0f);
        float acc = sp + bias;
        for (int i = 0; i < 64; i++)
            acc = fmaf(x[(((long)b * 64 + i) * 4096) + p], pwW[o * 64 + i], acc);
        yimg[p] = acc;
    }
    __syncthreads();
    float part = 0.f;
    for (int p = tid; p < 4096; p += 256) part += yimg[p];
    red[tid] = part;
    __syncthreads();
    for (int d = 128; d > 0; d >>= 1) { if (tid < d) red[tid] += red[tid + d]; __syncthreads(); }
    float mu = red[0] * (1.0f / 4096.0f);
    __syncthreads();
    float vp = 0.f;
    for (int p = tid; p < 4096; p += 256) { float dd = yimg[p] - mu; vp = fmaf(dd, dd, vp); }
    red[tid] = vp;
    __syncthreads();
    for (int d = 128; d > 0; d >>= 1) { if (tid < d) red[tid] += red[tid + d]; __syncthreads(); }
    float var = red[0] * (1.0f / 4096.0f);
    float inv = 1.0f / sqrtf(var + 1e-5f);
    for (int p = tid; p < 4096; p += 256) {
        float v = (yimg[p] - mu) * inv;
        xo[(long)blk * 4096 + p] = gelu_f(v);
    }
}

// ---------------------------------------------------------------- projection MLP (64 -> 64 -> 3)
__global__ void __launch_bounds__(256) k_proj(
    const float* __restrict__ y, const float* __restrict__ W1, const float* __restrict__ b1,
    const float* __restrict__ W2, const float* __restrict__ b2, float* __restrict__ out) {
    __shared__ __align__(16) float yr[4][64];
    __shared__ float h[4][64];
    int ql = threadIdx.x >> 6, j = threadIdx.x & 63;
    long node = (long)blockIdx.x * 4 + ql;
    yr[ql][j] = y[node * 64 + j];
    __syncthreads();
    float a = b1[j];
    for (int k = 0; k < 64; k += 4) {
        float w0 = W1[(k + 0) * 64 + j], w1 = W1[(k + 1) * 64 + j];
        float w2 = W1[(k + 2) * 64 + j], w3 = W1[(k + 3) * 64 + j];
        const float4 hv = *(const float4*)&yr[ql][k];
        a = fmaf(hv.x, w0, fmaf(hv.y, w1, fmaf(hv.z, w2, fmaf(hv.w, w3, a))));
    }
    h[ql][j] = gelu_f(a);
    __syncthreads();
    if (j < 3) {
        float a2 = b2[j];
        for (int k = 0; k < 64; k++) a2 = fmaf(h[ql][k], W2[k * 3 + j], a2);
        out[node * 3 + j] = a2;
    }
}

// ---------------------------------------------------------------- launch
extern "C" void kernel_launch(void* const* d_in, const int* in_sizes, int n_in,
                              void* d_out, int out_size, void* d_ws, size_t ws_size,
                              hipStream_t stream) {
    (void)in_sizes; (void)n_in; (void)out_size; (void)ws_size;
    const float* coords   = (const float*)d_in[0];
    const float* features = (const float*)d_in[1];
    const float* lift_W1 = (const float*)d_in[2];
    const float* lift_b1 = (const float*)d_in[3];
    const float* lift_W2 = (const float*)d_in[4];
    const float* lift_b2 = (const float*)d_in[5];
    const float* gin_W1 = (const float*)d_in[6];
    const float* gin_b1 = (const float*)d_in[7];
    const float* gin_W2 = (const float*)d_in[8];
    const float* gin_b2 = (const float*)d_in[9];
    const float* gin_W3 = (const float*)d_in[10];
    const float* gin_b3 = (const float*)d_in[11];
    const float* spec1 = (const float*)d_in[12];
    const float* spec2 = (const float*)d_in[13];
    const float* pw_W  = (const float*)d_in[14];
    const float* pw_b  = (const float*)d_in[15];
    const float* gout_W1 = (const float*)d_in[16];
    const float* gout_b1 = (const float*)d_in[17];
    const float* gout_W2 = (const float*)d_in[18];
    const float* gout_b2 = (const float*)d_in[19];
    const float* gout_W3 = (const float*)d_in[20];
    const float* gout_b3 = (const float*)d_in[21];
    const float* proj_W1 = (const float*)d_in[22];
    const float* proj_b1 = (const float*)d_in[23];
    const float* proj_W2 = (const float*)d_in[24];
    const float* proj_b2 = (const float*)d_in[25];

    char* ws = (char*)d_ws;
    size_t off = 0;
    auto alloc = [&](size_t bytes) -> char* {
        char* p = ws + off;
        off = (off + bytes + 255) & ~(size_t)255;
        return p;
    };
    float4* grid_pack = (float4*)alloc((size_t)NG * 16);
    float*  feat      = (float*)alloc((size_t)B_ * N_ * 64 * 4);
    int*    bin_cnt   = (int*)alloc((size_t)B_ * 4096 * 4);
    int*    bin_fill  = (int*)alloc((size_t)B_ * 4096 * 4);
    int*    bin_off   = (int*)alloc((size_t)B_ * 4097 * 4);
    float4* srt       = (float4*)alloc((size_t)B_ * N_ * 16);
    int*    idx_in    = (int*)alloc((size_t)B_ * NG * 16 * 4);
    float*  dist_in   = (float*)alloc((size_t)B_ * NG * 16 * 4);
    float*  lastd_in  = (float*)alloc((size_t)B_ * NG * 4);
    float*  sig_in    = (float*)alloc(256);
    float*  gout_buf  = (float*)alloc((size_t)B_ * NG * 64 * 4);
    float*  xb0       = (float*)alloc((size_t)B_ * 64 * NG * 4);
    float*  xb1       = (float*)alloc((size_t)B_ * 64 * NG * 4);
    float*  Xh        = (float*)alloc((size_t)B_ * 64 * 288 * 2 * 4);
    float*  Yh        = (float*)alloc((size_t)B_ * 64 * 288 * 2 * 4);
    float*  g2        = (float*)alloc((size_t)B_ * NG * 64 * 4);
    int*    idx_out   = (int*)alloc((size_t)B_ * N_ * 16 * 4);
    float*  dist_out  = (float*)alloc((size_t)B_ * N_ * 16 * 4);
    float*  lastd_out = (float*)alloc((size_t)B_ * N_ * 4);
    float*  sig_out   = (float*)alloc(256);
    float*  ybuf      = (float*)alloc((size_t)B_ * N_ * 64 * 4);

    hipMemsetAsync(bin_cnt, 0, (size_t)B_ * 4096 * 4, stream);
    hipMemsetAsync(bin_fill, 0, (size_t)B_ * 4096 * 4, stream);

    k_gridgen<<<NG / 256, 256, 0, stream>>>(grid_pack);
    k_lift<<<(B_ * N_) / 4, 256, 0, stream>>>(features, lift_W1, lift_b1, lift_W2, lift_b2, feat);
    k_bincount<<<(B_ * N_) / 256, 256, 0, stream>>>((const float2*)coords, bin_cnt);
    k_binscan<<<B_, 1024, 0, stream>>>(bin_cnt, bin_off);
    k_binscatter<<<(B_ * N_) / 256, 256, 0, stream>>>((const float2*)coords, bin_off, bin_fill, srt);
    k_knn_in<<<(B_ * NG * 64) / 256, 256, 0, stream>>>(grid_pack, srt, bin_off, idx_in, dist_in, lastd_in);
    k_median<<<1, 1024, 0, stream>>>(lastd_in, B_ * NG, (B_ * NG - 1) / 2, sig_in);
    k_edge<0><<<(B_ * NG) / 8, 64, 0, stream>>>(idx_in, dist_in, sig_in, (const float2*)coords,
        grid_pack, feat, gin_W1, gin_b1, gin_W2, gin_b2, gin_W3, gin_b3, gout_buf, NG, N_);
    {
        dim3 g(64 / 32, NG / 32, B_); dim3 t(32, 8);
        k_transp<<<g, t, 0, stream>>>(gout_buf, xb0, NG, 64);
    }
    float* xc = xb0; float* xn = xb1;
    for (int d = 0; d < 3; d++) {
        k_f1<<<B_ * 64, 256, 0, stream>>>(xc, Xh);
        k_f2<<<288, 128, 0, stream>>>(Xh, spec1 + (size_t)d * 1179648, spec2 + (size_t)d * 1179648, Yh);
        k_f3<<<B_ * 64, 256, 0, stream>>>(Yh, xc, pw_W + (size_t)d * 4096, pw_b + (size_t)d * 64, xn);
        float* tmp = xc; xc = xn; xn = tmp;
    }
    {
        dim3 g(NG / 32, 64 / 32, B_); dim3 t(32, 8);
        k_transp<<<g, t, 0, stream>>>(xc, g2, 64, NG);
    }
    k_knn_out<<<(B_ * N_ * 64) / 256, 256, 0, stream>>>((const float2*)coords, grid_pack, idx_out, dist_out, lastd_out);
    k_median<<<1, 1024, 0, stream>>>(lastd_out, B_ * N_, (B_ * N_ - 1) / 2, sig_out);
    k_edge<1><<<(B_ * N_) / 8, 64, 0, stream>>>(idx_out, dist_out, sig_out, (const float2*)coords,
        grid_pack, g2, gout_W1, gout_b1, gout_W2, gout_b2, gout_W3, gout_b3, ybuf, N_, NG);
    k_proj<<<(B_ * N_) / 4, 256, 0, stream>>>(ybuf, proj_W1, proj_b1, proj_W2, proj_b2, (float*)d_out);
}

// Round 3
// 722.545 us; speedup vs baseline: 1.3266x; 1.0348x over previous
//
#include <hip/hip_runtime.h>
#include <math.h>

#define B_ 2
#define N_ 8192          // points per batch
#define G_ 64
#define NG 4096          // G*G latent grid points
#define WID_ 64
#define K_ 16
#define CIN_ 6
#define COUT_ 3
#define PI_ 3.14159265358979323846

typedef unsigned long long u64k;

// ---------------------------------------------------------------- helpers
__device__ __forceinline__ float gelu_f(float x) {
    // exact-erf GELU, matches jax.nn.gelu(approximate=False)
    return 0.5f * x * (1.0f + erff(x * 0.70710678118654752440f));
}
__device__ __forceinline__ int cellof(float v) {
    int c = (int)floorf((v + 1.0f) * 32.0f);   // 64 cells over [-1,1], h = 0.03125
    return min(63, max(0, c));
}
__device__ __forceinline__ u64k umin64(u64k a, u64k b) { return a < b ? a : b; }
__device__ __forceinline__ u64k umax64(u64k a, u64k b) { return a < b ? b : a; }
__device__ __forceinline__ u64k shflxor64(u64k v, int m) {
    return (u64k)__shfl_xor((long long)v, m, 64);
}
// full 64-lane bitonic sort, ascending (PAD = ~0ull sorts to top)
__device__ __forceinline__ void bsort64(u64k& key, int lane) {
#pragma unroll
    for (int sz = 2; sz <= 64; sz <<= 1) {
#pragma unroll
        for (int j = sz >> 1; j >= 1; j >>= 1) {
            u64k o = shflxor64(key, j);
            bool keep_min = ((lane & j) == 0) == ((lane & sz) == 0);
            key = keep_min ? umin64(key, o) : umax64(key, o);
        }
    }
}
// merge sorted batch `key` into running sorted `R` (both ascending, 64 lanes);
// result: R = smallest 64 of the union, sorted ascending
__device__ __forceinline__ void bmerge_into(u64k& R, u64k key, int lane) {
    u64k o = shflxor64(key, 63);          // reversed batch
    u64k L = umin64(R, o);                // bitonic sequence of lower half
#pragma unroll
    for (int j = 32; j >= 1; j >>= 1) {
        u64k t = shflxor64(L, j);
        L = ((lane & j) == 0) ? umin64(L, t) : umax64(L, t);
    }
    R = L;
}

// ---------------------------------------------------------------- grid gen
// numpy linspace semantics: computed in double, endpoint forced, cast to f32.
__global__ void k_gridgen(float4* gp) {
    int p = blockIdx.x * blockDim.x + threadIdx.x;
    if (p >= NG) return;
    int i = p >> 6, j = p & 63;
    double st = 2.0 / 63.0;
    float gx = (i == 63) ? 1.0f : (float)(-1.0 + st * (double)i);
    float gy = (j == 63) ? 1.0f : (float)(-1.0 + st * (double)j);
    float s2 = __fadd_rn(__fmul_rn(gx, gx), __fmul_rn(gy, gy));
    gp[p] = make_float4(gx, gy, s2, 0.f);
}

// ---------------------------------------------------------------- lift MLP
__global__ void __launch_bounds__(256) k_lift(
    const float* __restrict__ fin, const float* __restrict__ W1,
    const float* __restrict__ b1, const float* __restrict__ W2,
    const float* __restrict__ b2, float* __restrict__ fout) {
    __shared__ float xr[4][8];
    __shared__ __align__(16) float h[4][64];
    int ql = threadIdx.x >> 6, j = threadIdx.x & 63;
    int node = blockIdx.x * 4 + ql;      // < B_*N_
    if (j < CIN_) xr[ql][j] = fin[node * CIN_ + j];
    __syncthreads();
    float a = b1[j];
#pragma unroll
    for (int i = 0; i < CIN_; i++) a = fmaf(xr[ql][i], W1[i * 64 + j], a);
    h[ql][j] = gelu_f(a);
    __syncthreads();
    float a2 = b2[j];
    for (int k = 0; k < 64; k += 4) {
        float w0 = W2[(k + 0) * 64 + j], w1 = W2[(k + 1) * 64 + j];
        float w2 = W2[(k + 2) * 64 + j], w3 = W2[(k + 3) * 64 + j];
        const float4 hv = *(const float4*)&h[ql][k];
        a2 = fmaf(hv.x, w0, fmaf(hv.y, w1, fmaf(hv.z, w2, fmaf(hv.w, w3, a2))));
    }
    fout[node * 64 + j] = a2;
}

// ---------------------------------------------------------------- binning
__global__ void k_bincount(const float2* __restrict__ coords, int* __restrict__ cnt) {
    int t = blockIdx.x * blockDim.x + threadIdx.x;
    if (t >= B_ * N_) return;
    float2 c = coords[t];
    int b = t >> 13;
    int cell = cellof(c.x) * 64 + cellof(c.y);
    atomicAdd(&cnt[b * 4096 + cell], 1);
}
__global__ void k_binscan(const int* __restrict__ cnt, int* __restrict__ offs) {
    int b = blockIdx.x, t = threadIdx.x;    // 1024 threads
    __shared__ int s[1024];
    int4 v = ((const int4*)(cnt + b * 4096))[t];
    int sum = v.x + v.y + v.z + v.w;
    s[t] = sum;
    __syncthreads();
    for (int d = 1; d < 1024; d <<= 1) {
        int x = (t >= d) ? s[t - d] : 0;
        __syncthreads();
        s[t] += x;
        __syncthreads();
    }
    int incl = s[t], excl = incl - sum;
    int* ob = offs + b * 4097;
    ob[4 * t] = excl; ob[4 * t + 1] = excl + v.x;
    ob[4 * t + 2] = excl + v.x + v.y; ob[4 * t + 3] = excl + v.x + v.y + v.z;
    if (t == 1023) ob[4096] = incl;
}
__global__ void k_binscatter(const float2* __restrict__ coords, const int* __restrict__ offs,
                             int* __restrict__ fill, float4* __restrict__ srt) {
    int t = blockIdx.x * blockDim.x + threadIdx.x;
    if (t >= B_ * N_) return;
    float2 c = coords[t];
    int b = t >> 13, n = t & 8191;
    int cell = cellof(c.x) * 64 + cellof(c.y);
    int pos = offs[b * 4097 + cell] + atomicAdd(&fill[b * 4096 + cell], 1);
    float s2 = __fadd_rn(__fmul_rn(c.x, c.x), __fmul_rn(c.y, c.y));
    srt[b * N_ + pos] = make_float4(c.x, c.y, s2, __int_as_float(n));
}

// ---------------------------------------------------------------- kNN grid->points: one wave per query
__global__ void __launch_bounds__(256) k_knn_in(
    const float4* __restrict__ gp, const float4* __restrict__ srt,
    const int* __restrict__ offs, int* __restrict__ oidx,
    float* __restrict__ odist, float* __restrict__ lastd) {
    int lane = threadIdx.x & 63;
    int w = (blockIdx.x * blockDim.x + threadIdx.x) >> 6;   // wave-uniform query id
    int b = w >> 12, p = w & 4095;
    float4 q = gp[p];
    float qx = q.x, qy = q.y, q2 = q.z;
    int cqx = cellof(qx), cqy = cellof(qy);
    const float4* S = srt + b * N_;
    const int* OF = offs + b * 4097;

    u64k R = ~0ull;          // running sorted top-64 (ascending)
    u64k pend = ~0ull;       // pending batch
    int fill = 0;

    auto flush = [&]() {
        bsort64(pend, lane);
        bmerge_into(R, pend, lane);
        pend = ~0ull;
        fill = 0;
    };
    auto feed = [&](int s0, int s1) {
        int cnt = s1 - s0;
        while (cnt > 0) {
            int take = min(cnt, 64 - fill);
            int t = lane - fill;
            if (t >= 0 && t < take) {
                float4 sp = S[s0 + t];
                float dot = __fadd_rn(__fmul_rn(qx, sp.x), __fmul_rn(qy, sp.y));
                float d2 = __fsub_rn(__fadd_rn(q2, sp.z), 2.0f * dot);
                d2 = fmaxf(d2, 0.0f);
                pend = ((u64k)__float_as_uint(d2) << 32) | (unsigned)__float_as_int(sp.w);
            }
            fill += take; s0 += take; cnt -= take;
            if (fill == 64) flush();
        }
    };

    {   // initial 5x5 square (radius 2)
        int xa = max(cqx - 2, 0), xb = min(cqx + 2, 63);
        int ya = max(cqy - 2, 0), yb = min(cqy + 2, 63);
        for (int cx = xa; cx <= xb; cx++) feed(OF[cx * 64 + ya], OF[cx * 64 + yb + 1]);
    }
    int r = 2;
    while (true) {
        if (fill) flush();
        u64k T = (u64k)__shfl((long long)R, 15, 64);
        float d16 = __uint_as_float((unsigned)(T >> 32));    // NaN if <16 found -> continue
        float bm = (float)r * 0.03125f;                      // min dist of any unseen point
        if (d16 < bm * bm - 1e-5f) break;
        if (cqx - r <= 0 && cqx + r >= 63 && cqy - r <= 0 && cqy + r >= 63) break;
        r++;
        int ya = max(cqy - r, 0), yb = min(cqy + r, 63);
        if (cqx - r >= 0)  { int c0 = (cqx - r) * 64; feed(OF[c0 + ya], OF[c0 + yb + 1]); }
        if (cqx + r <= 63) { int c0 = (cqx + r) * 64; feed(OF[c0 + ya], OF[c0 + yb + 1]); }
        int xa2 = max(cqx - r + 1, 0), xb2 = min(cqx + r - 1, 63);
        for (int cx = xa2; cx <= xb2; cx++) {
            if (cqy - r >= 0)  { int cc = cx * 64 + cqy - r; feed(OF[cc], OF[cc + 1]); }
            if (cqy + r <= 63) { int cc = cx * 64 + cqy + r; feed(OF[cc], OF[cc + 1]); }
        }
    }
    if (lane < 16) {
        float d2 = __uint_as_float((unsigned)(R >> 32));
        float d = sqrtf(d2);
        oidx[w * 16 + lane] = (int)(unsigned)(R & 0xffffffffu);
        odist[w * 16 + lane] = d;
        if (lane == 15) lastd[w] = d;
    }
}

// ---------------------------------------------------------------- kNN points->grid: one wave per query, fixed 8x8 lattice box
__global__ void __launch_bounds__(256) k_knn_out(
    const float2* __restrict__ coords, const float4* __restrict__ gp,
    int* __restrict__ oidx, float* __restrict__ odist, float* __restrict__ lastd) {
    int lane = threadIdx.x & 63;
    int w = (blockIdx.x * blockDim.x + threadIdx.x) >> 6;   // 0..B_*N_-1
    float2 c = coords[w];
    float qx = c.x, qy = c.y;
    float q2 = __fadd_rn(__fmul_rn(qx, qx), __fmul_rn(qy, qy));
    int i0 = (int)floorf((qx + 1.0f) * 31.5f);
    int j0 = (int)floorf((qy + 1.0f) * 31.5f);
    int li = min(max(i0 - 3, 0), 56);
    int lj = min(max(j0 - 3, 0), 56);
    int p = (li + (lane >> 3)) * 64 + (lj + (lane & 7));
    float4 sp = gp[p];
    float dot = __fadd_rn(__fmul_rn(qx, sp.x), __fmul_rn(qy, sp.y));
    float d2 = fmaxf(__fsub_rn(__fadd_rn(q2, sp.z), 2.0f * dot), 0.0f);
    u64k key = ((u64k)__float_as_uint(d2) << 32) | (unsigned)p;
    bsort64(key, lane);
    if (lane < 16) {
        float dd = sqrtf(__uint_as_float((unsigned)(key >> 32)));
        oidx[w * 16 + lane] = (int)(unsigned)(key & 0xffffffffu);
        odist[w * 16 + lane] = dd;
        if (lane == 15) lastd[w] = dd;
    }
}

// ---------------------------------------------------------------- exact lower-median via single-block in-LDS bitonic sort
// n must be a power of two (8192 or 16384 here); all vals >= 0 so uint-bit
// order == float order. rank = (n-1)/2 (torch.median lower-median semantics).
__global__ void __launch_bounds__(1024) k_median_sort(
    const float* __restrict__ vals, int n, float* __restrict__ sig) {
    __shared__ unsigned s[16384];      // 64 KB
    int tid = threadIdx.x;
    for (int i = tid; i < n; i += 1024) s[i] = __float_as_uint(vals[i]);
    __syncthreads();
    for (int k = 2; k <= n; k <<= 1) {
        for (int j = k >> 1; j >= 1; j >>= 1) {
            for (int t = tid; t < (n >> 1); t += 1024) {
                int i = ((t & ~(j - 1)) << 1) | (t & (j - 1));
                int ix = i + j;
                unsigned a = s[i], b = s[ix];
                bool up = ((i & k) == 0);
                if ((a > b) == up) { s[i] = b; s[ix] = a; }
            }
            __syncthreads();
        }
    }
    if (tid == 0) *sig = fmaxf(__uint_as_float(s[(n - 1) >> 1]), 1e-6f);
}

// ---------------------------------------------------------------- edge MLP + weighted aggregation
// One wave (64 lanes) per 8 queries: lane = (q_local<<3) | jg, each lane owns
// 8 output features (j = jg*8..jg*8+7). Edges processed in two halves of 8,
// re-gathering feats per half -> LDS ~19 KB -> 8 single-wave blocks/CU
// (2 waves/SIMD) instead of 4 (1/SIMD) with full-16 staging.
// Query row stride 580 floats (580 % 32 == 4) keeps the 8 queries'
// broadcast ds_read_b128 on disjoint 4-bank groups.
// MODE 0: queries = grid, sources = coords, feats rows = N_ per batch
// MODE 1: queries = coords, sources = grid,  feats rows = NG per batch
template <int MODE>
__global__ void __launch_bounds__(64, 1) k_edge(
    const int* __restrict__ idxb, const float* __restrict__ distb, const float* __restrict__ sigp,
    const float2* __restrict__ coords, const float4* __restrict__ gp,
    const float* __restrict__ feats,
    const float* __restrict__ W1, const float* __restrict__ b1,
    const float* __restrict__ W2, const float* __restrict__ b2,
    const float* __restrict__ W3, const float* __restrict__ b3,
    float* __restrict__ outb, int Nq, int srcRows) {
    __shared__ __align__(16) float eA[8][8 * 72 + 4];   // 8 q x 8 edge-rows x 72 (+pad)
    __shared__ float wtsH[8][8];
    __shared__ int   nidxH[8][8];
    const int lane = threadIdx.x;          // 0..63
    const int qw = blockIdx.x * 8;         // first query handled by this wave
    const float sig = *sigp;
    const int ql = lane >> 3, jg = lane & 7, j0 = jg * 8;

    float so[8];
#pragma unroll
    for (int jj = 0; jj < 8; jj++) so[jj] = 0.f;
    float sumw = 0.f;

    for (int eh = 0; eh < 2; eh++) {
        // ---- metadata + geometry: lane <-> (q=ql, el=jg)
        {
            int e = eh * 8 + jg;
            int gq = qw + ql;
            int b = gq / Nq, p = gq - b * Nq;
            int si = idxb[gq * 16 + e];
            float d = distb[gq * 16 + e];
            nidxH[ql][jg] = si;
            wtsH[ql][jg] = expf(-d / sig);
            float qx, qy, sx, sy;
            if (MODE == 0) {
                float4 g = gp[p]; qx = g.x; qy = g.y;
                float2 cc = coords[(long)b * srcRows + si]; sx = cc.x; sy = cc.y;
            } else {
                float2 cc = coords[(long)b * Nq + p]; qx = cc.x; qy = cc.y;
                float4 g = gp[si]; sx = g.x; sy = g.y;
            }
            float* row = &eA[ql][jg * 72];
            row[0] = qx; row[1] = qy; row[2] = sx; row[3] = sy;
            row[4] = qx - sx; row[5] = qy - sy; row[6] = d; row[7] = 0.f;
        }
        __syncthreads();
        // ---- feats gather: 64 rows x 16 float4 = 1024 slots / 64 lanes
        for (int it = 0; it < 16; it++) {
            int slot = it * 64 + lane;
            int rowi = slot >> 4, f4 = slot & 15;
            int q = rowi >> 3, el = rowi & 7;
            int gq = qw + q;
            int b = gq / Nq;
            int si = nidxH[q][el];
            const float4 v = *(const float4*)&feats[((long)b * srcRows + si) * 64 + f4 * 4];
            *(float4*)&eA[q][el * 72 + 8 + f4 * 4] = v;
        }
        __syncthreads();

        float acc[8][8];
        // ---------- layer 1: x[0..71] (x[7]==0, W1 rows skip slot 7)
        {
            float4 bv0 = *(const float4*)&b1[j0], bv1 = *(const float4*)&b1[j0 + 4];
            float bj[8] = {bv0.x, bv0.y, bv0.z, bv0.w, bv1.x, bv1.y, bv1.z, bv1.w};
#pragma unroll
            for (int e = 0; e < 8; e++)
#pragma unroll
                for (int jj = 0; jj < 8; jj++) acc[e][jj] = bj[jj];
            for (int c = 0; c < 18; c++) {
                float w[4][8];
#pragma unroll
                for (int rr = 0; rr < 4; rr++) {
                    int t = c * 4 + rr;
                    int wrow = t - (t > 6);
                    float4 a = *(const float4*)&W1[wrow * 64 + j0];
                    float4 bq = *(const float4*)&W1[wrow * 64 + j0 + 4];
                    if (t == 7) { a = make_float4(0.f, 0.f, 0.f, 0.f); bq = a; }
                    w[rr][0] = a.x; w[rr][1] = a.y; w[rr][2] = a.z; w[rr][3] = a.w;
                    w[rr][4] = bq.x; w[rr][5] = bq.y; w[rr][6] = bq.z; w[rr][7] = bq.w;
                }
#pragma unroll
                for (int e = 0; e < 8; e++) {
                    const float4 xv = *(const float4*)&eA[ql][e * 72 + c * 4];
                    const float xs[4] = {xv.x, xv.y, xv.z, xv.w};
#pragma unroll
                    for (int rr = 0; rr < 4; rr++)
#pragma unroll
                        for (int jj = 0; jj < 8; jj++)
                            acc[e][jj] = fmaf(xs[rr], w[rr][jj], acc[e][jj]);
                }
            }
        }
        __syncthreads();
#pragma unroll
        for (int e = 0; e < 8; e++) {
            float4 h0 = make_float4(gelu_f(acc[e][0]), gelu_f(acc[e][1]),
                                    gelu_f(acc[e][2]), gelu_f(acc[e][3]));
            float4 h1 = make_float4(gelu_f(acc[e][4]), gelu_f(acc[e][5]),
                                    gelu_f(acc[e][6]), gelu_f(acc[e][7]));
            *(float4*)&eA[ql][e * 72 + j0] = h0;
            *(float4*)&eA[ql][e * 72 + j0 + 4] = h1;
        }
        __syncthreads();
        // ---------- layer 2: x[0..63]
        {
            float4 bv0 = *(const float4*)&b2[j0], bv1 = *(const float4*)&b2[j0 + 4];
            float bj[8] = {bv0.x, bv0.y, bv0.z, bv0.w, bv1.x, bv1.y, bv1.z, bv1.w};
#pragma unroll
            for (int e = 0; e < 8; e++)
#pragma unroll
                for (int jj = 0; jj < 8; jj++) acc[e][jj] = bj[jj];
            for (int c = 0; c < 16; c++) {
                float w[4][8];
#pragma unroll
                for (int rr = 0; rr < 4; rr++) {
                    float4 a = *(const float4*)&W2[(c * 4 + rr) * 64 + j0];
                    float4 bq = *(const float4*)&W2[(c * 4 + rr) * 64 + j0 + 4];
                    w[rr][0] = a.x; w[rr][1] = a.y; w[rr][2] = a.z; w[rr][3] = a.w;
                    w[rr][4] = bq.x; w[rr][5] = bq.y; w[rr][6] = bq.z; w[rr][7] = bq.w;
                }
#pragma unroll
                for (int e = 0; e < 8; e++) {
                    const float4 xv = *(const float4*)&eA[ql][e * 72 + c * 4];
                    const float xs[4] = {xv.x, xv.y, xv.z, xv.w};
#pragma unroll
                    for (int rr = 0; rr < 4; rr++)
#pragma unroll
                        for (int jj = 0; jj < 8; jj++)
                            acc[e][jj] = fmaf(xs[rr], w[rr][jj], acc[e][jj]);
                }
            }
        }
        __syncthreads();
#pragma unroll
        for (int e = 0; e < 8; e++) {
            float4 h0 = make_float4(gelu_f(acc[e][0]), gelu_f(acc[e][1]),
                                    gelu_f(acc[e][2]), gelu_f(acc[e][3]));
            float4 h1 = make_float4(gelu_f(acc[e][4]), gelu_f(acc[e][5]),
                                    gelu_f(acc[e][6]), gelu_f(acc[e][7]));
            *(float4*)&eA[ql][e * 72 + j0] = h0;
            *(float4*)&eA[ql][e * 72 + j0 + 4] = h1;
        }
        __syncthreads();
        // ---------- layer 3: x[0..63], no activation; accumulate weighted sum
        {
            float4 bv0 = *(const float4*)&b3[j0], bv1 = *(const float4*)&b3[j0 + 4];
            float bj[8] = {bv0.x, bv0.y, bv0.z, bv0.w, bv1.x, bv1.y, bv1.z, bv1.w};
#pragma unroll
            for (int e = 0; e < 8; e++)
#pragma unroll
                for (int jj = 0; jj < 8; jj++) acc[e][jj] = bj[jj];
            for (int c = 0; c < 16; c++) {
                float w[4][8];
#pragma unroll
                for (int rr = 0; rr < 4; rr++) {
                    float4 a = *(const float4*)&W3[(c * 4 + rr) * 64 + j0];
                    float4 bq = *(const float4*)&W3[(c * 4 + rr) * 64 + j0 + 4];
                    w[rr][0] = a.x; w[rr][1] = a.y; w[rr][2] = a.z; w[rr][3] = a.w;
                    w[rr][4] = bq.x; w[rr][5] = bq.y; w[rr][6] = bq.z; w[rr][7] = bq.w;
                }
#pragma unroll
                for (int e = 0; e < 8; e++) {
                    const float4 xv = *(const float4*)&eA[ql][e * 72 + c * 4];
                    const float xs[4] = {xv.x, xv.y, xv.z, xv.w};
#pragma unroll
                    for (int rr = 0; rr < 4; rr++)
#pragma unroll
                        for (int jj = 0; jj < 8; jj++)
                            acc[e][jj] = fmaf(xs[rr], w[rr][jj], acc[e][jj]);
                }
            }
#pragma unroll
            for (int e = 0; e < 8; e++) {
                float wv = wtsH[ql][e];
                sumw += wv;
#pragma unroll
                for (int jj = 0; jj < 8; jj++) so[jj] = fmaf(wv, acc[e][jj], so[jj]);
            }
        }
        __syncthreads();
    }
    float den = fmaxf(sumw, 1e-6f);
    int gq = qw + ql;
    float4 o0 = make_float4(so[0] / den, so[1] / den, so[2] / den, so[3] / den);
    float4 o1 = make_float4(so[4] / den, so[5] / den, so[6] / den, so[7] / den);
    *(float4*)&outb[(long)gq * 64 + j0] = o0;
    *(float4*)&outb[(long)gq * 64 + j0 + 4] = o1;
}

// ---------------------------------------------------------------- transpose (B,R,C) -> (B,C,R)
__global__ void k_transp(const float* __restrict__ src, float* __restrict__ dst, int R, int C) {
    __shared__ float t[32][33];
    int b = blockIdx.z;
    int c0 = blockIdx.x * 32, r0 = blockIdx.y * 32;
    int tx = threadIdx.x, ty0 = threadIdx.y;    // (32,8)
    for (int yy = ty0; yy < 32; yy += 8) {
        int r = r0 + yy, c = c0 + tx;
        if (r < R && c < C) t[yy][tx] = src[((long)b * R + r) * C + c];
    }
    __syncthreads();
    for (int yy = ty0; yy < 32; yy += 8) {
        int c = c0 + yy, r = r0 + tx;
        if (r < R && c < C) dst[((long)b * C + c) * R + r] = t[tx][yy];
    }
}

// ---------------------------------------------------------------- FNO: truncated forward DFT (rows 0..11 & 52..63, cols 0..11)
__global__ void __launch_bounds__(1024) k_f1(const float* __restrict__ x, float* __restrict__ Xh) {
    int blk = blockIdx.x;    // b*64 + ch
    int tid = threadIdx.x;   // 1024
    __shared__ float img[4096];
    __shared__ float Tre[64][12], Tim[64][12];
    __shared__ float cs[64], sn[64];
    if (tid < 64) {
        double a = (2.0 * PI_ / 64.0) * (double)tid;
        cs[tid] = (float)cos(a);
        sn[tid] = (float)sin(a);
    }
    for (int p = tid; p < 4096; p += 1024) img[p] = x[(long)blk * 4096 + p];
    __syncthreads();
    for (int o = tid; o < 768; o += 1024) {      // (h, c)
        int h = o / 12, c = o - 12 * h;
        float re = 0.f, im = 0.f;
        for (int w = 0; w < 64; w++) {
            float v = img[h * 64 + w];
            int k = (c * w) & 63;
            re = fmaf(v, cs[k], re);
            im = fmaf(-v, sn[k], im);
        }
        Tre[h][c] = re; Tim[h][c] = im;
    }
    __syncthreads();
    for (int o = tid; o < 288; o += 1024) {      // (x24, c12)
        int xx = o / 12, c = o - 12 * xx;
        int r = (xx < 12) ? xx : (xx + 40);
        float re = 0.f, im = 0.f;
        for (int h = 0; h < 64; h++) {
            int k = (r * h) & 63;
            float cr = cs[k], si = sn[k];
            float a = Tre[h][c], bb = Tim[h][c];
            re += a * cr + bb * si;              // (a+ib)*e^{-i phi}
            im += bb * cr - a * si;
        }
        Xh[((long)blk * 288 + o) * 2] = re;
        Xh[((long)blk * 288 + o) * 2 + 1] = im;
    }
}

// mode-mix: Yhat[b,o,m] = sum_i Wc[i,o,m] * Xhat[b,i,m]
__global__ void __launch_bounds__(256) k_f2(const float* __restrict__ Xh, const float* __restrict__ s1,
                                            const float* __restrict__ s2, float* __restrict__ Yh) {
    int m = blockIdx.x;                  // 0..287
    int xx = m / 12, y = m - 12 * xx;
    const float* W; int xw;
    if (xx < 12) { W = s1; xw = xx; } else { W = s2; xw = xx - 12; }
    __shared__ float xr[128], xi[128];
    __shared__ float pr[256], pi[256];
    int tid = threadIdx.x;               // 256
    if (tid < 128) {
        int bb = tid >> 6, i = tid & 63;
        xr[tid] = Xh[(((long)bb * 64 + i) * 288 + m) * 2];
        xi[tid] = Xh[(((long)bb * 64 + i) * 288 + m) * 2 + 1];
    }
    __syncthreads();
    int half = tid >> 7;                 // i-range half
    int t2 = tid & 127;
    int bb = t2 >> 6, o = t2 & 63;
    float re = 0.f, im = 0.f;
    for (int i = half * 32; i < half * 32 + 32; i++) {
        long wb = (long)i * 18432 + (long)o * 288 + xw * 24 + y * 2;
        float wr = W[wb], wi = W[wb + 1];
        float a = xr[bb * 64 + i], cc = xi[bb * 64 + i];
        re += a * wr - cc * wi;
        im += a * wi + cc * wr;
    }
    pr[tid] = re; pi[tid] = im;
    __syncthreads();
    if (tid < 128) {
        float re2 = pr[tid] + pr[tid + 128];
        float im2 = pi[tid] + pi[tid + 128];
        Yh[(((long)bb * 64 + o) * 288 + m) * 2] = re2;
        Yh[(((long)bb * 64 + o) * 288 + m) * 2 + 1] = im2;
    }
}

// inverse DFT + pointwise conv + bias + InstanceNorm + GELU, fused per (b, out-channel)
__global__ void __launch_bounds__(1024) k_f3(const float* __restrict__ Yh, const float* __restrict__ x,
                                             const float* __restrict__ pwW, const float* __restrict__ pwb,
                                             float* __restrict__ xo) {
    int blk = blockIdx.x;
    int b = blk >> 6, o = blk & 63;
    int tid = threadIdx.x;   // 1024
    __shared__ float yre[288], yim[288];
    __shared__ float Qre[64][12], Qim[64][12];
    __shared__ float yimg[4096];
    __shared__ float cs[64], sn[64];
    __shared__ float red[1024];
    if (tid < 64) {
        double a = (2.0 * PI_ / 64.0) * (double)tid;
        cs[tid] = (float)cos(a);
        sn[tid] = (float)sin(a);
    }
    for (int t = tid; t < 288; t += 1024) {
        yre[t] = Yh[((long)blk * 288 + t) * 2];
        yim[t] = Yh[((long)blk * 288 + t) * 2 + 1];
    }
    __syncthreads();
    for (int q = tid; q < 768; q += 1024) {   // (h, c): complex ifft along rows (1/64 scale)
        int h = q / 12, c = q - 12 * h;
        float re = 0.f, im = 0.f;
#pragma unroll
        for (int xx = 0; xx < 24; xx++) {
            int r = (xx < 12) ? xx : (xx + 40);
            int k = (r * h) & 63;
            float wr = cs[k], wi = sn[k];
            float a = yre[xx * 12 + c], bb = yim[xx * 12 + c];
            re += a * wr - bb * wi;           // (a+ib)*e^{+i phi}
            im += a * wi + bb * wr;
        }
        Qre[h][c] = re * (1.0f / 64.0f);
        Qim[h][c] = im * (1.0f / 64.0f);
    }
    __syncthreads();
    float bias = pwb[o];
    for (int p = tid; p < 4096; p += 1024) {
        int h = p >> 6, w = p & 63;
        float sp = Qre[h][0];                 // irfft along cols: DC imag dropped
#pragma unroll
        for (int c = 1; c < 12; c++) {
            int k = (c * w) & 63;
            sp += 2.0f * (Qre[h][c] * cs[k] - Qim[h][c] * sn[k]);
        }
        sp *= (1.0f / 64.0f);
        float acc = sp + bias;
        for (int i = 0; i < 64; i++)
            acc = fmaf(x[(((long)b * 64 + i) * 4096) + p], pwW[o * 64 + i], acc);
        yimg[p] = acc;
    }
    __syncthreads();
    float part = 0.f;
    for (int p = tid; p < 4096; p += 1024) part += yimg[p];
    red[tid] = part;
    __syncthreads();
    for (int d = 512; d > 0; d >>= 1) { if (tid < d) red[tid] += red[tid + d]; __syncthreads(); }
    float mu = red[0] * (1.0f / 4096.0f);
    __syncthreads();
    float vp = 0.f;
    for (int p = tid; p < 4096; p += 1024) { float dd = yimg[p] - mu; vp = fmaf(dd, dd, vp); }
    red[tid] = vp;
    __syncthreads();
    for (int d = 512; d > 0; d >>= 1) { if (tid < d) red[tid] += red[tid + d]; __syncthreads(); }
    float var = red[0] * (1.0f / 4096.0f);
    float inv = 1.0f / sqrtf(var + 1e-5f);
    for (int p = tid; p < 4096; p += 1024) {
        float v = (yimg[p] - mu) * inv;
        xo[(long)blk * 4096 + p] = gelu_f(v);
    }
}

// ---------------------------------------------------------------- projection MLP (64 -> 64 -> 3)
__global__ void __launch_bounds__(256) k_proj(
    const float* __restrict__ y, const float* __restrict__ W1, const float* __restrict__ b1,
    const float* __restrict__ W2, const float* __restrict__ b2, float* __restrict__ out) {
    __shared__ __align__(16) float yr[4][64];
    __shared__ float h[4][64];
    int ql = threadIdx.x >> 6, j = threadIdx.x & 63;
    long node = (long)blockIdx.x * 4 + ql;
    yr[ql][j] = y[node * 64 + j];
    __syncthreads();
    float a = b1[j];
    for (int k = 0; k < 64; k += 4) {
        float w0 = W1[(k + 0) * 64 + j], w1 = W1[(k + 1) * 64 + j];
        float w2 = W1[(k + 2) * 64 + j], w3 = W1[(k + 3) * 64 + j];
        const float4 hv = *(const float4*)&yr[ql][k];
        a = fmaf(hv.x, w0, fmaf(hv.y, w1, fmaf(hv.z, w2, fmaf(hv.w, w3, a))));
    }
    h[ql][j] = gelu_f(a);
    __syncthreads();
    if (j < 3) {
        float a2 = b2[j];
        for (int k = 0; k < 64; k++) a2 = fmaf(h[ql][k], W2[k * 3 + j], a2);
        out[node * 3 + j] = a2;
    }
}

// ---------------------------------------------------------------- launch
extern "C" void kernel_launch(void* const* d_in, const int* in_sizes, int n_in,
                              void* d_out, int out_size, void* d_ws, size_t ws_size,
                              hipStream_t stream) {
    (void)in_sizes; (void)n_in; (void)out_size; (void)ws_size;
    const float* coords   = (const float*)d_in[0];
    const float* features = (const float*)d_in[1];
    const float* lift_W1 = (const float*)d_in[2];
    const float* lift_b1 = (const float*)d_in[3];
    const float* lift_W2 = (const float*)d_in[4];
    const float* lift_b2 = (const float*)d_in[5];
    const float* gin_W1 = (const float*)d_in[6];
    const float* gin_b1 = (const float*)d_in[7];
    const float* gin_W2 = (const float*)d_in[8];
    const float* gin_b2 = (const float*)d_in[9];
    const float* gin_W3 = (const float*)d_in[10];
    const float* gin_b3 = (const float*)d_in[11];
    const float* spec1 = (const float*)d_in[12];
    const float* spec2 = (const float*)d_in[13];
    const float* pw_W  = (const float*)d_in[14];
    const float* pw_b  = (const float*)d_in[15];
    const float* gout_W1 = (const float*)d_in[16];
    const float* gout_b1 = (const float*)d_in[17];
    const float* gout_W2 = (const float*)d_in[18];
    const float* gout_b2 = (const float*)d_in[19];
    const float* gout_W3 = (const float*)d_in[20];
    const float* gout_b3 = (const float*)d_in[21];
    const float* proj_W1 = (const float*)d_in[22];
    const float* proj_b1 = (const float*)d_in[23];
    const float* proj_W2 = (const float*)d_in[24];
    const float* proj_b2 = (const float*)d_in[25];

    char* ws = (char*)d_ws;
    size_t off = 0;
    auto alloc = [&](size_t bytes) -> char* {
        char* p = ws + off;
        off = (off + bytes + 255) & ~(size_t)255;
        return p;
    };
    float4* grid_pack = (float4*)alloc((size_t)NG * 16);
    float*  feat      = (float*)alloc((size_t)B_ * N_ * 64 * 4);
    int*    bin_cnt   = (int*)alloc((size_t)B_ * 4096 * 4);
    int*    bin_fill  = (int*)alloc((size_t)B_ * 4096 * 4);
    int*    bin_off   = (int*)alloc((size_t)B_ * 4097 * 4);
    float4* srt       = (float4*)alloc((size_t)B_ * N_ * 16);
    int*    idx_in    = (int*)alloc((size_t)B_ * NG * 16 * 4);
    float*  dist_in   = (float*)alloc((size_t)B_ * NG * 16 * 4);
    float*  lastd_in  = (float*)alloc((size_t)B_ * NG * 4);
    float*  sig_in    = (float*)alloc(256);
    float*  gout_buf  = (float*)alloc((size_t)B_ * NG * 64 * 4);
    float*  xb0       = (float*)alloc((size_t)B_ * 64 * NG * 4);
    float*  xb1       = (float*)alloc((size_t)B_ * 64 * NG * 4);
    float*  Xh        = (float*)alloc((size_t)B_ * 64 * 288 * 2 * 4);
    float*  Yh        = (float*)alloc((size_t)B_ * 64 * 288 * 2 * 4);
    float*  g2        = (float*)alloc((size_t)B_ * NG * 64 * 4);
    int*    idx_out   = (int*)alloc((size_t)B_ * N_ * 16 * 4);
    float*  dist_out  = (float*)alloc((size_t)B_ * N_ * 16 * 4);
    float*  lastd_out = (float*)alloc((size_t)B_ * N_ * 4);
    float*  sig_out   = (float*)alloc(256);
    float*  ybuf      = (float*)alloc((size_t)B_ * N_ * 64 * 4);

    hipMemsetAsync(bin_cnt, 0, (size_t)B_ * 4096 * 4, stream);
    hipMemsetAsync(bin_fill, 0, (size_t)B_ * 4096 * 4, stream);

    k_gridgen<<<NG / 256, 256, 0, stream>>>(grid_pack);
    k_lift<<<(B_ * N_) / 4, 256, 0, stream>>>(features, lift_W1, lift_b1, lift_W2, lift_b2, feat);
    k_bincount<<<(B_ * N_) / 256, 256, 0, stream>>>((const float2*)coords, bin_cnt);
    k_binscan<<<B_, 1024, 0, stream>>>(bin_cnt, bin_off);
    k_binscatter<<<(B_ * N_) / 256, 256, 0, stream>>>((const float2*)coords, bin_off, bin_fill, srt);
    k_knn_in<<<(B_ * NG * 64) / 256, 256, 0, stream>>>(grid_pack, srt, bin_off, idx_in, dist_in, lastd_in);
    k_median_sort<<<1, 1024, 0, stream>>>(lastd_in, B_ * NG, sig_in);
    k_edge<0><<<(B_ * NG) / 8, 64, 0, stream>>>(idx_in, dist_in, sig_in, (const float2*)coords,
        grid_pack, feat, gin_W1, gin_b1, gin_W2, gin_b2, gin_W3, gin_b3, gout_buf, NG, N_);
    {
        dim3 g(64 / 32, NG / 32, B_); dim3 t(32, 8);
        k_transp<<<g, t, 0, stream>>>(gout_buf, xb0, NG, 64);
    }
    float* xc = xb0; float* xn = xb1;
    for (int d = 0; d < 3; d++) {
        k_f1<<<B_ * 64, 1024, 0, stream>>>(xc, Xh);
        k_f2<<<288, 256, 0, stream>>>(Xh, spec1 + (size_t)d * 1179648, spec2 + (size_t)d * 1179648, Yh);
        k_f3<<<B_ * 64, 1024, 0, stream>>>(Yh, xc, pw_W + (size_t)d * 4096, pw_b + (size_t)d * 64, xn);
        float* tmp = xc; xc = xn; xn = tmp;
    }
    {
        dim3 g(NG / 32, 64 / 32, B_); dim3 t(32, 8);
        k_transp<<<g, t, 0, stream>>>(xc, g2, 64, NG);
    }
    k_knn_out<<<(B_ * N_ * 64) / 256, 256, 0, stream>>>((const float2*)coords, grid_pack, idx_out, dist_out, lastd_out);
    k_median_sort<<<1, 1024, 0, stream>>>(lastd_out, B_ * N_, sig_out);
    k_edge<1><<<(B_ * N_) / 8, 64, 0, stream>>>(idx_out, dist_out, sig_out, (const float2*)coords,
        grid_pack, g2, gout_W1, gout_b1, gout_W2, gout_b2, gout_W3, gout_b3, ybuf, N_, NG);
    k_proj<<<(B_ * N_) / 4, 256, 0, stream>>>(ybuf, proj_W1, proj_b1, proj_W2, proj_b2, (float*)d_out);
}

// Round 4
// 641.850 us; speedup vs baseline: 1.4934x; 1.1257x over previous
//
#include <hip/hip_runtime.h>
#include <math.h>

#define B_ 2
#define N_ 8192          // points per batch
#define G_ 64
#define NG 4096          // G*G latent grid points
#define WID_ 64
#define K_ 16
#define CIN_ 6
#define COUT_ 3
#define PI_ 3.14159265358979323846

typedef unsigned long long u64k;

// ---------------------------------------------------------------- helpers
__device__ __forceinline__ float gelu_f(float x) {
    return 0.5f * x * (1.0f + erff(x * 0.70710678118654752440f));
}
__device__ __forceinline__ int cellof(float v) {
    int c = (int)floorf((v + 1.0f) * 32.0f);
    return min(63, max(0, c));
}
__device__ __forceinline__ u64k umin64(u64k a, u64k b) { return a < b ? a : b; }
__device__ __forceinline__ u64k umax64(u64k a, u64k b) { return a < b ? b : a; }
__device__ __forceinline__ u64k shflxor64(u64k v, int m) {
    return (u64k)__shfl_xor((long long)v, m, 64);
}
__device__ __forceinline__ void bsort64(u64k& key, int lane) {
#pragma unroll
    for (int sz = 2; sz <= 64; sz <<= 1) {
#pragma unroll
        for (int j = sz >> 1; j >= 1; j >>= 1) {
            u64k o = shflxor64(key, j);
            bool keep_min = ((lane & j) == 0) == ((lane & sz) == 0);
            key = keep_min ? umin64(key, o) : umax64(key, o);
        }
    }
}
__device__ __forceinline__ void bmerge_into(u64k& R, u64k key, int lane) {
    u64k o = shflxor64(key, 63);
    u64k L = umin64(R, o);
#pragma unroll
    for (int j = 32; j >= 1; j >>= 1) {
        u64k t = shflxor64(L, j);
        L = ((lane & j) == 0) ? umin64(L, t) : umax64(L, t);
    }
    R = L;
}

// ---------------------------------------------------------------- grid gen
__global__ void k_gridgen(float4* gp) {
    int p = blockIdx.x * blockDim.x + threadIdx.x;
    if (p >= NG) return;
    int i = p >> 6, j = p & 63;
    double st = 2.0 / 63.0;
    float gx = (i == 63) ? 1.0f : (float)(-1.0 + st * (double)i);
    float gy = (j == 63) ? 1.0f : (float)(-1.0 + st * (double)j);
    float s2 = __fadd_rn(__fmul_rn(gx, gx), __fmul_rn(gy, gy));
    gp[p] = make_float4(gx, gy, s2, 0.f);
}

// ---------------------------------------------------------------- lift MLP
__global__ void __launch_bounds__(256) k_lift(
    const float* __restrict__ fin, const float* __restrict__ W1,
    const float* __restrict__ b1, const float* __restrict__ W2,
    const float* __restrict__ b2, float* __restrict__ fout) {
    __shared__ float xr[4][8];
    __shared__ __align__(16) float h[4][64];
    int ql = threadIdx.x >> 6, j = threadIdx.x & 63;
    int node = blockIdx.x * 4 + ql;
    if (j < CIN_) xr[ql][j] = fin[node * CIN_ + j];
    __syncthreads();
    float a = b1[j];
#pragma unroll
    for (int i = 0; i < CIN_; i++) a = fmaf(xr[ql][i], W1[i * 64 + j], a);
    h[ql][j] = gelu_f(a);
    __syncthreads();
    float a2 = b2[j];
    for (int k = 0; k < 64; k += 4) {
        float w0 = W2[(k + 0) * 64 + j], w1 = W2[(k + 1) * 64 + j];
        float w2 = W2[(k + 2) * 64 + j], w3 = W2[(k + 3) * 64 + j];
        const float4 hv = *(const float4*)&h[ql][k];
        a2 = fmaf(hv.x, w0, fmaf(hv.y, w1, fmaf(hv.z, w2, fmaf(hv.w, w3, a2))));
    }
    fout[node * 64 + j] = a2;
}

// ---------------------------------------------------------------- binning
__global__ void k_bincount(const float2* __restrict__ coords, int* __restrict__ cnt) {
    int t = blockIdx.x * blockDim.x + threadIdx.x;
    if (t >= B_ * N_) return;
    float2 c = coords[t];
    int b = t >> 13;
    int cell = cellof(c.x) * 64 + cellof(c.y);
    atomicAdd(&cnt[b * 4096 + cell], 1);
}
__global__ void k_binscan(const int* __restrict__ cnt, int* __restrict__ offs) {
    int b = blockIdx.x, t = threadIdx.x;    // 1024 threads
    __shared__ int s[1024];
    int4 v = ((const int4*)(cnt + b * 4096))[t];
    int sum = v.x + v.y + v.z + v.w;
    s[t] = sum;
    __syncthreads();
    for (int d = 1; d < 1024; d <<= 1) {
        int x = (t >= d) ? s[t - d] : 0;
        __syncthreads();
        s[t] += x;
        __syncthreads();
    }
    int incl = s[t], excl = incl - sum;
    int* ob = offs + b * 4097;
    ob[4 * t] = excl; ob[4 * t + 1] = excl + v.x;
    ob[4 * t + 2] = excl + v.x + v.y; ob[4 * t + 3] = excl + v.x + v.y + v.z;
    if (t == 1023) ob[4096] = incl;
}
__global__ void k_binscatter(const float2* __restrict__ coords, const int* __restrict__ offs,
                             int* __restrict__ fill, float4* __restrict__ srt) {
    int t = blockIdx.x * blockDim.x + threadIdx.x;
    if (t >= B_ * N_) return;
    float2 c = coords[t];
    int b = t >> 13, n = t & 8191;
    int cell = cellof(c.x) * 64 + cellof(c.y);
    int pos = offs[b * 4097 + cell] + atomicAdd(&fill[b * 4096 + cell], 1);
    float s2 = __fadd_rn(__fmul_rn(c.x, c.x), __fmul_rn(c.y, c.y));
    srt[b * N_ + pos] = make_float4(c.x, c.y, s2, __int_as_float(n));
}

// ---------------------------------------------------------------- kNN grid->points: one wave per query
__global__ void __launch_bounds__(256) k_knn_in(
    const float4* __restrict__ gp, const float4* __restrict__ srt,
    const int* __restrict__ offs, int* __restrict__ oidx,
    float* __restrict__ odist, float* __restrict__ lastd) {
    int lane = threadIdx.x & 63;
    int w = (blockIdx.x * blockDim.x + threadIdx.x) >> 6;
    int b = w >> 12, p = w & 4095;
    float4 q = gp[p];
    float qx = q.x, qy = q.y, q2 = q.z;
    int cqx = cellof(qx), cqy = cellof(qy);
    const float4* S = srt + b * N_;
    const int* OF = offs + b * 4097;

    u64k R = ~0ull;
    u64k pend = ~0ull;
    int fill = 0;

    auto flush = [&]() {
        bsort64(pend, lane);
        bmerge_into(R, pend, lane);
        pend = ~0ull;
        fill = 0;
    };
    auto feed = [&](int s0, int s1) {
        int cnt = s1 - s0;
        while (cnt > 0) {
            int take = min(cnt, 64 - fill);
            int t = lane - fill;
            if (t >= 0 && t < take) {
                float4 sp = S[s0 + t];
                float dot = __fadd_rn(__fmul_rn(qx, sp.x), __fmul_rn(qy, sp.y));
                float d2 = __fsub_rn(__fadd_rn(q2, sp.z), 2.0f * dot);
                d2 = fmaxf(d2, 0.0f);
                pend = ((u64k)__float_as_uint(d2) << 32) | (unsigned)__float_as_int(sp.w);
            }
            fill += take; s0 += take; cnt -= take;
            if (fill == 64) flush();
        }
    };

    {
        int xa = max(cqx - 2, 0), xb = min(cqx + 2, 63);
        int ya = max(cqy - 2, 0), yb = min(cqy + 2, 63);
        for (int cx = xa; cx <= xb; cx++) feed(OF[cx * 64 + ya], OF[cx * 64 + yb + 1]);
    }
    int r = 2;
    while (true) {
        if (fill) flush();
        u64k T = (u64k)__shfl((long long)R, 15, 64);
        float d16 = __uint_as_float((unsigned)(T >> 32));
        float bm = (float)r * 0.03125f;
        if (d16 < bm * bm - 1e-5f) break;
        if (cqx - r <= 0 && cqx + r >= 63 && cqy - r <= 0 && cqy + r >= 63) break;
        r++;
        int ya = max(cqy - r, 0), yb = min(cqy + r, 63);
        if (cqx - r >= 0)  { int c0 = (cqx - r) * 64; feed(OF[c0 + ya], OF[c0 + yb + 1]); }
        if (cqx + r <= 63) { int c0 = (cqx + r) * 64; feed(OF[c0 + ya], OF[c0 + yb + 1]); }
        int xa2 = max(cqx - r + 1, 0), xb2 = min(cqx + r - 1, 63);
        for (int cx = xa2; cx <= xb2; cx++) {
            if (cqy - r >= 0)  { int cc = cx * 64 + cqy - r; feed(OF[cc], OF[cc + 1]); }
            if (cqy + r <= 63) { int cc = cx * 64 + cqy + r; feed(OF[cc], OF[cc + 1]); }
        }
    }
    if (lane < 16) {
        float d2 = __uint_as_float((unsigned)(R >> 32));
        float d = sqrtf(d2);
        oidx[w * 16 + lane] = (int)(unsigned)(R & 0xffffffffu);
        odist[w * 16 + lane] = d;
        if (lane == 15) lastd[w] = d;
    }
}

// ---------------------------------------------------------------- kNN points->grid: one wave per query
__global__ void __launch_bounds__(256) k_knn_out(
    const float2* __restrict__ coords, const float4* __restrict__ gp,
    int* __restrict__ oidx, float* __restrict__ odist, float* __restrict__ lastd) {
    int lane = threadIdx.x & 63;
    int w = (blockIdx.x * blockDim.x + threadIdx.x) >> 6;
    float2 c = coords[w];
    float qx = c.x, qy = c.y;
    float q2 = __fadd_rn(__fmul_rn(qx, qx), __fmul_rn(qy, qy));
    int i0 = (int)floorf((qx + 1.0f) * 31.5f);
    int j0 = (int)floorf((qy + 1.0f) * 31.5f);
    int li = min(max(i0 - 3, 0), 56);
    int lj = min(max(j0 - 3, 0), 56);
    int p = (li + (lane >> 3)) * 64 + (lj + (lane & 7));
    float4 sp = gp[p];
    float dot = __fadd_rn(__fmul_rn(qx, sp.x), __fmul_rn(qy, sp.y));
    float d2 = fmaxf(__fsub_rn(__fadd_rn(q2, sp.z), 2.0f * dot), 0.0f);
    u64k key = ((u64k)__float_as_uint(d2) << 32) | (unsigned)p;
    bsort64(key, lane);
    if (lane < 16) {
        float dd = sqrtf(__uint_as_float((unsigned)(key >> 32)));
        oidx[w * 16 + lane] = (int)(unsigned)(key & 0xffffffffu);
        odist[w * 16 + lane] = dd;
        if (lane == 15) lastd[w] = dd;
    }
}

// ---------------------------------------------------------------- exact lower-median: 3-level radix select (14/14/4 bits)
// all vals >= 0 so uint-bit order == float order; exact rank (n-1)/2.
__global__ void __launch_bounds__(1024) k_median3(
    const float* __restrict__ vals, int n, float* __restrict__ sig) {
    __shared__ unsigned hist[16384];     // 64 KB
    __shared__ unsigned psum[1024];
    __shared__ unsigned s_bin, s_res;
    int tid = threadIdx.x;
    int rank = (n - 1) >> 1;

    auto select16k = [&](unsigned rk, unsigned& bin, unsigned& res) {
        unsigned local = 0;
        unsigned base = tid * 16;
#pragma unroll
        for (int k = 0; k < 16; k++) local += hist[base + k];
        psum[tid] = local;
        __syncthreads();
        for (int d = 1; d < 1024; d <<= 1) {
            unsigned v = (tid >= d) ? psum[tid - d] : 0;
            __syncthreads();
            psum[tid] += v;
            __syncthreads();
        }
        unsigned incl = psum[tid], excl = incl - local;
        if (rk >= excl && rk < incl) {
            unsigned rr = rk - excl;
#pragma unroll
            for (int k = 0; k < 16; k++) {
                unsigned c = hist[base + k];
                if (rr < c) { s_bin = base + k; s_res = rr; break; }
                rr -= c;
            }
        }
        __syncthreads();
        bin = s_bin; res = s_res;
        __syncthreads();
    };

    // ---- level 0: bits [31:18]
    for (int i = tid; i < 16384; i += 1024) hist[i] = 0;
    __syncthreads();
    for (int i = tid; i < n; i += 1024)
        atomicAdd(&hist[__float_as_uint(vals[i]) >> 18], 1u);
    __syncthreads();
    unsigned B0, r0;
    select16k((unsigned)rank, B0, r0);
    // ---- level 1: bits [17:4]
    for (int i = tid; i < 16384; i += 1024) hist[i] = 0;
    __syncthreads();
    for (int i = tid; i < n; i += 1024) {
        unsigned u = __float_as_uint(vals[i]);
        if ((u >> 18) == B0) atomicAdd(&hist[(u >> 4) & 16383], 1u);
    }
    __syncthreads();
    unsigned B1, r1;
    select16k(r0, B1, r1);
    // ---- level 2: bits [3:0]
    if (tid < 16) hist[tid] = 0;
    __syncthreads();
    unsigned hi28 = (B0 << 14) | B1;
    for (int i = tid; i < n; i += 1024) {
        unsigned u = __float_as_uint(vals[i]);
        if ((u >> 4) == hi28) atomicAdd(&hist[u & 15], 1u);
    }
    __syncthreads();
    if (tid == 0) {
        unsigned rr = r1, bsel = 15;
        for (unsigned k = 0; k < 16; k++) {
            unsigned c = hist[k];
            if (rr < c) { bsel = k; break; }
            rr -= c;
        }
        unsigned u = (hi28 << 4) | bsel;
        *sig = fmaxf(__uint_as_float(u), 1e-6f);
    }
}

// ---------------------------------------------------------------- precompute softmax-style weights + clamped sum per query
__global__ void __launch_bounds__(256) k_wts(
    const float* __restrict__ distb, const float* __restrict__ sigp,
    float* __restrict__ wtsb, float* __restrict__ wsum, int tot) {
    int t = blockIdx.x * blockDim.x + threadIdx.x;
    if (t >= tot) return;
    float sig = *sigp;
    float s = 0.f;
#pragma unroll
    for (int e = 0; e < 16; e++) {
        float w = expf(-distb[t * 16 + e] / sig);
        wtsb[t * 16 + e] = w;
        s += w;
    }
    wsum[t] = fmaxf(s, 1e-6f);
}

// ---------------------------------------------------------------- edge MLP + weighted aggregation
// One wave per (8 queries x 4-edge slice). lane = (q<<3)|jg; lane owns 8 output
// features j = jg*8..+7 for its 8 queries; 4 edges in registers. Partial
// weighted sums atomically accumulated into outacc (zeroed beforehand);
// k_findiv divides by precomputed wsum. Query LDS stride 292 (== 4 mod 32)
// keeps the 8 queries' broadcast ds_read_b128 on disjoint 4-bank groups.
template <int MODE>
__global__ void __launch_bounds__(64, 4) k_edge(
    const int* __restrict__ idxb, const float* __restrict__ distb,
    const float* __restrict__ wtsb,
    const float2* __restrict__ coords, const float4* __restrict__ gp,
    const float* __restrict__ feats,
    const float* __restrict__ W1, const float* __restrict__ b1,
    const float* __restrict__ W2, const float* __restrict__ b2,
    const float* __restrict__ W3, const float* __restrict__ b3,
    float* __restrict__ outacc, int Nq, int srcRows) {
    __shared__ __align__(16) float eA[8][292];   // 8 q x (4 edges x 72) + pad
    __shared__ float wtsQ[8][4];
    __shared__ int   nidxQ[8][4];
    const int lane = threadIdx.x;          // 0..63
    const int sl = blockIdx.x & 3;         // edge slice
    const int qw = (blockIdx.x >> 2) * 8;  // first query
    const int ql = lane >> 3, jg = lane & 7, j0 = jg * 8;

    if (lane < 32) {
        int q = lane >> 2, el = lane & 3;
        int e = sl * 4 + el;
        int gq = qw + q;
        int b = gq / Nq, p = gq - b * Nq;
        int si = idxb[gq * 16 + e];
        float d = distb[gq * 16 + e];
        nidxQ[q][el] = si;
        wtsQ[q][el] = wtsb[gq * 16 + e];
        float qx, qy, sx, sy;
        if (MODE == 0) {
            float4 g = gp[p]; qx = g.x; qy = g.y;
            float2 cc = coords[(long)b * srcRows + si]; sx = cc.x; sy = cc.y;
        } else {
            float2 cc = coords[(long)b * Nq + p]; qx = cc.x; qy = cc.y;
            float4 g = gp[si]; sx = g.x; sy = g.y;
        }
        float* row = &eA[q][el * 72];
        row[0] = qx; row[1] = qy; row[2] = sx; row[3] = sy;
        row[4] = qx - sx; row[5] = qy - sy; row[6] = d; row[7] = 0.f;
    }
    __syncthreads();
    // feats gather: 32 rows x 16 float4 = 512 slots
    for (int it = 0; it < 8; it++) {
        int slot = it * 64 + lane;
        int rowi = slot >> 4, f4 = slot & 15;
        int q = rowi >> 2, el = rowi & 3;
        int gq = qw + q;
        int b = gq / Nq;
        int si = nidxQ[q][el];
        const float4 v = *(const float4*)&feats[((long)b * srcRows + si) * 64 + f4 * 4];
        *(float4*)&eA[q][el * 72 + 8 + f4 * 4] = v;
    }
    __syncthreads();

    float acc[4][8];
    // ---------- layer 1: x[0..71] (x[7]==0, W1 rows skip slot 7)
    {
        float4 bv0 = *(const float4*)&b1[j0], bv1 = *(const float4*)&b1[j0 + 4];
        float bj[8] = {bv0.x, bv0.y, bv0.z, bv0.w, bv1.x, bv1.y, bv1.z, bv1.w};
#pragma unroll
        for (int e = 0; e < 4; e++)
#pragma unroll
            for (int jj = 0; jj < 8; jj++) acc[e][jj] = bj[jj];
        for (int c = 0; c < 18; c++) {
            float w[4][8];
#pragma unroll
            for (int rr = 0; rr < 4; rr++) {
                int t = c * 4 + rr;
                int wrow = t - (t > 6);
                float4 a = *(const float4*)&W1[wrow * 64 + j0];
                float4 bq = *(const float4*)&W1[wrow * 64 + j0 + 4];
                if (t == 7) { a = make_float4(0.f, 0.f, 0.f, 0.f); bq = a; }
                w[rr][0] = a.x; w[rr][1] = a.y; w[rr][2] = a.z; w[rr][3] = a.w;
                w[rr][4] = bq.x; w[rr][5] = bq.y; w[rr][6] = bq.z; w[rr][7] = bq.w;
            }
#pragma unroll
            for (int e = 0; e < 4; e++) {
                const float4 xv = *(const float4*)&eA[ql][e * 72 + c * 4];
                const float xs[4] = {xv.x, xv.y, xv.z, xv.w};
#pragma unroll
                for (int rr = 0; rr < 4; rr++)
#pragma unroll
                    for (int jj = 0; jj < 8; jj++)
                        acc[e][jj] = fmaf(xs[rr], w[rr][jj], acc[e][jj]);
            }
        }
    }
    __syncthreads();
#pragma unroll
    for (int e = 0; e < 4; e++) {
        float4 h0 = make_float4(gelu_f(acc[e][0]), gelu_f(acc[e][1]),
                                gelu_f(acc[e][2]), gelu_f(acc[e][3]));
        float4 h1 = make_float4(gelu_f(acc[e][4]), gelu_f(acc[e][5]),
                                gelu_f(acc[e][6]), gelu_f(acc[e][7]));
        *(float4*)&eA[ql][e * 72 + j0] = h0;
        *(float4*)&eA[ql][e * 72 + j0 + 4] = h1;
    }
    __syncthreads();
    // ---------- layer 2: x[0..63]
    {
        float4 bv0 = *(const float4*)&b2[j0], bv1 = *(const float4*)&b2[j0 + 4];
        float bj[8] = {bv0.x, bv0.y, bv0.z, bv0.w, bv1.x, bv1.y, bv1.z, bv1.w};
#pragma unroll
        for (int e = 0; e < 4; e++)
#pragma unroll
            for (int jj = 0; jj < 8; jj++) acc[e][jj] = bj[jj];
        for (int c = 0; c < 16; c++) {
            float w[4][8];
#pragma unroll
            for (int rr = 0; rr < 4; rr++) {
                float4 a = *(const float4*)&W2[(c * 4 + rr) * 64 + j0];
                float4 bq = *(const float4*)&W2[(c * 4 + rr) * 64 + j0 + 4];
                w[rr][0] = a.x; w[rr][1] = a.y; w[rr][2] = a.z; w[rr][3] = a.w;
                w[rr][4] = bq.x; w[rr][5] = bq.y; w[rr][6] = bq.z; w[rr][7] = bq.w;
            }
#pragma unroll
            for (int e = 0; e < 4; e++) {
                const float4 xv = *(const float4*)&eA[ql][e * 72 + c * 4];
                const float xs[4] = {xv.x, xv.y, xv.z, xv.w};
#pragma unroll
                for (int rr = 0; rr < 4; rr++)
#pragma unroll
                    for (int jj = 0; jj < 8; jj++)
                        acc[e][jj] = fmaf(xs[rr], w[rr][jj], acc[e][jj]);
            }
        }
    }
    __syncthreads();
#pragma unroll
    for (int e = 0; e < 4; e++) {
        float4 h0 = make_float4(gelu_f(acc[e][0]), gelu_f(acc[e][1]),
                                gelu_f(acc[e][2]), gelu_f(acc[e][3]));
        float4 h1 = make_float4(gelu_f(acc[e][4]), gelu_f(acc[e][5]),
                                gelu_f(acc[e][6]), gelu_f(acc[e][7]));
        *(float4*)&eA[ql][e * 72 + j0] = h0;
        *(float4*)&eA[ql][e * 72 + j0 + 4] = h1;
    }
    __syncthreads();
    // ---------- layer 3: x[0..63], no activation; weighted partial sum
    float so[8];
#pragma unroll
    for (int jj = 0; jj < 8; jj++) so[jj] = 0.f;
    {
        float4 bv0 = *(const float4*)&b3[j0], bv1 = *(const float4*)&b3[j0 + 4];
        float bj[8] = {bv0.x, bv0.y, bv0.z, bv0.w, bv1.x, bv1.y, bv1.z, bv1.w};
#pragma unroll
        for (int e = 0; e < 4; e++)
#pragma unroll
            for (int jj = 0; jj < 8; jj++) acc[e][jj] = bj[jj];
        for (int c = 0; c < 16; c++) {
            float w[4][8];
#pragma unroll
            for (int rr = 0; rr < 4; rr++) {
                float4 a = *(const float4*)&W3[(c * 4 + rr) * 64 + j0];
                float4 bq = *(const float4*)&W3[(c * 4 + rr) * 64 + j0 + 4];
                w[rr][0] = a.x; w[rr][1] = a.y; w[rr][2] = a.z; w[rr][3] = a.w;
                w[rr][4] = bq.x; w[rr][5] = bq.y; w[rr][6] = bq.z; w[rr][7] = bq.w;
            }
#pragma unroll
            for (int e = 0; e < 4; e++) {
                const float4 xv = *(const float4*)&eA[ql][e * 72 + c * 4];
                const float xs[4] = {xv.x, xv.y, xv.z, xv.w};
#pragma unroll
                for (int rr = 0; rr < 4; rr++)
#pragma unroll
                    for (int jj = 0; jj < 8; jj++)
                        acc[e][jj] = fmaf(xs[rr], w[rr][jj], acc[e][jj]);
            }
        }
#pragma unroll
        for (int e = 0; e < 4; e++) {
            float wv = wtsQ[ql][e];
#pragma unroll
            for (int jj = 0; jj < 8; jj++) so[jj] = fmaf(wv, acc[e][jj], so[jj]);
        }
    }
    int gq = qw + ql;
    float* dst = &outacc[(long)gq * 64 + j0];
#pragma unroll
    for (int jj = 0; jj < 8; jj++) atomicAdd(&dst[jj], so[jj]);
}

// divide accumulated numerator by clamped weight sum (in place)
__global__ void __launch_bounds__(256) k_findiv(
    float* __restrict__ acc, const float* __restrict__ wsum) {
    long t = (long)blockIdx.x * 256 + threadIdx.x;
    acc[t] = acc[t] / wsum[t >> 6];
}

// ---------------------------------------------------------------- transpose (B,R,C) -> (B,C,R)
__global__ void k_transp(const float* __restrict__ src, float* __restrict__ dst, int R, int C) {
    __shared__ float t[32][33];
    int b = blockIdx.z;
    int c0 = blockIdx.x * 32, r0 = blockIdx.y * 32;
    int tx = threadIdx.x, ty0 = threadIdx.y;    // (32,8)
    for (int yy = ty0; yy < 32; yy += 8) {
        int r = r0 + yy, c = c0 + tx;
        if (r < R && c < C) t[yy][tx] = src[((long)b * R + r) * C + c];
    }
    __syncthreads();
    for (int yy = ty0; yy < 32; yy += 8) {
        int c = c0 + yy, r = r0 + tx;
        if (r < R && c < C) dst[((long)b * C + c) * R + r] = t[tx][yy];
    }
}

// ---------------------------------------------------------------- FNO: truncated forward DFT
__global__ void __launch_bounds__(1024) k_f1(const float* __restrict__ x, float* __restrict__ Xh) {
    int blk = blockIdx.x;    // b*64 + ch
    int tid = threadIdx.x;   // 1024
    __shared__ __align__(16) float img[4096];
    __shared__ float Tre[64][12], Tim[64][12];
    __shared__ float cs[64], sn[64];
    if (tid < 64) {
        double a = (2.0 * PI_ / 64.0) * (double)tid;
        cs[tid] = (float)cos(a);
        sn[tid] = (float)sin(a);
    }
    ((float4*)img)[tid] = ((const float4*)(x + (long)blk * 4096))[tid];
    __syncthreads();
    if (tid < 768) {                             // (h, c)
        int h = tid / 12, c = tid - 12 * h;
        float re = 0.f, im = 0.f;
        for (int w = 0; w < 64; w++) {
            float v = img[h * 64 + w];
            int k = (c * w) & 63;
            re = fmaf(v, cs[k], re);
            im = fmaf(-v, sn[k], im);
        }
        Tre[h][c] = re; Tim[h][c] = im;
    }
    __syncthreads();
    if (tid < 288) {                             // (x24, c12)
        int xx = tid / 12, c = tid - 12 * xx;
        int r = (xx < 12) ? xx : (xx + 40);
        float re = 0.f, im = 0.f;
        for (int h = 0; h < 64; h++) {
            int k = (r * h) & 63;
            float cr = cs[k], si = sn[k];
            float a = Tre[h][c], bb = Tim[h][c];
            re += a * cr + bb * si;
            im += bb * cr - a * si;
        }
        Xh[((long)blk * 288 + tid) * 2] = re;
        Xh[((long)blk * 288 + tid) * 2 + 1] = im;
    }
}

// mode-mix: Yhat[b,o,m] = sum_i Wc[i,o,m] * Xhat[b,i,m]
__global__ void __launch_bounds__(256) k_f2(const float* __restrict__ Xh, const float* __restrict__ s1,
                                            const float* __restrict__ s2, float* __restrict__ Yh) {
    int m = blockIdx.x;                  // 0..287
    int xx = m / 12, y = m - 12 * xx;
    const float* W; int xw;
    if (xx < 12) { W = s1; xw = xx; } else { W = s2; xw = xx - 12; }
    __shared__ float xr[128], xi[128];
    __shared__ float pr[256], pi[256];
    int tid = threadIdx.x;               // 256
    if (tid < 128) {
        int bb = tid >> 6, i = tid & 63;
        xr[tid] = Xh[(((long)bb * 64 + i) * 288 + m) * 2];
        xi[tid] = Xh[(((long)bb * 64 + i) * 288 + m) * 2 + 1];
    }
    __syncthreads();
    int half = tid >> 7;
    int t2 = tid & 127;
    int bb = t2 >> 6, o = t2 & 63;
    float re = 0.f, im = 0.f;
    for (int i = half * 32; i < half * 32 + 32; i++) {
        long wb = (long)i * 18432 + (long)o * 288 + xw * 24 + y * 2;
        float wr = W[wb], wi = W[wb + 1];
        float a = xr[bb * 64 + i], cc = xi[bb * 64 + i];
        re += a * wr - cc * wi;
        im += a * wi + cc * wr;
    }
    pr[tid] = re; pi[tid] = im;
    __syncthreads();
    if (tid < 128) {
        float re2 = pr[tid] + pr[tid + 128];
        float im2 = pi[tid] + pi[tid + 128];
        Yh[(((long)bb * 64 + o) * 288 + m) * 2] = re2;
        Yh[(((long)bb * 64 + o) * 288 + m) * 2 + 1] = im2;
    }
}

// inverse DFT + pointwise conv + bias + InstanceNorm + GELU, fused per (b, out-channel)
__global__ void __launch_bounds__(1024) k_f3(const float* __restrict__ Yh, const float* __restrict__ x,
                                             const float* __restrict__ pwW, const float* __restrict__ pwb,
                                             float* __restrict__ xo) {
    int blk = blockIdx.x;
    int b = blk >> 6, o = blk & 63;
    int tid = threadIdx.x;   // 1024; each thread owns 4 consecutive pixels
    __shared__ float yre[288], yim[288];
    __shared__ float Qre[64][12], Qim[64][12];
    __shared__ float cs[64], sn[64];
    __shared__ float red[1024];
    if (tid < 64) {
        double a = (2.0 * PI_ / 64.0) * (double)tid;
        cs[tid] = (float)cos(a);
        sn[tid] = (float)sin(a);
    }
    if (tid < 288) {
        yre[tid] = Yh[((long)blk * 288 + tid) * 2];
        yim[tid] = Yh[((long)blk * 288 + tid) * 2 + 1];
    }
    __syncthreads();
    if (tid < 768) {    // (h, c): complex ifft along rows (1/64 scale)
        int h = tid / 12, c = tid - 12 * h;
        float re = 0.f, im = 0.f;
#pragma unroll
        for (int xx = 0; xx < 24; xx++) {
            int r = (xx < 12) ? xx : (xx + 40);
            int k = (r * h) & 63;
            float wr = cs[k], wi = sn[k];
            float a = yre[xx * 12 + c], bb = yim[xx * 12 + c];
            re += a * wr - bb * wi;
            im += a * wi + bb * wr;
        }
        Qre[h][c] = re * (1.0f / 64.0f);
        Qim[h][c] = im * (1.0f / 64.0f);
    }
    __syncthreads();
    float bias = pwb[o];
    int h = tid >> 4;
    int w0 = (tid & 15) * 4;
    float sp0, sp1, sp2, sp3;
    {
        float base = Qre[h][0];
        sp0 = sp1 = sp2 = sp3 = base;
#pragma unroll
        for (int c = 1; c < 12; c++) {
            float qr = Qre[h][c], qi = Qim[h][c];
            int k0 = (c * w0) & 63, k1 = (c * (w0 + 1)) & 63;
            int k2 = (c * (w0 + 2)) & 63, k3 = (c * (w0 + 3)) & 63;
            sp0 += 2.0f * (qr * cs[k0] - qi * sn[k0]);
            sp1 += 2.0f * (qr * cs[k1] - qi * sn[k1]);
            sp2 += 2.0f * (qr * cs[k2] - qi * sn[k2]);
            sp3 += 2.0f * (qr * cs[k3] - qi * sn[k3]);
        }
    }
    float a0 = sp0 * (1.0f / 64.0f) + bias;
    float a1 = sp1 * (1.0f / 64.0f) + bias;
    float a2 = sp2 * (1.0f / 64.0f) + bias;
    float a3 = sp3 * (1.0f / 64.0f) + bias;
    const float* xb = x + ((long)b * 64) * 4096 + tid * 4;
    for (int i = 0; i < 64; i++) {
        float wv = pwW[o * 64 + i];
        const float4 xv = *(const float4*)(xb + (long)i * 4096);
        a0 = fmaf(xv.x, wv, a0);
        a1 = fmaf(xv.y, wv, a1);
        a2 = fmaf(xv.z, wv, a2);
        a3 = fmaf(xv.w, wv, a3);
    }
    red[tid] = a0 + a1 + a2 + a3;
    __syncthreads();
    for (int d = 512; d > 0; d >>= 1) { if (tid < d) red[tid] += red[tid + d]; __syncthreads(); }
    float mu = red[0] * (1.0f / 4096.0f);
    __syncthreads();
    float d0 = a0 - mu, d1 = a1 - mu, d2 = a2 - mu, d3 = a3 - mu;
    red[tid] = d0 * d0 + d1 * d1 + d2 * d2 + d3 * d3;
    __syncthreads();
    for (int d = 512; d > 0; d >>= 1) { if (tid < d) red[tid] += red[tid + d]; __syncthreads(); }
    float var = red[0] * (1.0f / 4096.0f);
    float inv = 1.0f / sqrtf(var + 1e-5f);
    float4 ov = make_float4(gelu_f(d0 * inv), gelu_f(d1 * inv), gelu_f(d2 * inv), gelu_f(d3 * inv));
    *(float4*)&xo[(long)blk * 4096 + tid * 4] = ov;
}

// ---------------------------------------------------------------- projection MLP (64 -> 64 -> 3)
__global__ void __launch_bounds__(256) k_proj(
    const float* __restrict__ y, const float* __restrict__ W1, const float* __restrict__ b1,
    const float* __restrict__ W2, const float* __restrict__ b2, float* __restrict__ out) {
    __shared__ __align__(16) float yr[4][64];
    __shared__ float h[4][64];
    int ql = threadIdx.x >> 6, j = threadIdx.x & 63;
    long node = (long)blockIdx.x * 4 + ql;
    yr[ql][j] = y[node * 64 + j];
    __syncthreads();
    float a = b1[j];
    for (int k = 0; k < 64; k += 4) {
        float w0 = W1[(k + 0) * 64 + j], w1 = W1[(k + 1) * 64 + j];
        float w2 = W1[(k + 2) * 64 + j], w3 = W1[(k + 3) * 64 + j];
        const float4 hv = *(const float4*)&yr[ql][k];
        a = fmaf(hv.x, w0, fmaf(hv.y, w1, fmaf(hv.z, w2, fmaf(hv.w, w3, a))));
    }
    h[ql][j] = gelu_f(a);
    __syncthreads();
    if (j < 3) {
        float a2 = b2[j];
        for (int k = 0; k < 64; k++) a2 = fmaf(h[ql][k], W2[k * 3 + j], a2);
        out[node * 3 + j] = a2;
    }
}

// ---------------------------------------------------------------- launch
extern "C" void kernel_launch(void* const* d_in, const int* in_sizes, int n_in,
                              void* d_out, int out_size, void* d_ws, size_t ws_size,
                              hipStream_t stream) {
    (void)in_sizes; (void)n_in; (void)out_size; (void)ws_size;
    const float* coords   = (const float*)d_in[0];
    const float* features = (const float*)d_in[1];
    const float* lift_W1 = (const float*)d_in[2];
    const float* lift_b1 = (const float*)d_in[3];
    const float* lift_W2 = (const float*)d_in[4];
    const float* lift_b2 = (const float*)d_in[5];
    const float* gin_W1 = (const float*)d_in[6];
    const float* gin_b1 = (const float*)d_in[7];
    const float* gin_W2 = (const float*)d_in[8];
    const float* gin_b2 = (const float*)d_in[9];
    const float* gin_W3 = (const float*)d_in[10];
    const float* gin_b3 = (const float*)d_in[11];
    const float* spec1 = (const float*)d_in[12];
    const float* spec2 = (const float*)d_in[13];
    const float* pw_W  = (const float*)d_in[14];
    const float* pw_b  = (const float*)d_in[15];
    const float* gout_W1 = (const float*)d_in[16];
    const float* gout_b1 = (const float*)d_in[17];
    const float* gout_W2 = (const float*)d_in[18];
    const float* gout_b2 = (const float*)d_in[19];
    const float* gout_W3 = (const float*)d_in[20];
    const float* gout_b3 = (const float*)d_in[21];
    const float* proj_W1 = (const float*)d_in[22];
    const float* proj_b1 = (const float*)d_in[23];
    const float* proj_W2 = (const float*)d_in[24];
    const float* proj_b2 = (const float*)d_in[25];

    char* ws = (char*)d_ws;
    size_t off = 0;
    auto alloc = [&](size_t bytes) -> char* {
        char* p = ws + off;
        off = (off + bytes + 255) & ~(size_t)255;
        return p;
    };
    float4* grid_pack = (float4*)alloc((size_t)NG * 16);
    float*  feat      = (float*)alloc((size_t)B_ * N_ * 64 * 4);
    int*    bin_cnt   = (int*)alloc((size_t)B_ * 4096 * 4);
    int*    bin_fill  = (int*)alloc((size_t)B_ * 4096 * 4);
    int*    bin_off   = (int*)alloc((size_t)B_ * 4097 * 4);
    float4* srt       = (float4*)alloc((size_t)B_ * N_ * 16);
    int*    idx_in    = (int*)alloc((size_t)B_ * NG * 16 * 4);
    float*  dist_in   = (float*)alloc((size_t)B_ * NG * 16 * 4);
    float*  lastd_in  = (float*)alloc((size_t)B_ * NG * 4);
    float*  sig_in    = (float*)alloc(256);
    float*  wtsb_in   = (float*)alloc((size_t)B_ * NG * 16 * 4);
    float*  wsum_in   = (float*)alloc((size_t)B_ * NG * 4);
    float*  gout_buf  = (float*)alloc((size_t)B_ * NG * 64 * 4);
    float*  xb0       = (float*)alloc((size_t)B_ * 64 * NG * 4);
    float*  xb1       = (float*)alloc((size_t)B_ * 64 * NG * 4);
    float*  Xh        = (float*)alloc((size_t)B_ * 64 * 288 * 2 * 4);
    float*  Yh        = (float*)alloc((size_t)B_ * 64 * 288 * 2 * 4);
    float*  g2        = (float*)alloc((size_t)B_ * NG * 64 * 4);
    int*    idx_out   = (int*)alloc((size_t)B_ * N_ * 16 * 4);
    float*  dist_out  = (float*)alloc((size_t)B_ * N_ * 16 * 4);
    float*  lastd_out = (float*)alloc((size_t)B_ * N_ * 4);
    float*  sig_out   = (float*)alloc(256);
    float*  wtsb_out  = (float*)alloc((size_t)B_ * N_ * 16 * 4);
    float*  wsum_out  = (float*)alloc((size_t)B_ * N_ * 4);
    float*  ybuf      = (float*)alloc((size_t)B_ * N_ * 64 * 4);

    hipMemsetAsync(bin_cnt, 0, (size_t)B_ * 4096 * 4, stream);
    hipMemsetAsync(bin_fill, 0, (size_t)B_ * 4096 * 4, stream);
    hipMemsetAsync(gout_buf, 0, (size_t)B_ * NG * 64 * 4, stream);
    hipMemsetAsync(ybuf, 0, (size_t)B_ * N_ * 64 * 4, stream);

    k_gridgen<<<NG / 256, 256, 0, stream>>>(grid_pack);
    k_lift<<<(B_ * N_) / 4, 256, 0, stream>>>(features, lift_W1, lift_b1, lift_W2, lift_b2, feat);
    k_bincount<<<(B_ * N_) / 256, 256, 0, stream>>>((const float2*)coords, bin_cnt);
    k_binscan<<<B_, 1024, 0, stream>>>(bin_cnt, bin_off);
    k_binscatter<<<(B_ * N_) / 256, 256, 0, stream>>>((const float2*)coords, bin_off, bin_fill, srt);
    k_knn_in<<<(B_ * NG * 64) / 256, 256, 0, stream>>>(grid_pack, srt, bin_off, idx_in, dist_in, lastd_in);
    k_median3<<<1, 1024, 0, stream>>>(lastd_in, B_ * NG, sig_in);
    k_wts<<<(B_ * NG) / 256, 256, 0, stream>>>(dist_in, sig_in, wtsb_in, wsum_in, B_ * NG);
    k_edge<0><<<(B_ * NG / 8) * 4, 64, 0, stream>>>(idx_in, dist_in, wtsb_in, (const float2*)coords,
        grid_pack, feat, gin_W1, gin_b1, gin_W2, gin_b2, gin_W3, gin_b3, gout_buf, NG, N_);
    k_findiv<<<(B_ * NG * 64) / 256, 256, 0, stream>>>(gout_buf, wsum_in);
    {
        dim3 g(64 / 32, NG / 32, B_); dim3 t(32, 8);
        k_transp<<<g, t, 0, stream>>>(gout_buf, xb0, NG, 64);
    }
    float* xc = xb0; float* xn = xb1;
    for (int d = 0; d < 3; d++) {
        k_f1<<<B_ * 64, 1024, 0, stream>>>(xc, Xh);
        k_f2<<<288, 256, 0, stream>>>(Xh, spec1 + (size_t)d * 1179648, spec2 + (size_t)d * 1179648, Yh);
        k_f3<<<B_ * 64, 1024, 0, stream>>>(Yh, xc, pw_W + (size_t)d * 4096, pw_b + (size_t)d * 64, xn);
        float* tmp = xc; xc = xn; xn = tmp;
    }
    {
        dim3 g(NG / 32, 64 / 32, B_); dim3 t(32, 8);
        k_transp<<<g, t, 0, stream>>>(xc, g2, 64, NG);
    }
    k_knn_out<<<(B_ * N_ * 64) / 256, 256, 0, stream>>>((const float2*)coords, grid_pack, idx_out, dist_out, lastd_out);
    k_median3<<<1, 1024, 0, stream>>>(lastd_out, B_ * N_, sig_out);
    k_wts<<<(B_ * N_) / 256, 256, 0, stream>>>(dist_out, sig_out, wtsb_out, wsum_out, B_ * N_);
    k_edge<1><<<(B_ * N_ / 8) * 4, 64, 0, stream>>>(idx_out, dist_out, wtsb_out, (const float2*)coords,
        grid_pack, g2, gout_W1, gout_b1, gout_W2, gout_b2, gout_W3, gout_b3, ybuf, N_, NG);
    k_findiv<<<(B_ * N_ * 64) / 256, 256, 0, stream>>>(ybuf, wsum_out);
    k_proj<<<(B_ * N_) / 4, 256, 0, stream>>>(ybuf, proj_W1, proj_b1, proj_W2, proj_b2, (float*)d_out);
}

// Round 6
// 618.626 us; speedup vs baseline: 1.5495x; 1.0375x over previous
//
#include <hip/hip_runtime.h>
#include <math.h>

#define B_ 2
#define N_ 8192          // points per batch
#define G_ 64
#define NG 4096          // G*G latent grid points
#define WID_ 64
#define K_ 16
#define CIN_ 6
#define COUT_ 3
#define PI_ 3.14159265358979323846

typedef unsigned long long u64k;

// ---------------------------------------------------------------- helpers
__device__ __forceinline__ float gelu_f(float x) {
    return 0.5f * x * (1.0f + erff(x * 0.70710678118654752440f));
}
__device__ __forceinline__ int cellof(float v) {
    int c = (int)floorf((v + 1.0f) * 32.0f);
    return min(63, max(0, c));
}
__device__ __forceinline__ u64k umin64(u64k a, u64k b) { return a < b ? a : b; }
__device__ __forceinline__ u64k umax64(u64k a, u64k b) { return a < b ? b : a; }
__device__ __forceinline__ u64k shflxor64(u64k v, int m) {
    return (u64k)__shfl_xor((long long)v, m, 64);
}
__device__ __forceinline__ void bsort64(u64k& key, int lane) {
#pragma unroll
    for (int sz = 2; sz <= 64; sz <<= 1) {
#pragma unroll
        for (int j = sz >> 1; j >= 1; j >>= 1) {
            u64k o = shflxor64(key, j);
            bool keep_min = ((lane & j) == 0) == ((lane & sz) == 0);
            key = keep_min ? umin64(key, o) : umax64(key, o);
        }
    }
}
__device__ __forceinline__ void bmerge_into(u64k& R, u64k key, int lane) {
    u64k o = shflxor64(key, 63);
    u64k L = umin64(R, o);
#pragma unroll
    for (int j = 32; j >= 1; j >>= 1) {
        u64k t = shflxor64(L, j);
        L = ((lane & j) == 0) ? umin64(L, t) : umax64(L, t);
    }
    R = L;
}

// ---------------------------------------------------------------- grid gen
__global__ void k_gridgen(float4* gp) {
    int p = blockIdx.x * blockDim.x + threadIdx.x;
    if (p >= NG) return;
    int i = p >> 6, j = p & 63;
    double st = 2.0 / 63.0;
    float gx = (i == 63) ? 1.0f : (float)(-1.0 + st * (double)i);
    float gy = (j == 63) ? 1.0f : (float)(-1.0 + st * (double)j);
    float s2 = __fadd_rn(__fmul_rn(gx, gx), __fmul_rn(gy, gy));
    gp[p] = make_float4(gx, gy, s2, 0.f);
}

// ---------------------------------------------------------------- lift MLP
__global__ void __launch_bounds__(256) k_lift(
    const float* __restrict__ fin, const float* __restrict__ W1,
    const float* __restrict__ b1, const float* __restrict__ W2,
    const float* __restrict__ b2, float* __restrict__ fout) {
    __shared__ float xr[4][8];
    __shared__ __align__(16) float h[4][64];
    int ql = threadIdx.x >> 6, j = threadIdx.x & 63;
    int node = blockIdx.x * 4 + ql;
    if (j < CIN_) xr[ql][j] = fin[node * CIN_ + j];
    __syncthreads();
    float a = b1[j];
#pragma unroll
    for (int i = 0; i < CIN_; i++) a = fmaf(xr[ql][i], W1[i * 64 + j], a);
    h[ql][j] = gelu_f(a);
    __syncthreads();
    float a2 = b2[j];
    for (int k = 0; k < 64; k += 4) {
        float w0 = W2[(k + 0) * 64 + j], w1 = W2[(k + 1) * 64 + j];
        float w2 = W2[(k + 2) * 64 + j], w3 = W2[(k + 3) * 64 + j];
        const float4 hv = *(const float4*)&h[ql][k];
        a2 = fmaf(hv.x, w0, fmaf(hv.y, w1, fmaf(hv.z, w2, fmaf(hv.w, w3, a2))));
    }
    fout[node * 64 + j] = a2;
}

// ---------------------------------------------------------------- binning
__global__ void k_bincount(const float2* __restrict__ coords, int* __restrict__ cnt) {
    int t = blockIdx.x * blockDim.x + threadIdx.x;
    if (t >= B_ * N_) return;
    float2 c = coords[t];
    int b = t >> 13;
    int cell = cellof(c.x) * 64 + cellof(c.y);
    atomicAdd(&cnt[b * 4096 + cell], 1);
}
__global__ void k_binscan(const int* __restrict__ cnt, int* __restrict__ offs) {
    int b = blockIdx.x, t = threadIdx.x;    // 1024 threads
    __shared__ int s[1024];
    int4 v = ((const int4*)(cnt + b * 4096))[t];
    int sum = v.x + v.y + v.z + v.w;
    s[t] = sum;
    __syncthreads();
    for (int d = 1; d < 1024; d <<= 1) {
        int x = (t >= d) ? s[t - d] : 0;
        __syncthreads();
        s[t] += x;
        __syncthreads();
    }
    int incl = s[t], excl = incl - sum;
    int* ob = offs + b * 4097;
    ob[4 * t] = excl; ob[4 * t + 1] = excl + v.x;
    ob[4 * t + 2] = excl + v.x + v.y; ob[4 * t + 3] = excl + v.x + v.y + v.z;
    if (t == 1023) ob[4096] = incl;
}
__global__ void k_binscatter(const float2* __restrict__ coords, const int* __restrict__ offs,
                             int* __restrict__ fill, float4* __restrict__ srt) {
    int t = blockIdx.x * blockDim.x + threadIdx.x;
    if (t >= B_ * N_) return;
    float2 c = coords[t];
    int b = t >> 13, n = t & 8191;
    int cell = cellof(c.x) * 64 + cellof(c.y);
    int pos = offs[b * 4097 + cell] + atomicAdd(&fill[b * 4096 + cell], 1);
    float s2 = __fadd_rn(__fmul_rn(c.x, c.x), __fmul_rn(c.y, c.y));
    srt[b * N_ + pos] = make_float4(c.x, c.y, s2, __int_as_float(n));
}

// ---------------------------------------------------------------- kNN grid->points: one wave per query
__global__ void __launch_bounds__(256) k_knn_in(
    const float4* __restrict__ gp, const float4* __restrict__ srt,
    const int* __restrict__ offs, int* __restrict__ oidx,
    float* __restrict__ odist, float* __restrict__ lastd) {
    int lane = threadIdx.x & 63;
    int w = (blockIdx.x * blockDim.x + threadIdx.x) >> 6;
    int b = w >> 12, p = w & 4095;
    float4 q = gp[p];
    float qx = q.x, qy = q.y, q2 = q.z;
    int cqx = cellof(qx), cqy = cellof(qy);
    const float4* S = srt + b * N_;
    const int* OF = offs + b * 4097;

    u64k R = ~0ull;
    u64k pend = ~0ull;
    int fill = 0;

    auto flush = [&]() {
        bsort64(pend, lane);
        bmerge_into(R, pend, lane);
        pend = ~0ull;
        fill = 0;
    };
    auto feed = [&](int s0, int s1) {
        int cnt = s1 - s0;
        while (cnt > 0) {
            int take = min(cnt, 64 - fill);
            int t = lane - fill;
            if (t >= 0 && t < take) {
                float4 sp = S[s0 + t];
                float dot = __fadd_rn(__fmul_rn(qx, sp.x), __fmul_rn(qy, sp.y));
                float d2 = __fsub_rn(__fadd_rn(q2, sp.z), 2.0f * dot);
                d2 = fmaxf(d2, 0.0f);
                pend = ((u64k)__float_as_uint(d2) << 32) | (unsigned)__float_as_int(sp.w);
            }
            fill += take; s0 += take; cnt -= take;
            if (fill == 64) flush();
        }
    };

    {
        int xa = max(cqx - 2, 0), xb = min(cqx + 2, 63);
        int ya = max(cqy - 2, 0), yb = min(cqy + 2, 63);
        for (int cx = xa; cx <= xb; cx++) feed(OF[cx * 64 + ya], OF[cx * 64 + yb + 1]);
    }
    int r = 2;
    while (true) {
        if (fill) flush();
        u64k T = (u64k)__shfl((long long)R, 15, 64);
        float d16 = __uint_as_float((unsigned)(T >> 32));
        float bm = (float)r * 0.03125f;
        if (d16 < bm * bm - 1e-5f) break;
        if (cqx - r <= 0 && cqx + r >= 63 && cqy - r <= 0 && cqy + r >= 63) break;
        r++;
        int ya = max(cqy - r, 0), yb = min(cqy + r, 63);
        if (cqx - r >= 0)  { int c0 = (cqx - r) * 64; feed(OF[c0 + ya], OF[c0 + yb + 1]); }
        if (cqx + r <= 63) { int c0 = (cqx + r) * 64; feed(OF[c0 + ya], OF[c0 + yb + 1]); }
        int xa2 = max(cqx - r + 1, 0), xb2 = min(cqx + r - 1, 63);
        for (int cx = xa2; cx <= xb2; cx++) {
            if (cqy - r >= 0)  { int cc = cx * 64 + cqy - r; feed(OF[cc], OF[cc + 1]); }
            if (cqy + r <= 63) { int cc = cx * 64 + cqy + r; feed(OF[cc], OF[cc + 1]); }
        }
    }
    if (lane < 16) {
        float d2 = __uint_as_float((unsigned)(R >> 32));
        float d = sqrtf(d2);
        oidx[w * 16 + lane] = (int)(unsigned)(R & 0xffffffffu);
        odist[w * 16 + lane] = d;
        if (lane == 15) lastd[w] = d;
    }
}

// ---------------------------------------------------------------- kNN points->grid: one wave per query
__global__ void __launch_bounds__(256) k_knn_out(
    const float2* __restrict__ coords, const float4* __restrict__ gp,
    int* __restrict__ oidx, float* __restrict__ odist, float* __restrict__ lastd) {
    int lane = threadIdx.x & 63;
    int w = (blockIdx.x * blockDim.x + threadIdx.x) >> 6;
    float2 c = coords[w];
    float qx = c.x, qy = c.y;
    float q2 = __fadd_rn(__fmul_rn(qx, qx), __fmul_rn(qy, qy));
    int i0 = (int)floorf((qx + 1.0f) * 31.5f);
    int j0 = (int)floorf((qy + 1.0f) * 31.5f);
    int li = min(max(i0 - 3, 0), 56);
    int lj = min(max(j0 - 3, 0), 56);
    int p = (li + (lane >> 3)) * 64 + (lj + (lane & 7));
    float4 sp = gp[p];
    float dot = __fadd_rn(__fmul_rn(qx, sp.x), __fmul_rn(qy, sp.y));
    float d2 = fmaxf(__fsub_rn(__fadd_rn(q2, sp.z), 2.0f * dot), 0.0f);
    u64k key = ((u64k)__float_as_uint(d2) << 32) | (unsigned)p;
    bsort64(key, lane);
    if (lane < 16) {
        float dd = sqrtf(__uint_as_float((unsigned)(key >> 32)));
        oidx[w * 16 + lane] = (int)(unsigned)(key & 0xffffffffu);
        odist[w * 16 + lane] = dd;
        if (lane == 15) lastd[w] = dd;
    }
}

// ---------------------------------------------------------------- exact lower-median via 32-step bisection on float bits
// vals >= 0 so uint order == float order. n multiple of 1024, n/1024 <= 16.
// Finds the rank-(n-1)/2 order statistic exactly. Values held in registers.
__global__ void __launch_bounds__(1024) k_median_bis(
    const float* __restrict__ vals, int n, float* __restrict__ sig) {
    __shared__ int wred[16];
    __shared__ unsigned s_bcast;
    int tid = threadIdx.x;
    int lane = tid & 63, wv = tid >> 6;
    int cnt_per = n >> 10;           // 8 or 16
    unsigned v[16];
    for (int i = 0; i < cnt_per; i++) v[i] = __float_as_uint(vals[tid + (i << 10)]);
    int r = (n - 1) >> 1;
    unsigned prefix = 0;
    for (int bit = 31; bit >= 0; bit--) {
        unsigned cand = prefix | (1u << bit);
        int c = 0;
        for (int i = 0; i < cnt_per; i++) c += (v[i] < cand) ? 1 : 0;
        for (int o = 32; o >= 1; o >>= 1) c += __shfl_down(c, o, 64);
        if (lane == 0) wred[wv] = c;
        __syncthreads();
        if (tid == 0) {
            int tot = 0;
            for (int k = 0; k < 16; k++) tot += wred[k];
            s_bcast = (tot <= r) ? cand : prefix;
        }
        __syncthreads();
        prefix = s_bcast;
        __syncthreads();
    }
    if (tid == 0) *sig = fmaxf(__uint_as_float(prefix), 1e-6f);
}

// ---------------------------------------------------------------- precompute weights + clamped sum per query
__global__ void __launch_bounds__(256) k_wts(
    const float* __restrict__ distb, const float* __restrict__ sigp,
    float* __restrict__ wtsb, float* __restrict__ wsum, int tot) {
    int t = blockIdx.x * blockDim.x + threadIdx.x;
    if (t >= tot) return;
    float sig = *sigp;
    float s = 0.f;
#pragma unroll
    for (int e = 0; e < 16; e++) {
        float w = expf(-distb[t * 16 + e] / sig);
        wtsb[t * 16 + e] = w;
        s += w;
    }
    wsum[t] = fmaxf(s, 1e-6f);
}

// ---------------------------------------------------------------- edge MLP + weighted aggregation (v3)
// One block (4 waves, 256 thr) per 8 queries; wave wv owns edge slice wv*4..+3.
// Weights staged per-layer into LDS (row-7-zero trick removes the W1 branch);
// inner loop = broadcast ds_read_b128 + FMA. Partials combined via LDS
// reduction; final store divides by precomputed wsum. No atomics, no memset.
// LDS: eA 8x1156 (36.9 KB, stride%32==4 -> conflict-free broadcasts)
//    + wS 72x64 (18 KB, reused as 4x8x64 reduction buffer) ~= 56.5 KB
// -> 2 blocks/CU (8 waves/CU).
template <int MODE>
__global__ void __launch_bounds__(256, 2) k_edge(
    const int* __restrict__ idxb, const float* __restrict__ distb,
    const float* __restrict__ wtsb, const float* __restrict__ wsump,
    const float2* __restrict__ coords, const float4* __restrict__ gp,
    const float* __restrict__ feats,
    const float* __restrict__ W1, const float* __restrict__ b1,
    const float* __restrict__ W2, const float* __restrict__ b2,
    const float* __restrict__ W3, const float* __restrict__ b3,
    float* __restrict__ outb, int Nq, int srcRows) {
    __shared__ __align__(16) float eA[8 * 1156];   // 8 q x (16 edges x 72) + pad
    __shared__ __align__(16) float wS[72 * 64];    // staged layer weights / reduction
    __shared__ float wtsQ[8][16];
    __shared__ int   nidxQ[8][16];
    __shared__ float wsumS[8];
    const int tid = threadIdx.x;
    const int wv = tid >> 6, lane = tid & 63;
    const int ql = lane >> 3, jg = lane & 7, j0 = jg * 8;
    const int e0 = wv * 4;                 // this wave's first edge
    const int qw = blockIdx.x * 8;

    // ---- metadata + geometry (128 (q,e) pairs)
    if (tid < 128) {
        int q = tid >> 4, e = tid & 15;
        int gq = qw + q;
        int b = gq / Nq, p = gq - b * Nq;
        int si = idxb[gq * 16 + e];
        float d = distb[gq * 16 + e];
        nidxQ[q][e] = si;
        wtsQ[q][e] = wtsb[gq * 16 + e];
        float qx, qy, sx, sy;
        if (MODE == 0) {
            float4 g = gp[p]; qx = g.x; qy = g.y;
            float2 cc = coords[(long)b * srcRows + si]; sx = cc.x; sy = cc.y;
        } else {
            float2 cc = coords[(long)b * Nq + p]; qx = cc.x; qy = cc.y;
            float4 g = gp[si]; sx = g.x; sy = g.y;
        }
        float* row = &eA[q * 1156 + e * 72];
        row[0] = qx; row[1] = qy; row[2] = sx; row[3] = sy;
        row[4] = qx - sx; row[5] = qy - sy; row[6] = d; row[7] = 0.f;
    }
    if (tid >= 128 && tid < 136) wsumS[tid - 128] = wsump[qw + tid - 128];
    __syncthreads();
    // ---- feats gather: 128 rows x 16 float4 = 2048 slots
    for (int it = 0; it < 8; it++) {
        int slot = it * 256 + tid;
        int rowi = slot >> 4, f4 = slot & 15;
        int q = rowi >> 4, e = rowi & 15;
        int gq = qw + q;
        int b = gq / Nq;
        int si = nidxQ[q][e];
        const float4 v = *(const float4*)&feats[((long)b * srcRows + si) * 64 + f4 * 4];
        *(float4*)&eA[q * 1156 + e * 72 + 8 + f4 * 4] = v;
    }
    // ---- stage W1 (72 rows; row 7 = zeros, rows 8..71 <- W1 rows 7..70)
    for (int idx = tid; idx < 1152; idx += 256) {
        int t = idx >> 4, c4 = idx & 15;
        float4 v;
        if (t == 7) v = make_float4(0.f, 0.f, 0.f, 0.f);
        else        v = *(const float4*)&W1[(t - (t > 6)) * 64 + c4 * 4];
        *(float4*)&wS[t * 64 + c4 * 4] = v;
    }
    __syncthreads();

    const float* myA = &eA[ql * 1156 + e0 * 72];
    float acc[4][8];
    // ---------- layer 1: x[0..71]
    {
        float4 bv0 = *(const float4*)&b1[j0], bv1 = *(const float4*)&b1[j0 + 4];
        float bj[8] = {bv0.x, bv0.y, bv0.z, bv0.w, bv1.x, bv1.y, bv1.z, bv1.w};
#pragma unroll
        for (int e = 0; e < 4; e++)
#pragma unroll
            for (int jj = 0; jj < 8; jj++) acc[e][jj] = bj[jj];
        for (int c = 0; c < 18; c++) {
            float w[4][8];
#pragma unroll
            for (int rr = 0; rr < 4; rr++) {
                float4 a = *(const float4*)&wS[(c * 4 + rr) * 64 + j0];
                float4 bq = *(const float4*)&wS[(c * 4 + rr) * 64 + j0 + 4];
                w[rr][0] = a.x; w[rr][1] = a.y; w[rr][2] = a.z; w[rr][3] = a.w;
                w[rr][4] = bq.x; w[rr][5] = bq.y; w[rr][6] = bq.z; w[rr][7] = bq.w;
            }
#pragma unroll
            for (int e = 0; e < 4; e++) {
                const float4 xv = *(const float4*)&myA[e * 72 + c * 4];
                const float xs[4] = {xv.x, xv.y, xv.z, xv.w};
#pragma unroll
                for (int rr = 0; rr < 4; rr++)
#pragma unroll
                    for (int jj = 0; jj < 8; jj++)
                        acc[e][jj] = fmaf(xs[rr], w[rr][jj], acc[e][jj]);
            }
        }
    }
    __syncthreads();        // all waves done reading W1 region
#pragma unroll
    for (int e = 0; e < 4; e++) {
        float4 h0 = make_float4(gelu_f(acc[e][0]), gelu_f(acc[e][1]),
                                gelu_f(acc[e][2]), gelu_f(acc[e][3]));
        float4 h1 = make_float4(gelu_f(acc[e][4]), gelu_f(acc[e][5]),
                                gelu_f(acc[e][6]), gelu_f(acc[e][7]));
        *(float4*)&eA[ql * 1156 + (e0 + e) * 72 + j0] = h0;
        *(float4*)&eA[ql * 1156 + (e0 + e) * 72 + j0 + 4] = h1;
    }
    // ---- stage W2
    for (int idx = tid; idx < 1024; idx += 256) {
        int t = idx >> 4, c4 = idx & 15;
        *(float4*)&wS[t * 64 + c4 * 4] = *(const float4*)&W2[t * 64 + c4 * 4];
    }
    __syncthreads();
    // ---------- layer 2: x[0..63]
    {
        float4 bv0 = *(const float4*)&b2[j0], bv1 = *(const float4*)&b2[j0 + 4];
        float bj[8] = {bv0.x, bv0.y, bv0.z, bv0.w, bv1.x, bv1.y, bv1.z, bv1.w};
#pragma unroll
        for (int e = 0; e < 4; e++)
#pragma unroll
            for (int jj = 0; jj < 8; jj++) acc[e][jj] = bj[jj];
        for (int c = 0; c < 16; c++) {
            float w[4][8];
#pragma unroll
            for (int rr = 0; rr < 4; rr++) {
                float4 a = *(const float4*)&wS[(c * 4 + rr) * 64 + j0];
                float4 bq = *(const float4*)&wS[(c * 4 + rr) * 64 + j0 + 4];
                w[rr][0] = a.x; w[rr][1] = a.y; w[rr][2] = a.z; w[rr][3] = a.w;
                w[rr][4] = bq.x; w[rr][5] = bq.y; w[rr][6] = bq.z; w[rr][7] = bq.w;
            }
#pragma unroll
            for (int e = 0; e < 4; e++) {
                const float4 xv = *(const float4*)&myA[e * 72 + c * 4];
                const float xs[4] = {xv.x, xv.y, xv.z, xv.w};
#pragma unroll
                for (int rr = 0; rr < 4; rr++)
#pragma unroll
                    for (int jj = 0; jj < 8; jj++)
                        acc[e][jj] = fmaf(xs[rr], w[rr][jj], acc[e][jj]);
            }
        }
    }
    __syncthreads();
#pragma unroll
    for (int e = 0; e < 4; e++) {
        float4 h0 = make_float4(gelu_f(acc[e][0]), gelu_f(acc[e][1]),
                                gelu_f(acc[e][2]), gelu_f(acc[e][3]));
        float4 h1 = make_float4(gelu_f(acc[e][4]), gelu_f(acc[e][5]),
                                gelu_f(acc[e][6]), gelu_f(acc[e][7]));
        *(float4*)&eA[ql * 1156 + (e0 + e) * 72 + j0] = h0;
        *(float4*)&eA[ql * 1156 + (e0 + e) * 72 + j0 + 4] = h1;
    }
    // ---- stage W3
    for (int idx = tid; idx < 1024; idx += 256) {
        int t = idx >> 4, c4 = idx & 15;
        *(float4*)&wS[t * 64 + c4 * 4] = *(const float4*)&W3[t * 64 + c4 * 4];
    }
    __syncthreads();
    // ---------- layer 3: x[0..63], no activation; weighted partial sum
    float so[8];
#pragma unroll
    for (int jj = 0; jj < 8; jj++) so[jj] = 0.f;
    {
        float4 bv0 = *(const float4*)&b3[j0], bv1 = *(const float4*)&b3[j0 + 4];
        float bj[8] = {bv0.x, bv0.y, bv0.z, bv0.w, bv1.x, bv1.y, bv1.z, bv1.w};
#pragma unroll
        for (int e = 0; e < 4; e++)
#pragma unroll
            for (int jj = 0; jj < 8; jj++) acc[e][jj] = bj[jj];
        for (int c = 0; c < 16; c++) {
            float w[4][8];
#pragma unroll
            for (int rr = 0; rr < 4; rr++) {
                float4 a = *(const float4*)&wS[(c * 4 + rr) * 64 + j0];
                float4 bq = *(const float4*)&wS[(c * 4 + rr) * 64 + j0 + 4];
                w[rr][0] = a.x; w[rr][1] = a.y; w[rr][2] = a.z; w[rr][3] = a.w;
                w[rr][4] = bq.x; w[rr][5] = bq.y; w[rr][6] = bq.z; w[rr][7] = bq.w;
            }
#pragma unroll
            for (int e = 0; e < 4; e++) {
                const float4 xv = *(const float4*)&myA[e * 72 + c * 4];
                const float xs[4] = {xv.x, xv.y, xv.z, xv.w};
#pragma unroll
                for (int rr = 0; rr < 4; rr++)
#pragma unroll
                    for (int jj = 0; jj < 8; jj++)
                        acc[e][jj] = fmaf(xs[rr], w[rr][jj], acc[e][jj]);
            }
        }
#pragma unroll
        for (int e = 0; e < 4; e++) {
            float wvt = wtsQ[ql][e0 + e];
#pragma unroll
            for (int jj = 0; jj < 8; jj++) so[jj] = fmaf(wvt, acc[e][jj], so[jj]);
        }
    }
    __syncthreads();        // all waves done reading W3 region -> reuse as reduction buf
    *(float4*)&wS[wv * 512 + ql * 64 + j0]     = make_float4(so[0], so[1], so[2], so[3]);
    *(float4*)&wS[wv * 512 + ql * 64 + j0 + 4] = make_float4(so[4], so[5], so[6], so[7]);
    __syncthreads();
    for (int t2 = tid; t2 < 512; t2 += 256) {      // FIX: 512 slots, 256 threads
        int q = t2 >> 6, col = t2 & 63;
        float s = wS[q * 64 + col] + wS[512 + q * 64 + col]
                + wS[1024 + q * 64 + col] + wS[1536 + q * 64 + col];
        outb[(long)(qw + q) * 64 + col] = s / wsumS[q];
    }
}

// ---------------------------------------------------------------- transpose (B,R,C) -> (B,C,R)
__global__ void k_transp(const float* __restrict__ src, float* __restrict__ dst, int R, int C) {
    __shared__ float t[32][33];
    int b = blockIdx.z;
    int c0 = blockIdx.x * 32, r0 = blockIdx.y * 32;
    int tx = threadIdx.x, ty0 = threadIdx.y;    // (32,8)
    for (int yy = ty0; yy < 32; yy += 8) {
        int r = r0 + yy, c = c0 + tx;
        if (r < R && c < C) t[yy][tx] = src[((long)b * R + r) * C + c];
    }
    __syncthreads();
    for (int yy = ty0; yy < 32; yy += 8) {
        int c = c0 + yy, r = r0 + tx;
        if (r < R && c < C) dst[((long)b * C + c) * R + r] = t[tx][yy];
    }
}

// ---------------------------------------------------------------- FNO: truncated forward DFT
__global__ void __launch_bounds__(1024) k_f1(const float* __restrict__ x, float* __restrict__ Xh) {
    int blk = blockIdx.x;    // b*64 + ch
    int tid = threadIdx.x;   // 1024
    __shared__ __align__(16) float img[4096];
    __shared__ float Tre[64][12], Tim[64][12];
    __shared__ float cs[64], sn[64];
    if (tid < 64) {
        double a = (2.0 * PI_ / 64.0) * (double)tid;
        cs[tid] = (float)cos(a);
        sn[tid] = (float)sin(a);
    }
    ((float4*)img)[tid] = ((const float4*)(x + (long)blk * 4096))[tid];
    __syncthreads();
    if (tid < 768) {                             // (h, c)
        int h = tid / 12, c = tid - 12 * h;
        float re = 0.f, im = 0.f;
        for (int w = 0; w < 64; w++) {
            float v = img[h * 64 + w];
            int k = (c * w) & 63;
            re = fmaf(v, cs[k], re);
            im = fmaf(-v, sn[k], im);
        }
        Tre[h][c] = re; Tim[h][c] = im;
    }
    __syncthreads();
    if (tid < 288) {                             // (x24, c12)
        int xx = tid / 12, c = tid - 12 * xx;
        int r = (xx < 12) ? xx : (xx + 40);
        float re = 0.f, im = 0.f;
        for (int h = 0; h < 64; h++) {
            int k = (r * h) & 63;
            float cr = cs[k], si = sn[k];
            float a = Tre[h][c], bb = Tim[h][c];
            re += a * cr + bb * si;
            im += bb * cr - a * si;
        }
        Xh[((long)blk * 288 + tid) * 2] = re;
        Xh[((long)blk * 288 + tid) * 2 + 1] = im;
    }
}

// mode-mix: Yhat[b,o,m] = sum_i Wc[i,o,m] * Xhat[b,i,m]
__global__ void __launch_bounds__(256) k_f2(const float* __restrict__ Xh, const float* __restrict__ s1,
                                            const float* __restrict__ s2, float* __restrict__ Yh) {
    int m = blockIdx.x;                  // 0..287
    int xx = m / 12, y = m - 12 * xx;
    const float* W; int xw;
    if (xx < 12) { W = s1; xw = xx; } else { W = s2; xw = xx - 12; }
    __shared__ float xr[128], xi[128];
    __shared__ float pr[256], pi[256];
    int tid = threadIdx.x;               // 256
    if (tid < 128) {
        int bb = tid >> 6, i = tid & 63;
        xr[tid] = Xh[(((long)bb * 64 + i) * 288 + m) * 2];
        xi[tid] = Xh[(((long)bb * 64 + i) * 288 + m) * 2 + 1];
    }
    __syncthreads();
    int half = tid >> 7;
    int t2 = tid & 127;
    int bb = t2 >> 6, o = t2 & 63;
    float re = 0.f, im = 0.f;
    for (int i = half * 32; i < half * 32 + 32; i++) {
        long wb = (long)i * 18432 + (long)o * 288 + xw * 24 + y * 2;
        float wr = W[wb], wi = W[wb + 1];
        float a = xr[bb * 64 + i], cc = xi[bb * 64 + i];
        re += a * wr - cc * wi;
        im += a * wi + cc * wr;
    }
    pr[tid] = re; pi[tid] = im;
    __syncthreads();
    if (tid < 128) {
        float re2 = pr[tid] + pr[tid + 128];
        float im2 = pi[tid] + pi[tid + 128];
        Yh[(((long)bb * 64 + o) * 288 + m) * 2] = re2;
        Yh[(((long)bb * 64 + o) * 288 + m) * 2 + 1] = im2;
    }
}

// inverse DFT + pointwise conv + bias + InstanceNorm + GELU, fused per (b, out-channel)
__global__ void __launch_bounds__(1024) k_f3(const float* __restrict__ Yh, const float* __restrict__ x,
                                             const float* __restrict__ pwW, const float* __restrict__ pwb,
                                             float* __restrict__ xo) {
    int blk = blockIdx.x;
    int b = blk >> 6, o = blk & 63;
    int tid = threadIdx.x;   // 1024; each thread owns 4 consecutive pixels
    __shared__ float yre[288], yim[288];
    __shared__ float Qre[64][12], Qim[64][12];
    __shared__ float cs[64], sn[64];
    __shared__ float red[1024];
    if (tid < 64) {
        double a = (2.0 * PI_ / 64.0) * (double)tid;
        cs[tid] = (float)cos(a);
        sn[tid] = (float)sin(a);
    }
    if (tid < 288) {
        yre[tid] = Yh[((long)blk * 288 + tid) * 2];
        yim[tid] = Yh[((long)blk * 288 + tid) * 2 + 1];
    }
    __syncthreads();
    if (tid < 768) {    // (h, c): complex ifft along rows (1/64 scale)
        int h = tid / 12, c = tid - 12 * h;
        float re = 0.f, im = 0.f;
#pragma unroll
        for (int xx = 0; xx < 24; xx++) {
            int r = (xx < 12) ? xx : (xx + 40);
            int k = (r * h) & 63;
            float wr = cs[k], wi = sn[k];
            float a = yre[xx * 12 + c], bb = yim[xx * 12 + c];
            re += a * wr - bb * wi;
            im += a * wi + bb * wr;
        }
        Qre[h][c] = re * (1.0f / 64.0f);
        Qim[h][c] = im * (1.0f / 64.0f);
    }
    __syncthreads();
    float bias = pwb[o];
    int h = tid >> 4;
    int w0 = (tid & 15) * 4;
    float sp0, sp1, sp2, sp3;
    {
        float base = Qre[h][0];
        sp0 = sp1 = sp2 = sp3 = base;
#pragma unroll
        for (int c = 1; c < 12; c++) {
            float qr = Qre[h][c], qi = Qim[h][c];
            int k0 = (c * w0) & 63, k1 = (c * (w0 + 1)) & 63;
            int k2 = (c * (w0 + 2)) & 63, k3 = (c * (w0 + 3)) & 63;
            sp0 += 2.0f * (qr * cs[k0] - qi * sn[k0]);
            sp1 += 2.0f * (qr * cs[k1] - qi * sn[k1]);
            sp2 += 2.0f * (qr * cs[k2] - qi * sn[k2]);
            sp3 += 2.0f * (qr * cs[k3] - qi * sn[k3]);
        }
    }
    float a0 = sp0 * (1.0f / 64.0f) + bias;
    float a1 = sp1 * (1.0f / 64.0f) + bias;
    float a2 = sp2 * (1.0f / 64.0f) + bias;
    float a3 = sp3 * (1.0f / 64.0f) + bias;
    const float* xb = x + ((long)b * 64) * 4096 + tid * 4;
    for (int i = 0; i < 64; i++) {
        float wv = pwW[o * 64 + i];
        const float4 xv = *(const float4*)(xb + (long)i * 4096);
        a0 = fmaf(xv.x, wv, a0);
        a1 = fmaf(xv.y, wv, a1);
        a2 = fmaf(xv.z, wv, a2);
        a3 = fmaf(xv.w, wv, a3);
    }
    red[tid] = a0 + a1 + a2 + a3;
    __syncthreads();
    for (int d = 512; d > 0; d >>= 1) { if (tid < d) red[tid] += red[tid + d]; __syncthreads(); }
    float mu = red[0] * (1.0f / 4096.0f);
    __syncthreads();
    float d0 = a0 - mu, d1 = a1 - mu, d2 = a2 - mu, d3 = a3 - mu;
    red[tid] = d0 * d0 + d1 * d1 + d2 * d2 + d3 * d3;
    __syncthreads();
    for (int d = 512; d > 0; d >>= 1) { if (tid < d) red[tid] += red[tid + d]; __syncthreads(); }
    float var = red[0] * (1.0f / 4096.0f);
    float inv = 1.0f / sqrtf(var + 1e-5f);
    float4 ov = make_float4(gelu_f(d0 * inv), gelu_f(d1 * inv), gelu_f(d2 * inv), gelu_f(d3 * inv));
    *(float4*)&xo[(long)blk * 4096 + tid * 4] = ov;
}

// ---------------------------------------------------------------- projection MLP (64 -> 64 -> 3)
__global__ void __launch_bounds__(256) k_proj(
    const float* __restrict__ y, const float* __restrict__ W1, const float* __restrict__ b1,
    const float* __restrict__ W2, const float* __restrict__ b2, float* __restrict__ out) {
    __shared__ __align__(16) float yr[4][64];
    __shared__ float h[4][64];
    int ql = threadIdx.x >> 6, j = threadIdx.x & 63;
    long node = (long)blockIdx.x * 4 + ql;
    yr[ql][j] = y[node * 64 + j];
    __syncthreads();
    float a = b1[j];
    for (int k = 0; k < 64; k += 4) {
        float w0 = W1[(k + 0) * 64 + j], w1 = W1[(k + 1) * 64 + j];
        float w2 = W1[(k + 2) * 64 + j], w3 = W1[(k + 3) * 64 + j];
        const float4 hv = *(const float4*)&yr[ql][k];
        a = fmaf(hv.x, w0, fmaf(hv.y, w1, fmaf(hv.z, w2, fmaf(hv.w, w3, a))));
    }
    h[ql][j] = gelu_f(a);
    __syncthreads();
    if (j < 3) {
        float a2 = b2[j];
        for (int k = 0; k < 64; k++) a2 = fmaf(h[ql][k], W2[k * 3 + j], a2);
        out[node * 3 + j] = a2;
    }
}

// ---------------------------------------------------------------- launch
extern "C" void kernel_launch(void* const* d_in, const int* in_sizes, int n_in,
                              void* d_out, int out_size, void* d_ws, size_t ws_size,
                              hipStream_t stream) {
    (void)in_sizes; (void)n_in; (void)out_size; (void)ws_size;
    const float* coords   = (const float*)d_in[0];
    const float* features = (const float*)d_in[1];
    const float* lift_W1 = (const float*)d_in[2];
    const float* lift_b1 = (const float*)d_in[3];
    const float* lift_W2 = (const float*)d_in[4];
    const float* lift_b2 = (const float*)d_in[5];
    const float* gin_W1 = (const float*)d_in[6];
    const float* gin_b1 = (const float*)d_in[7];
    const float* gin_W2 = (const float*)d_in[8];
    const float* gin_b2 = (const float*)d_in[9];
    const float* gin_W3 = (const float*)d_in[10];
    const float* gin_b3 = (const float*)d_in[11];
    const float* spec1 = (const float*)d_in[12];
    const float* spec2 = (const float*)d_in[13];
    const float* pw_W  = (const float*)d_in[14];
    const float* pw_b  = (const float*)d_in[15];
    const float* gout_W1 = (const float*)d_in[16];
    const float* gout_b1 = (const float*)d_in[17];
    const float* gout_W2 = (const float*)d_in[18];
    const float* gout_b2 = (const float*)d_in[19];
    const float* gout_W3 = (const float*)d_in[20];
    const float* gout_b3 = (const float*)d_in[21];
    const float* proj_W1 = (const float*)d_in[22];
    const float* proj_b1 = (const float*)d_in[23];
    const float* proj_W2 = (const float*)d_in[24];
    const float* proj_b2 = (const float*)d_in[25];

    char* ws = (char*)d_ws;
    size_t off = 0;
    auto alloc = [&](size_t bytes) -> char* {
        char* p = ws + off;
        off = (off + bytes + 255) & ~(size_t)255;
        return p;
    };
    float4* grid_pack = (float4*)alloc((size_t)NG * 16);
    float*  feat      = (float*)alloc((size_t)B_ * N_ * 64 * 4);
    int*    bin_cnt   = (int*)alloc((size_t)B_ * 4096 * 4);
    int*    bin_fill  = (int*)alloc((size_t)B_ * 4096 * 4);
    int*    bin_off   = (int*)alloc((size_t)B_ * 4097 * 4);
    float4* srt       = (float4*)alloc((size_t)B_ * N_ * 16);
    int*    idx_in    = (int*)alloc((size_t)B_ * NG * 16 * 4);
    float*  dist_in   = (float*)alloc((size_t)B_ * NG * 16 * 4);
    float*  lastd_in  = (float*)alloc((size_t)B_ * NG * 4);
    float*  sig_in    = (float*)alloc(256);
    float*  wtsb_in   = (float*)alloc((size_t)B_ * NG * 16 * 4);
    float*  wsum_in   = (float*)alloc((size_t)B_ * NG * 4);
    float*  gout_buf  = (float*)alloc((size_t)B_ * NG * 64 * 4);
    float*  xb0       = (float*)alloc((size_t)B_ * 64 * NG * 4);
    float*  xb1       = (float*)alloc((size_t)B_ * 64 * NG * 4);
    float*  Xh        = (float*)alloc((size_t)B_ * 64 * 288 * 2 * 4);
    float*  Yh        = (float*)alloc((size_t)B_ * 64 * 288 * 2 * 4);
    float*  g2        = (float*)alloc((size_t)B_ * NG * 64 * 4);
    int*    idx_out   = (int*)alloc((size_t)B_ * N_ * 16 * 4);
    float*  dist_out  = (float*)alloc((size_t)B_ * N_ * 16 * 4);
    float*  lastd_out = (float*)alloc((size_t)B_ * N_ * 4);
    float*  sig_out   = (float*)alloc(256);
    float*  wtsb_out  = (float*)alloc((size_t)B_ * N_ * 16 * 4);
    float*  wsum_out  = (float*)alloc((size_t)B_ * N_ * 4);
    float*  ybuf      = (float*)alloc((size_t)B_ * N_ * 64 * 4);

    hipMemsetAsync(bin_cnt, 0, (size_t)B_ * 4096 * 4, stream);
    hipMemsetAsync(bin_fill, 0, (size_t)B_ * 4096 * 4, stream);

    k_gridgen<<<NG / 256, 256, 0, stream>>>(grid_pack);
    k_lift<<<(B_ * N_) / 4, 256, 0, stream>>>(features, lift_W1, lift_b1, lift_W2, lift_b2, feat);
    k_bincount<<<(B_ * N_) / 256, 256, 0, stream>>>((const float2*)coords, bin_cnt);
    k_binscan<<<B_, 1024, 0, stream>>>(bin_cnt, bin_off);
    k_binscatter<<<(B_ * N_) / 256, 256, 0, stream>>>((const float2*)coords, bin_off, bin_fill, srt);
    k_knn_in<<<(B_ * NG * 64) / 256, 256, 0, stream>>>(grid_pack, srt, bin_off, idx_in, dist_in, lastd_in);
    k_median_bis<<<1, 1024, 0, stream>>>(lastd_in, B_ * NG, sig_in);
    k_wts<<<(B_ * NG) / 256, 256, 0, stream>>>(dist_in, sig_in, wtsb_in, wsum_in, B_ * NG);
    k_edge<0><<<(B_ * NG) / 8, 256, 0, stream>>>(idx_in, dist_in, wtsb_in, wsum_in,
        (const float2*)coords, grid_pack, feat,
        gin_W1, gin_b1, gin_W2, gin_b2, gin_W3, gin_b3, gout_buf, NG, N_);
    {
        dim3 g(64 / 32, NG / 32, B_); dim3 t(32, 8);
        k_transp<<<g, t, 0, stream>>>(gout_buf, xb0, NG, 64);
    }
    float* xc = xb0; float* xn = xb1;
    for (int d = 0; d < 3; d++) {
        k_f1<<<B_ * 64, 1024, 0, stream>>>(xc, Xh);
        k_f2<<<288, 256, 0, stream>>>(Xh, spec1 + (size_t)d * 1179648, spec2 + (size_t)d * 1179648, Yh);
        k_f3<<<B_ * 64, 1024, 0, stream>>>(Yh, xc, pw_W + (size_t)d * 4096, pw_b + (size_t)d * 64, xn);
        float* tmp = xc; xc = xn; xn = tmp;
    }
    {
        dim3 g(NG / 32, 64 / 32, B_); dim3 t(32, 8);
        k_transp<<<g, t, 0, stream>>>(xc, g2, 64, NG);
    }
    k_knn_out<<<(B_ * N_ * 64) / 256, 256, 0, stream>>>((const float2*)coords, grid_pack, idx_out, dist_out, lastd_out);
    k_median_bis<<<1, 1024, 0, stream>>>(lastd_out, B_ * N_, sig_out);
    k_wts<<<(B_ * N_) / 256, 256, 0, stream>>>(dist_out, sig_out, wtsb_out, wsum_out, B_ * N_);
    k_edge<1><<<(B_ * N_) / 8, 256, 0, stream>>>(idx_out, dist_out, wtsb_out, wsum_out,
        (const float2*)coords, grid_pack, g2,
        gout_W1, gout_b1, gout_W2, gout_b2, gout_W3, gout_b3, ybuf, N_, NG);
    k_proj<<<(B_ * N_) / 4, 256, 0, stream>>>(ybuf, proj_W1, proj_b1, proj_W2, proj_b2, (float*)d_out);
}

// Round 7
// 605.010 us; speedup vs baseline: 1.5844x; 1.0225x over previous
//
#include <hip/hip_runtime.h>
#include <math.h>

#define B_ 2
#define N_ 8192          // points per batch
#define G_ 64
#define NG 4096          // G*G latent grid points
#define WID_ 64
#define K_ 16
#define CIN_ 6
#define COUT_ 3
#define PI_ 3.14159265358979323846

typedef unsigned long long u64k;

// ---------------------------------------------------------------- helpers
__device__ __forceinline__ float gelu_f(float x) {
    return 0.5f * x * (1.0f + erff(x * 0.70710678118654752440f));
}
__device__ __forceinline__ int cellof(float v) {
    int c = (int)floorf((v + 1.0f) * 32.0f);
    return min(63, max(0, c));
}
__device__ __forceinline__ u64k umin64(u64k a, u64k b) { return a < b ? a : b; }
__device__ __forceinline__ u64k umax64(u64k a, u64k b) { return a < b ? b : a; }
__device__ __forceinline__ u64k shflxor64(u64k v, int m) {
    return (u64k)__shfl_xor((long long)v, m, 64);
}
__device__ __forceinline__ void bsort64(u64k& key, int lane) {
#pragma unroll
    for (int sz = 2; sz <= 64; sz <<= 1) {
#pragma unroll
        for (int j = sz >> 1; j >= 1; j >>= 1) {
            u64k o = shflxor64(key, j);
            bool keep_min = ((lane & j) == 0) == ((lane & sz) == 0);
            key = keep_min ? umin64(key, o) : umax64(key, o);
        }
    }
}
__device__ __forceinline__ void bmerge_into(u64k& R, u64k key, int lane) {
    u64k o = shflxor64(key, 63);
    u64k L = umin64(R, o);
#pragma unroll
    for (int j = 32; j >= 1; j >>= 1) {
        u64k t = shflxor64(L, j);
        L = ((lane & j) == 0) ? umin64(L, t) : umax64(L, t);
    }
    R = L;
}

// ---------------------------------------------------------------- grid gen
__global__ void k_gridgen(float4* gp) {
    int p = blockIdx.x * blockDim.x + threadIdx.x;
    if (p >= NG) return;
    int i = p >> 6, j = p & 63;
    double st = 2.0 / 63.0;
    float gx = (i == 63) ? 1.0f : (float)(-1.0 + st * (double)i);
    float gy = (j == 63) ? 1.0f : (float)(-1.0 + st * (double)j);
    float s2 = __fadd_rn(__fmul_rn(gx, gx), __fmul_rn(gy, gy));
    gp[p] = make_float4(gx, gy, s2, 0.f);
}

// ---------------------------------------------------------------- lift MLP
__global__ void __launch_bounds__(256) k_lift(
    const float* __restrict__ fin, const float* __restrict__ W1,
    const float* __restrict__ b1, const float* __restrict__ W2,
    const float* __restrict__ b2, float* __restrict__ fout) {
    __shared__ float xr[4][8];
    __shared__ __align__(16) float h[4][64];
    int ql = threadIdx.x >> 6, j = threadIdx.x & 63;
    int node = blockIdx.x * 4 + ql;
    if (j < CIN_) xr[ql][j] = fin[node * CIN_ + j];
    __syncthreads();
    float a = b1[j];
#pragma unroll
    for (int i = 0; i < CIN_; i++) a = fmaf(xr[ql][i], W1[i * 64 + j], a);
    h[ql][j] = gelu_f(a);
    __syncthreads();
    float a2 = b2[j];
    for (int k = 0; k < 64; k += 4) {
        float w0 = W2[(k + 0) * 64 + j], w1 = W2[(k + 1) * 64 + j];
        float w2 = W2[(k + 2) * 64 + j], w3 = W2[(k + 3) * 64 + j];
        const float4 hv = *(const float4*)&h[ql][k];
        a2 = fmaf(hv.x, w0, fmaf(hv.y, w1, fmaf(hv.z, w2, fmaf(hv.w, w3, a2))));
    }
    fout[node * 64 + j] = a2;
}

// ---------------------------------------------------------------- binning
__global__ void k_bincount(const float2* __restrict__ coords, int* __restrict__ cnt) {
    int t = blockIdx.x * blockDim.x + threadIdx.x;
    if (t >= B_ * N_) return;
    float2 c = coords[t];
    int b = t >> 13;
    int cell = cellof(c.x) * 64 + cellof(c.y);
    atomicAdd(&cnt[b * 4096 + cell], 1);
}
__global__ void k_binscan(const int* __restrict__ cnt, int* __restrict__ offs) {
    int b = blockIdx.x, t = threadIdx.x;    // 1024 threads
    __shared__ int s[1024];
    int4 v = ((const int4*)(cnt + b * 4096))[t];
    int sum = v.x + v.y + v.z + v.w;
    s[t] = sum;
    __syncthreads();
    for (int d = 1; d < 1024; d <<= 1) {
        int x = (t >= d) ? s[t - d] : 0;
        __syncthreads();
        s[t] += x;
        __syncthreads();
    }
    int incl = s[t], excl = incl - sum;
    int* ob = offs + b * 4097;
    ob[4 * t] = excl; ob[4 * t + 1] = excl + v.x;
    ob[4 * t + 2] = excl + v.x + v.y; ob[4 * t + 3] = excl + v.x + v.y + v.z;
    if (t == 1023) ob[4096] = incl;
}
__global__ void k_binscatter(const float2* __restrict__ coords, const int* __restrict__ offs,
                             int* __restrict__ fill, float4* __restrict__ srt) {
    int t = blockIdx.x * blockDim.x + threadIdx.x;
    if (t >= B_ * N_) return;
    float2 c = coords[t];
    int b = t >> 13, n = t & 8191;
    int cell = cellof(c.x) * 64 + cellof(c.y);
    int pos = offs[b * 4097 + cell] + atomicAdd(&fill[b * 4096 + cell], 1);
    float s2 = __fadd_rn(__fmul_rn(c.x, c.x), __fmul_rn(c.y, c.y));
    srt[b * N_ + pos] = make_float4(c.x, c.y, s2, __int_as_float(n));
}

// ---------------------------------------------------------------- kNN grid->points: one wave per query
__global__ void __launch_bounds__(256) k_knn_in(
    const float4* __restrict__ gp, const float4* __restrict__ srt,
    const int* __restrict__ offs, int* __restrict__ oidx,
    float* __restrict__ odist, float* __restrict__ lastd) {
    int lane = threadIdx.x & 63;
    int w = (blockIdx.x * blockDim.x + threadIdx.x) >> 6;
    int b = w >> 12, p = w & 4095;
    float4 q = gp[p];
    float qx = q.x, qy = q.y, q2 = q.z;
    int cqx = cellof(qx), cqy = cellof(qy);
    const float4* S = srt + b * N_;
    const int* OF = offs + b * 4097;

    u64k R = ~0ull;
    u64k pend = ~0ull;
    int fill = 0;

    auto flush = [&]() {
        bsort64(pend, lane);
        bmerge_into(R, pend, lane);
        pend = ~0ull;
        fill = 0;
    };
    auto feed = [&](int s0, int s1) {
        int cnt = s1 - s0;
        while (cnt > 0) {
            int take = min(cnt, 64 - fill);
            int t = lane - fill;
            if (t >= 0 && t < take) {
                float4 sp = S[s0 + t];
                float dot = __fadd_rn(__fmul_rn(qx, sp.x), __fmul_rn(qy, sp.y));
                float d2 = __fsub_rn(__fadd_rn(q2, sp.z), 2.0f * dot);
                d2 = fmaxf(d2, 0.0f);
                pend = ((u64k)__float_as_uint(d2) << 32) | (unsigned)__float_as_int(sp.w);
            }
            fill += take; s0 += take; cnt -= take;
            if (fill == 64) flush();
        }
    };

    {
        int xa = max(cqx - 2, 0), xb = min(cqx + 2, 63);
        int ya = max(cqy - 2, 0), yb = min(cqy + 2, 63);
        for (int cx = xa; cx <= xb; cx++) feed(OF[cx * 64 + ya], OF[cx * 64 + yb + 1]);
    }
    int r = 2;
    while (true) {
        if (fill) flush();
        u64k T = (u64k)__shfl((long long)R, 15, 64);
        float d16 = __uint_as_float((unsigned)(T >> 32));
        float bm = (float)r * 0.03125f;
        if (d16 < bm * bm - 1e-5f) break;
        if (cqx - r <= 0 && cqx + r >= 63 && cqy - r <= 0 && cqy + r >= 63) break;
        r++;
        int ya = max(cqy - r, 0), yb = min(cqy + r, 63);
        if (cqx - r >= 0)  { int c0 = (cqx - r) * 64; feed(OF[c0 + ya], OF[c0 + yb + 1]); }
        if (cqx + r <= 63) { int c0 = (cqx + r) * 64; feed(OF[c0 + ya], OF[c0 + yb + 1]); }
        int xa2 = max(cqx - r + 1, 0), xb2 = min(cqx + r - 1, 63);
        for (int cx = xa2; cx <= xb2; cx++) {
            if (cqy - r >= 0)  { int cc = cx * 64 + cqy - r; feed(OF[cc], OF[cc + 1]); }
            if (cqy + r <= 63) { int cc = cx * 64 + cqy + r; feed(OF[cc], OF[cc + 1]); }
        }
    }
    if (lane < 16) {
        float d2 = __uint_as_float((unsigned)(R >> 32));
        float d = sqrtf(d2);
        oidx[w * 16 + lane] = (int)(unsigned)(R & 0xffffffffu);
        odist[w * 16 + lane] = d;
        if (lane == 15) lastd[w] = d;
    }
}

// ---------------------------------------------------------------- kNN points->grid: one wave per query
__global__ void __launch_bounds__(256) k_knn_out(
    const float2* __restrict__ coords, const float4* __restrict__ gp,
    int* __restrict__ oidx, float* __restrict__ odist, float* __restrict__ lastd) {
    int lane = threadIdx.x & 63;
    int w = (blockIdx.x * blockDim.x + threadIdx.x) >> 6;
    float2 c = coords[w];
    float qx = c.x, qy = c.y;
    float q2 = __fadd_rn(__fmul_rn(qx, qx), __fmul_rn(qy, qy));
    int i0 = (int)floorf((qx + 1.0f) * 31.5f);
    int j0 = (int)floorf((qy + 1.0f) * 31.5f);
    int li = min(max(i0 - 3, 0), 56);
    int lj = min(max(j0 - 3, 0), 56);
    int p = (li + (lane >> 3)) * 64 + (lj + (lane & 7));
    float4 sp = gp[p];
    float dot = __fadd_rn(__fmul_rn(qx, sp.x), __fmul_rn(qy, sp.y));
    float d2 = fmaxf(__fsub_rn(__fadd_rn(q2, sp.z), 2.0f * dot), 0.0f);
    u64k key = ((u64k)__float_as_uint(d2) << 32) | (unsigned)p;
    bsort64(key, lane);
    if (lane < 16) {
        float dd = sqrtf(__uint_as_float((unsigned)(key >> 32)));
        oidx[w * 16 + lane] = (int)(unsigned)(key & 0xffffffffu);
        odist[w * 16 + lane] = dd;
        if (lane == 15) lastd[w] = dd;
    }
}

// ---------------------------------------------------------------- exact lower-median via 32-step bisection (v2)
// 1 barrier per bit (double-buffered wave counts), no serial section.
__global__ void __launch_bounds__(1024) k_median_bis(
    const float* __restrict__ vals, int n, float* __restrict__ sig) {
    __shared__ int wred[2][16];
    int tid = threadIdx.x;
    int lane = tid & 63, wv = tid >> 6;
    int cnt_per = n >> 10;           // 8 or 16
    unsigned v[16];
    for (int i = 0; i < cnt_per; i++) v[i] = __float_as_uint(vals[tid + (i << 10)]);
    int r = (n - 1) >> 1;
    unsigned prefix = 0;
    for (int bit = 31; bit >= 0; bit--) {
        unsigned cand = prefix | (1u << bit);
        int c = 0;
        for (int i = 0; i < cnt_per; i++) c += (v[i] < cand) ? 1 : 0;
        for (int o = 32; o >= 1; o >>= 1) c += __shfl_down(c, o, 64);
        int buf = bit & 1;
        if (lane == 0) wred[buf][wv] = c;
        __syncthreads();
        int tot = 0;
#pragma unroll
        for (int k = 0; k < 16; k++) tot += wred[buf][k];
        prefix = (tot <= r) ? cand : prefix;
    }
    if (tid == 0) *sig = fmaxf(__uint_as_float(prefix), 1e-6f);
}

// ---------------------------------------------------------------- precompute weights + clamped sum per query
__global__ void __launch_bounds__(256) k_wts(
    const float* __restrict__ distb, const float* __restrict__ sigp,
    float* __restrict__ wtsb, float* __restrict__ wsum, int tot) {
    int t = blockIdx.x * blockDim.x + threadIdx.x;
    if (t >= tot) return;
    float sig = *sigp;
    float s = 0.f;
#pragma unroll
    for (int e = 0; e < 16; e++) {
        float w = expf(-distb[t * 16 + e] / sig);
        wtsb[t * 16 + e] = w;
        s += w;
    }
    wsum[t] = fmaxf(s, 1e-6f);
}

// ---------------------------------------------------------------- edge MLP + weighted aggregation (v4)
// One block (4 waves) per 8 queries; wave wv owns edge slice wv*4..+3
// end-to-end (staging + 3 layers) -> NO mid-kernel barriers. Weights come
// from GLOBAL (L1-resident, vmem pipe); only x fragments go through LDS
// (4 ds_read_b128 per c-iter vs 256 VALU cycles -> VALU-bound).
// eA reused as the cross-wave reduction buffer after the single barrier.
// LDS ~38 KB -> 4 blocks/CU (16 waves, 4/SIMD).
template <int MODE>
__global__ void __launch_bounds__(256, 4) k_edge(
    const int* __restrict__ idxb, const float* __restrict__ distb,
    const float* __restrict__ wtsb, const float* __restrict__ wsump,
    const float2* __restrict__ coords, const float4* __restrict__ gp,
    const float* __restrict__ feats,
    const float* __restrict__ W1, const float* __restrict__ b1,
    const float* __restrict__ W2, const float* __restrict__ b2,
    const float* __restrict__ W3, const float* __restrict__ b3,
    float* __restrict__ outb, int Nq, int srcRows) {
    __shared__ __align__(16) float eA[8 * 1156];   // 8 q x (16 e x 72) + pad; reused as 4x8x64 reduction
    __shared__ float wtsQ[8][16];
    __shared__ int   nidxQ[8][16];
    __shared__ float wsumS[8];
    const int tid = threadIdx.x;
    const int wv = tid >> 6, lane = tid & 63;
    const int ql = lane >> 3, jg = lane & 7, j0 = jg * 8;
    const int e0 = wv * 4;                 // this wave's edge slice
    const int qw = blockIdx.x * 8;

    // ---- wave-local metadata + geometry (32 (q,e) pairs per wave)
    if (lane < 32) {
        int q = lane >> 2, e = e0 + (lane & 3);
        int gq = qw + q;
        int b = gq / Nq, p = gq - b * Nq;
        int si = idxb[gq * 16 + e];
        float d = distb[gq * 16 + e];
        nidxQ[q][e] = si;
        wtsQ[q][e] = wtsb[gq * 16 + e];
        float qx, qy, sx, sy;
        if (MODE == 0) {
            float4 g = gp[p]; qx = g.x; qy = g.y;
            float2 cc = coords[(long)b * srcRows + si]; sx = cc.x; sy = cc.y;
        } else {
            float2 cc = coords[(long)b * Nq + p]; qx = cc.x; qy = cc.y;
            float4 g = gp[si]; sx = g.x; sy = g.y;
        }
        float* row = &eA[q * 1156 + e * 72];
        row[0] = qx; row[1] = qy; row[2] = sx; row[3] = sy;
        row[4] = qx - sx; row[5] = qy - sy; row[6] = d; row[7] = 0.f;
    }
    if (wv == 0 && lane < 8) wsumS[lane] = wsump[qw + lane];
    // ---- wave-local feats gather: 32 rows x 16 float4 = 512 slots
    for (int it = 0; it < 8; it++) {
        int slot = it * 64 + lane;
        int rowi = slot >> 4, f4 = slot & 15;
        int q = rowi >> 2, e = e0 + (rowi & 3);
        int gq = qw + q;
        int b = gq / Nq;
        int si = nidxQ[q][e];
        const float4 v = *(const float4*)&feats[((long)b * srcRows + si) * 64 + f4 * 4];
        *(float4*)&eA[q * 1156 + e * 72 + 8 + f4 * 4] = v;
    }
    // (no barrier: each wave only touches its own edge slice until the reduction)

    const float* myA = &eA[ql * 1156 + e0 * 72];
    float acc[4][8];
    // ---------- layer 1: x[0..71] (x[7]==0; W1 rows skip slot 7)
    {
        float4 bv0 = *(const float4*)&b1[j0], bv1 = *(const float4*)&b1[j0 + 4];
        float bj[8] = {bv0.x, bv0.y, bv0.z, bv0.w, bv1.x, bv1.y, bv1.z, bv1.w};
#pragma unroll
        for (int e = 0; e < 4; e++)
#pragma unroll
            for (int jj = 0; jj < 8; jj++) acc[e][jj] = bj[jj];
        for (int c = 0; c < 18; c++) {
            float w[4][8];
#pragma unroll
            for (int rr = 0; rr < 4; rr++) {
                int t = c * 4 + rr;
                int wrow = t - (t > 6);
                float4 a = *(const float4*)&W1[wrow * 64 + j0];
                float4 bq = *(const float4*)&W1[wrow * 64 + j0 + 4];
                if (t == 7) { a = make_float4(0.f, 0.f, 0.f, 0.f); bq = a; }
                w[rr][0] = a.x; w[rr][1] = a.y; w[rr][2] = a.z; w[rr][3] = a.w;
                w[rr][4] = bq.x; w[rr][5] = bq.y; w[rr][6] = bq.z; w[rr][7] = bq.w;
            }
#pragma unroll
            for (int e = 0; e < 4; e++) {
                const float4 xv = *(const float4*)&myA[e * 72 + c * 4];
                const float xs[4] = {xv.x, xv.y, xv.z, xv.w};
#pragma unroll
                for (int rr = 0; rr < 4; rr++)
#pragma unroll
                    for (int jj = 0; jj < 8; jj++)
                        acc[e][jj] = fmaf(xs[rr], w[rr][jj], acc[e][jj]);
            }
        }
    }
#pragma unroll
    for (int e = 0; e < 4; e++) {
        float4 h0 = make_float4(gelu_f(acc[e][0]), gelu_f(acc[e][1]),
                                gelu_f(acc[e][2]), gelu_f(acc[e][3]));
        float4 h1 = make_float4(gelu_f(acc[e][4]), gelu_f(acc[e][5]),
                                gelu_f(acc[e][6]), gelu_f(acc[e][7]));
        *(float4*)&eA[ql * 1156 + (e0 + e) * 72 + j0] = h0;
        *(float4*)&eA[ql * 1156 + (e0 + e) * 72 + j0 + 4] = h1;
    }
    // ---------- layer 2: x[0..63]
    {
        float4 bv0 = *(const float4*)&b2[j0], bv1 = *(const float4*)&b2[j0 + 4];
        float bj[8] = {bv0.x, bv0.y, bv0.z, bv0.w, bv1.x, bv1.y, bv1.z, bv1.w};
#pragma unroll
        for (int e = 0; e < 4; e++)
#pragma unroll
            for (int jj = 0; jj < 8; jj++) acc[e][jj] = bj[jj];
        for (int c = 0; c < 16; c++) {
            float w[4][8];
#pragma unroll
            for (int rr = 0; rr < 4; rr++) {
                float4 a = *(const float4*)&W2[(c * 4 + rr) * 64 + j0];
                float4 bq = *(const float4*)&W2[(c * 4 + rr) * 64 + j0 + 4];
                w[rr][0] = a.x; w[rr][1] = a.y; w[rr][2] = a.z; w[rr][3] = a.w;
                w[rr][4] = bq.x; w[rr][5] = bq.y; w[rr][6] = bq.z; w[rr][7] = bq.w;
            }
#pragma unroll
            for (int e = 0; e < 4; e++) {
                const float4 xv = *(const float4*)&myA[e * 72 + c * 4];
                const float xs[4] = {xv.x, xv.y, xv.z, xv.w};
#pragma unroll
                for (int rr = 0; rr < 4; rr++)
#pragma unroll
                    for (int jj = 0; jj < 8; jj++)
                        acc[e][jj] = fmaf(xs[rr], w[rr][jj], acc[e][jj]);
            }
        }
    }
#pragma unroll
    for (int e = 0; e < 4; e++) {
        float4 h0 = make_float4(gelu_f(acc[e][0]), gelu_f(acc[e][1]),
                                gelu_f(acc[e][2]), gelu_f(acc[e][3]));
        float4 h1 = make_float4(gelu_f(acc[e][4]), gelu_f(acc[e][5]),
                                gelu_f(acc[e][6]), gelu_f(acc[e][7]));
        *(float4*)&eA[ql * 1156 + (e0 + e) * 72 + j0] = h0;
        *(float4*)&eA[ql * 1156 + (e0 + e) * 72 + j0 + 4] = h1;
    }
    // ---------- layer 3: x[0..63], no activation; weighted partial sum
    float so[8];
#pragma unroll
    for (int jj = 0; jj < 8; jj++) so[jj] = 0.f;
    {
        float4 bv0 = *(const float4*)&b3[j0], bv1 = *(const float4*)&b3[j0 + 4];
        float bj[8] = {bv0.x, bv0.y, bv0.z, bv0.w, bv1.x, bv1.y, bv1.z, bv1.w};
#pragma unroll
        for (int e = 0; e < 4; e++)
#pragma unroll
            for (int jj = 0; jj < 8; jj++) acc[e][jj] = bj[jj];
        for (int c = 0; c < 16; c++) {
            float w[4][8];
#pragma unroll
            for (int rr = 0; rr < 4; rr++) {
                float4 a = *(const float4*)&W3[(c * 4 + rr) * 64 + j0];
                float4 bq = *(const float4*)&W3[(c * 4 + rr) * 64 + j0 + 4];
                w[rr][0] = a.x; w[rr][1] = a.y; w[rr][2] = a.z; w[rr][3] = a.w;
                w[rr][4] = bq.x; w[rr][5] = bq.y; w[rr][6] = bq.z; w[rr][7] = bq.w;
            }
#pragma unroll
            for (int e = 0; e < 4; e++) {
                const float4 xv = *(const float4*)&myA[e * 72 + c * 4];
                const float xs[4] = {xv.x, xv.y, xv.z, xv.w};
#pragma unroll
                for (int rr = 0; rr < 4; rr++)
#pragma unroll
                    for (int jj = 0; jj < 8; jj++)
                        acc[e][jj] = fmaf(xs[rr], w[rr][jj], acc[e][jj]);
            }
        }
#pragma unroll
        for (int e = 0; e < 4; e++) {
            float wvt = wtsQ[ql][e0 + e];
#pragma unroll
            for (int jj = 0; jj < 8; jj++) so[jj] = fmaf(wvt, acc[e][jj], so[jj]);
        }
    }
    __syncthreads();        // all waves done with eA -> reuse as reduction buffer
    *(float4*)&eA[wv * 512 + ql * 64 + j0]     = make_float4(so[0], so[1], so[2], so[3]);
    *(float4*)&eA[wv * 512 + ql * 64 + j0 + 4] = make_float4(so[4], so[5], so[6], so[7]);
    __syncthreads();
    for (int t2 = tid; t2 < 512; t2 += 256) {
        int q = t2 >> 6, col = t2 & 63;
        float s = eA[q * 64 + col] + eA[512 + q * 64 + col]
                + eA[1024 + q * 64 + col] + eA[1536 + q * 64 + col];
        outb[(long)(qw + q) * 64 + col] = s / wsumS[q];
    }
}

// ---------------------------------------------------------------- transpose (B,R,C) -> (B,C,R)
__global__ void k_transp(const float* __restrict__ src, float* __restrict__ dst, int R, int C) {
    __shared__ float t[32][33];
    int b = blockIdx.z;
    int c0 = blockIdx.x * 32, r0 = blockIdx.y * 32;
    int tx = threadIdx.x, ty0 = threadIdx.y;    // (32,8)
    for (int yy = ty0; yy < 32; yy += 8) {
        int r = r0 + yy, c = c0 + tx;
        if (r < R && c < C) t[yy][tx] = src[((long)b * R + r) * C + c];
    }
    __syncthreads();
    for (int yy = ty0; yy < 32; yy += 8) {
        int c = c0 + yy, r = r0 + tx;
        if (r < R && c < C) dst[((long)b * C + c) * R + r] = t[tx][yy];
    }
}

// ---------------------------------------------------------------- FNO: truncated forward DFT
__global__ void __launch_bounds__(1024) k_f1(const float* __restrict__ x, float* __restrict__ Xh) {
    int blk = blockIdx.x;    // b*64 + ch
    int tid = threadIdx.x;   // 1024
    __shared__ __align__(16) float img[4096];
    __shared__ float Tre[64][12], Tim[64][12];
    __shared__ float cs[64], sn[64];
    if (tid < 64) {
        double a = (2.0 * PI_ / 64.0) * (double)tid;
        cs[tid] = (float)cos(a);
        sn[tid] = (float)sin(a);
    }
    ((float4*)img)[tid] = ((const float4*)(x + (long)blk * 4096))[tid];
    __syncthreads();
    if (tid < 768) {                             // (h, c)
        int h = tid / 12, c = tid - 12 * h;
        float re = 0.f, im = 0.f;
        for (int w = 0; w < 64; w++) {
            float v = img[h * 64 + w];
            int k = (c * w) & 63;
            re = fmaf(v, cs[k], re);
            im = fmaf(-v, sn[k], im);
        }
        Tre[h][c] = re; Tim[h][c] = im;
    }
    __syncthreads();
    if (tid < 288) {                             // (x24, c12)
        int xx = tid / 12, c = tid - 12 * xx;
        int r = (xx < 12) ? xx : (xx + 40);
        float re = 0.f, im = 0.f;
        for (int h = 0; h < 64; h++) {
            int k = (r * h) & 63;
            float cr = cs[k], si = sn[k];
            float a = Tre[h][c], bb = Tim[h][c];
            re += a * cr + bb * si;
            im += bb * cr - a * si;
        }
        Xh[((long)blk * 288 + tid) * 2] = re;
        Xh[((long)blk * 288 + tid) * 2 + 1] = im;
    }
}

// mode-mix: Yhat[b,o,m] = sum_i Wc[i,o,m] * Xhat[b,i,m]
__global__ void __launch_bounds__(256) k_f2(const float* __restrict__ Xh, const float* __restrict__ s1,
                                            const float* __restrict__ s2, float* __restrict__ Yh) {
    int m = blockIdx.x;                  // 0..287
    int xx = m / 12, y = m - 12 * xx;
    const float* W; int xw;
    if (xx < 12) { W = s1; xw = xx; } else { W = s2; xw = xx - 12; }
    __shared__ float xr[128], xi[128];
    __shared__ float pr[256], pi[256];
    int tid = threadIdx.x;               // 256
    if (tid < 128) {
        int bb = tid >> 6, i = tid & 63;
        xr[tid] = Xh[(((long)bb * 64 + i) * 288 + m) * 2];
        xi[tid] = Xh[(((long)bb * 64 + i) * 288 + m) * 2 + 1];
    }
    __syncthreads();
    int half = tid >> 7;
    int t2 = tid & 127;
    int bb = t2 >> 6, o = t2 & 63;
    float re = 0.f, im = 0.f;
    for (int i = half * 32; i < half * 32 + 32; i++) {
        long wb = (long)i * 18432 + (long)o * 288 + xw * 24 + y * 2;
        float wr = W[wb], wi = W[wb + 1];
        float a = xr[bb * 64 + i], cc = xi[bb * 64 + i];
        re += a * wr - cc * wi;
        im += a * wi + cc * wr;
    }
    pr[tid] = re; pi[tid] = im;
    __syncthreads();
    if (tid < 128) {
        float re2 = pr[tid] + pr[tid + 128];
        float im2 = pi[tid] + pi[tid + 128];
        Yh[(((long)bb * 64 + o) * 288 + m) * 2] = re2;
        Yh[(((long)bb * 64 + o) * 288 + m) * 2 + 1] = im2;
    }
}

// inverse DFT + pointwise conv + bias + InstanceNorm + GELU, fused per (b, out-channel)
__global__ void __launch_bounds__(1024) k_f3(const float* __restrict__ Yh, const float* __restrict__ x,
                                             const float* __restrict__ pwW, const float* __restrict__ pwb,
                                             float* __restrict__ xo) {
    int blk = blockIdx.x;
    int b = blk >> 6, o = blk & 63;
    int tid = threadIdx.x;   // 1024; each thread owns 4 consecutive pixels
    __shared__ float yre[288], yim[288];
    __shared__ float Qre[64][12], Qim[64][12];
    __shared__ float cs[64], sn[64];
    __shared__ float red[1024];
    if (tid < 64) {
        double a = (2.0 * PI_ / 64.0) * (double)tid;
        cs[tid] = (float)cos(a);
        sn[tid] = (float)sin(a);
    }
    if (tid < 288) {
        yre[tid] = Yh[((long)blk * 288 + tid) * 2];
        yim[tid] = Yh[((long)blk * 288 + tid) * 2 + 1];
    }
    __syncthreads();
    if (tid < 768) {    // (h, c): complex ifft along rows (1/64 scale)
        int h = tid / 12, c = tid - 12 * h;
        float re = 0.f, im = 0.f;
#pragma unroll
        for (int xx = 0; xx < 24; xx++) {
            int r = (xx < 12) ? xx : (xx + 40);
            int k = (r * h) & 63;
            float wr = cs[k], wi = sn[k];
            float a = yre[xx * 12 + c], bb = yim[xx * 12 + c];
            re += a * wr - bb * wi;
            im += a * wi + bb * wr;
        }
        Qre[h][c] = re * (1.0f / 64.0f);
        Qim[h][c] = im * (1.0f / 64.0f);
    }
    __syncthreads();
    float bias = pwb[o];
    int h = tid >> 4;
    int w0 = (tid & 15) * 4;
    float sp0, sp1, sp2, sp3;
    {
        float base = Qre[h][0];
        sp0 = sp1 = sp2 = sp3 = base;
#pragma unroll
        for (int c = 1; c < 12; c++) {
            float qr = Qre[h][c], qi = Qim[h][c];
            int k0 = (c * w0) & 63, k1 = (c * (w0 + 1)) & 63;
            int k2 = (c * (w0 + 2)) & 63, k3 = (c * (w0 + 3)) & 63;
            sp0 += 2.0f * (qr * cs[k0] - qi * sn[k0]);
            sp1 += 2.0f * (qr * cs[k1] - qi * sn[k1]);
            sp2 += 2.0f * (qr * cs[k2] - qi * sn[k2]);
            sp3 += 2.0f * (qr * cs[k3] - qi * sn[k3]);
        }
    }
    float a0 = sp0 * (1.0f / 64.0f) + bias;
    float a1 = sp1 * (1.0f / 64.0f) + bias;
    float a2 = sp2 * (1.0f / 64.0f) + bias;
    float a3 = sp3 * (1.0f / 64.0f) + bias;
    const float* xb = x + ((long)b * 64) * 4096 + tid * 4;
    for (int i = 0; i < 64; i++) {
        float wv = pwW[o * 64 + i];
        const float4 xv = *(const float4*)(xb + (long)i * 4096);
        a0 = fmaf(xv.x, wv, a0);
        a1 = fmaf(xv.y, wv, a1);
        a2 = fmaf(xv.z, wv, a2);
        a3 = fmaf(xv.w, wv, a3);
    }
    red[tid] = a0 + a1 + a2 + a3;
    __syncthreads();
    for (int d = 512; d > 0; d >>= 1) { if (tid < d) red[tid] += red[tid + d]; __syncthreads(); }
    float mu = red[0] * (1.0f / 4096.0f);
    __syncthreads();
    float d0 = a0 - mu, d1 = a1 - mu, d2 = a2 - mu, d3 = a3 - mu;
    red[tid] = d0 * d0 + d1 * d1 + d2 * d2 + d3 * d3;
    __syncthreads();
    for (int d = 512; d > 0; d >>= 1) { if (tid < d) red[tid] += red[tid + d]; __syncthreads(); }
    float var = red[0] * (1.0f / 4096.0f);
    float inv = 1.0f / sqrtf(var + 1e-5f);
    float4 ov = make_float4(gelu_f(d0 * inv), gelu_f(d1 * inv), gelu_f(d2 * inv), gelu_f(d3 * inv));
    *(float4*)&xo[(long)blk * 4096 + tid * 4] = ov;
}

// ---------------------------------------------------------------- projection MLP (64 -> 64 -> 3)
__global__ void __launch_bounds__(256) k_proj(
    const float* __restrict__ y, const float* __restrict__ W1, const float* __restrict__ b1,
    const float* __restrict__ W2, const float* __restrict__ b2, float* __restrict__ out) {
    __shared__ __align__(16) float yr[4][64];
    __shared__ float h[4][64];
    int ql = threadIdx.x >> 6, j = threadIdx.x & 63;
    long node = (long)blockIdx.x * 4 + ql;
    yr[ql][j] = y[node * 64 + j];
    __syncthreads();
    float a = b1[j];
    for (int k = 0; k < 64; k += 4) {
        float w0 = W1[(k + 0) * 64 + j], w1 = W1[(k + 1) * 64 + j];
        float w2 = W1[(k + 2) * 64 + j], w3 = W1[(k + 3) * 64 + j];
        const float4 hv = *(const float4*)&yr[ql][k];
        a = fmaf(hv.x, w0, fmaf(hv.y, w1, fmaf(hv.z, w2, fmaf(hv.w, w3, a))));
    }
    h[ql][j] = gelu_f(a);
    __syncthreads();
    if (j < 3) {
        float a2 = b2[j];
        for (int k = 0; k < 64; k++) a2 = fmaf(h[ql][k], W2[k * 3 + j], a2);
        out[node * 3 + j] = a2;
    }
}

// ---------------------------------------------------------------- launch
extern "C" void kernel_launch(void* const* d_in, const int* in_sizes, int n_in,
                              void* d_out, int out_size, void* d_ws, size_t ws_size,
                              hipStream_t stream) {
    (void)in_sizes; (void)n_in; (void)out_size; (void)ws_size;
    const float* coords   = (const float*)d_in[0];
    const float* features = (const float*)d_in[1];
    const float* lift_W1 = (const float*)d_in[2];
    const float* lift_b1 = (const float*)d_in[3];
    const float* lift_W2 = (const float*)d_in[4];
    const float* lift_b2 = (const float*)d_in[5];
    const float* gin_W1 = (const float*)d_in[6];
    const float* gin_b1 = (const float*)d_in[7];
    const float* gin_W2 = (const float*)d_in[8];
    const float* gin_b2 = (const float*)d_in[9];
    const float* gin_W3 = (const float*)d_in[10];
    const float* gin_b3 = (const float*)d_in[11];
    const float* spec1 = (const float*)d_in[12];
    const float* spec2 = (const float*)d_in[13];
    const float* pw_W  = (const float*)d_in[14];
    const float* pw_b  = (const float*)d_in[15];
    const float* gout_W1 = (const float*)d_in[16];
    const float* gout_b1 = (const float*)d_in[17];
    const float* gout_W2 = (const float*)d_in[18];
    const float* gout_b2 = (const float*)d_in[19];
    const float* gout_W3 = (const float*)d_in[20];
    const float* gout_b3 = (const float*)d_in[21];
    const float* proj_W1 = (const float*)d_in[22];
    const float* proj_b1 = (const float*)d_in[23];
    const float* proj_W2 = (const float*)d_in[24];
    const float* proj_b2 = (const float*)d_in[25];

    char* ws = (char*)d_ws;
    size_t off = 0;
    auto alloc = [&](size_t bytes) -> char* {
        char* p = ws + off;
        off = (off + bytes + 255) & ~(size_t)255;
        return p;
    };
    float4* grid_pack = (float4*)alloc((size_t)NG * 16);
    float*  feat      = (float*)alloc((size_t)B_ * N_ * 64 * 4);
    int*    bin_cnt   = (int*)alloc((size_t)B_ * 4096 * 4);
    int*    bin_fill  = (int*)alloc((size_t)B_ * 4096 * 4);
    int*    bin_off   = (int*)alloc((size_t)B_ * 4097 * 4);
    float4* srt       = (float4*)alloc((size_t)B_ * N_ * 16);
    int*    idx_in    = (int*)alloc((size_t)B_ * NG * 16 * 4);
    float*  dist_in   = (float*)alloc((size_t)B_ * NG * 16 * 4);
    float*  lastd_in  = (float*)alloc((size_t)B_ * NG * 4);
    float*  sig_in    = (float*)alloc(256);
    float*  wtsb_in   = (float*)alloc((size_t)B_ * NG * 16 * 4);
    float*  wsum_in   = (float*)alloc((size_t)B_ * NG * 4);
    float*  gout_buf  = (float*)alloc((size_t)B_ * NG * 64 * 4);
    float*  xb0       = (float*)alloc((size_t)B_ * 64 * NG * 4);
    float*  xb1       = (float*)alloc((size_t)B_ * 64 * NG * 4);
    float*  Xh        = (float*)alloc((size_t)B_ * 64 * 288 * 2 * 4);
    float*  Yh        = (float*)alloc((size_t)B_ * 64 * 288 * 2 * 4);
    float*  g2        = (float*)alloc((size_t)B_ * NG * 64 * 4);
    int*    idx_out   = (int*)alloc((size_t)B_ * N_ * 16 * 4);
    float*  dist_out  = (float*)alloc((size_t)B_ * N_ * 16 * 4);
    float*  lastd_out = (float*)alloc((size_t)B_ * N_ * 4);
    float*  sig_out   = (float*)alloc(256);
    float*  wtsb_out  = (float*)alloc((size_t)B_ * N_ * 16 * 4);
    float*  wsum_out  = (float*)alloc((size_t)B_ * N_ * 4);
    float*  ybuf      = (float*)alloc((size_t)B_ * N_ * 64 * 4);

    hipMemsetAsync(bin_cnt, 0, (size_t)B_ * 4096 * 4, stream);
    hipMemsetAsync(bin_fill, 0, (size_t)B_ * 4096 * 4, stream);

    k_gridgen<<<NG / 256, 256, 0, stream>>>(grid_pack);
    k_lift<<<(B_ * N_) / 4, 256, 0, stream>>>(features, lift_W1, lift_b1, lift_W2, lift_b2, feat);
    k_bincount<<<(B_ * N_) / 256, 256, 0, stream>>>((const float2*)coords, bin_cnt);
    k_binscan<<<B_, 1024, 0, stream>>>(bin_cnt, bin_off);
    k_binscatter<<<(B_ * N_) / 256, 256, 0, stream>>>((const float2*)coords, bin_off, bin_fill, srt);
    k_knn_in<<<(B_ * NG * 64) / 256, 256, 0, stream>>>(grid_pack, srt, bin_off, idx_in, dist_in, lastd_in);
    k_median_bis<<<1, 1024, 0, stream>>>(lastd_in, B_ * NG, sig_in);
    k_wts<<<(B_ * NG) / 256, 256, 0, stream>>>(dist_in, sig_in, wtsb_in, wsum_in, B_ * NG);
    k_edge<0><<<(B_ * NG) / 8, 256, 0, stream>>>(idx_in, dist_in, wtsb_in, wsum_in,
        (const float2*)coords, grid_pack, feat,
        gin_W1, gin_b1, gin_W2, gin_b2, gin_W3, gin_b3, gout_buf, NG, N_);
    {
        dim3 g(64 / 32, NG / 32, B_); dim3 t(32, 8);
        k_transp<<<g, t, 0, stream>>>(gout_buf, xb0, NG, 64);
    }
    float* xc = xb0; float* xn = xb1;
    for (int d = 0; d < 3; d++) {
        k_f1<<<B_ * 64, 1024, 0, stream>>>(xc, Xh);
        k_f2<<<288, 256, 0, stream>>>(Xh, spec1 + (size_t)d * 1179648, spec2 + (size_t)d * 1179648, Yh);
        k_f3<<<B_ * 64, 1024, 0, stream>>>(Yh, xc, pw_W + (size_t)d * 4096, pw_b + (size_t)d * 64, xn);
        float* tmp = xc; xc = xn; xn = tmp;
    }
    {
        dim3 g(NG / 32, 64 / 32, B_); dim3 t(32, 8);
        k_transp<<<g, t, 0, stream>>>(xc, g2, 64, NG);
    }
    k_knn_out<<<(B_ * N_ * 64) / 256, 256, 0, stream>>>((const float2*)coords, grid_pack, idx_out, dist_out, lastd_out);
    k_median_bis<<<1, 1024, 0, stream>>>(lastd_out, B_ * N_, sig_out);
    k_wts<<<(B_ * N_) / 256, 256, 0, stream>>>(dist_out, sig_out, wtsb_out, wsum_out, B_ * N_);
    k_edge<1><<<(B_ * N_) / 8, 256, 0, stream>>>(idx_out, dist_out, wtsb_out, wsum_out,
        (const float2*)coords, grid_pack, g2,
        gout_W1, gout_b1, gout_W2, gout_b2, gout_W3, gout_b3, ybuf, N_, NG);
    k_proj<<<(B_ * N_) / 4, 256, 0, stream>>>(ybuf, proj_W1, proj_b1, proj_W2, proj_b2, (float*)d_out);
}